// Round 3
// 1395.709 us; speedup vs baseline: 1.2447x; 1.2447x over previous
//
#include <hip/hip_runtime.h>
#include <math.h>

// B=64, T=32, D=768, NH=2, dk=384, N=901 (1 cls + 900 local)

typedef short bf16x8 __attribute__((ext_vector_type(8)));
typedef float f32x4 __attribute__((ext_vector_type(4)));
typedef unsigned short ushort_t;

#define GRU_NB 48

__device__ __forceinline__ unsigned short f2b(float f) {
    unsigned int u = __float_as_uint(f);
    unsigned int r = (u + 0x7FFFu + ((u >> 16) & 1u)) >> 16;
    return (unsigned short)r;
}
__device__ __forceinline__ float b2f(unsigned short s) {
    return __uint_as_float(((unsigned int)s) << 16);
}
__device__ __forceinline__ float sigm(float x) { return 1.f / (1.f + __expf(-x)); }
__device__ __forceinline__ float tanhx(float x) {
    x = fminf(fmaxf(x, -15.f), 15.f);
    float e = __expf(2.f * x);
    return (e - 1.f) / (e + 1.f);
}

// flag barrier: arrival = agent store of monotonically-increasing phase id; poll =
// parallel relaxed agent loads (no RMW contention). Data written before the barrier
// must use agent-scope stores (bypass L2 -> L3) so readers' plain loads (fresh lines)
// see it. flags zeroed by k_cvt_all each launch.
__device__ __forceinline__ void gbar(int* flags, int nb, int phase, int bid, int tid) {
    __syncthreads();   // drains each wave's vmcnt -> agent stores are in L3
    if (tid == 0) __hip_atomic_store(&flags[bid], phase, __ATOMIC_RELAXED, __HIP_MEMORY_SCOPE_AGENT);
    if (tid < 64) {
        for (;;) {
            int v = 0x7fffffff;
            for (int f = tid; f < nb; f += 64)
                v = min(v, __hip_atomic_load(&flags[f], __ATOMIC_RELAXED, __HIP_MEMORY_SCOPE_AGENT));
            if (__all(v >= phase)) break;
            __builtin_amdgcn_s_sleep(1);
        }
    }
    __syncthreads();
}

// ---------------- setup: convert weights to bf16, pool sums, zero flags ----------------

__global__ void k_cvt_all(const float* __restrict__ whh, const float* __restrict__ la0,
                          const float* __restrict__ la1, const float* __restrict__ h0,
                          const float* __restrict__ gp, const float* __restrict__ lp,
                          ushort_t* __restrict__ whhb, ushort_t* __restrict__ law0b,
                          ushort_t* __restrict__ law1b, ushort_t* __restrict__ h0b,
                          float* __restrict__ hbuf, float* __restrict__ scal,
                          int* __restrict__ bar) {
    if (blockIdx.x == 0) {
        int t = threadIdx.x;
        if (t < 64) {
            float v1 = (t < 32) ? gp[t] : 0.f;
            float v2 = (t < 32) ? lp[t] : 0.f;
#pragma unroll
            for (int m = 1; m < 32; m <<= 1) { v1 += __shfl_xor(v1, m, 64); v2 += __shfl_xor(v2, m, 64); }
            if (t == 0) { scal[0] = v1; scal[1] = v2; }
        }
        for (int i = threadIdx.x; i < 1024; i += 256) bar[i] = 0;
    }
    long i = (long)blockIdx.x * 256 + threadIdx.x;
    const long n1 = 2304L * 768, n2 = n1 + 768L * 768, n3 = n2 + 768L * 768, n4 = n3 + 64L * 768;
    if (i < n1) whhb[i] = f2b(whh[i]);
    else if (i < n2) law0b[i - n1] = f2b(la0[i - n1]);
    else if (i < n3) law1b[i - n2] = f2b(la1[i - n2]);
    else if (i < n4) { float v = h0[i - n3]; h0b[i - n3] = f2b(v); hbuf[i - n3] = v; }
}

// ---------------- generic fp32 tile GEMM: 4 rows x <=256 cols per block ----------------
// out = acc*s1 + bias[c]*s2 (+ bias2[c] if c<b2lim); optional relu; optional agent store.
// K unrolled by 16: 16 independent B-loads in flight per thread (latency hiding).

__device__ __forceinline__ void tgemm(
    const float* __restrict__ A, long lda,
    const float* __restrict__ Bm, int ldb, int transB,
    const float* __restrict__ bias, float s1, float s2,
    const float* __restrict__ bias2, int b2lim,
    float* __restrict__ C, int ldc, int ncols, int K, int relu, int agent,
    int m0, int n0, float* As, int tid)
{
    for (int r = 0; r < 4; r++)
        for (int k = tid; k < K; k += 256)
            As[r * K + k] = A[(long)(m0 + r) * lda + k];
    __syncthreads();
    if (tid < ncols) {
        int c = n0 + tid;
        const float* Bp = transB ? (Bm + (long)c * ldb) : (Bm + c);
        float a0 = 0.f, a1 = 0.f, a2 = 0.f, a3 = 0.f;
        for (int k = 0; k < K; k += 16) {
            float bv[16];
            if (!transB) {
#pragma unroll
                for (int i = 0; i < 16; i++) bv[i] = Bp[(long)(k + i) * ldb];
            } else {
                float4 q0 = *(const float4*)(Bp + k);
                float4 q1 = *(const float4*)(Bp + k + 4);
                float4 q2 = *(const float4*)(Bp + k + 8);
                float4 q3 = *(const float4*)(Bp + k + 12);
                bv[0] = q0.x; bv[1] = q0.y; bv[2]  = q0.z; bv[3]  = q0.w;
                bv[4] = q1.x; bv[5] = q1.y; bv[6]  = q1.z; bv[7]  = q1.w;
                bv[8] = q2.x; bv[9] = q2.y; bv[10] = q2.z; bv[11] = q2.w;
                bv[12] = q3.x; bv[13] = q3.y; bv[14] = q3.z; bv[15] = q3.w;
            }
#pragma unroll
            for (int i = 0; i < 16; i += 4) {
                float4 x0 = *(const float4*)&As[0 * K + k + i];
                float4 x1 = *(const float4*)&As[1 * K + k + i];
                float4 x2 = *(const float4*)&As[2 * K + k + i];
                float4 x3 = *(const float4*)&As[3 * K + k + i];
                a0 += x0.x * bv[i] + x0.y * bv[i + 1] + x0.z * bv[i + 2] + x0.w * bv[i + 3];
                a1 += x1.x * bv[i] + x1.y * bv[i + 1] + x1.z * bv[i + 2] + x1.w * bv[i + 3];
                a2 += x2.x * bv[i] + x2.y * bv[i + 1] + x2.z * bv[i + 2] + x2.w * bv[i + 3];
                a3 += x3.x * bv[i] + x3.y * bv[i + 1] + x3.z * bv[i + 2] + x3.w * bv[i + 3];
            }
        }
        float bb = (bias ? bias[c] * s2 : 0.f) + ((bias2 && c < b2lim) ? bias2[c] : 0.f);
        float o0 = a0 * s1 + bb, o1 = a1 * s1 + bb, o2 = a2 * s1 + bb, o3 = a3 * s1 + bb;
        if (relu) { o0 = fmaxf(o0, 0.f); o1 = fmaxf(o1, 0.f); o2 = fmaxf(o2, 0.f); o3 = fmaxf(o3, 0.f); }
        if (agent) {
            __hip_atomic_store(&C[(long)(m0 + 0) * ldc + c], o0, __ATOMIC_RELAXED, __HIP_MEMORY_SCOPE_AGENT);
            __hip_atomic_store(&C[(long)(m0 + 1) * ldc + c], o1, __ATOMIC_RELAXED, __HIP_MEMORY_SCOPE_AGENT);
            __hip_atomic_store(&C[(long)(m0 + 2) * ldc + c], o2, __ATOMIC_RELAXED, __HIP_MEMORY_SCOPE_AGENT);
            __hip_atomic_store(&C[(long)(m0 + 3) * ldc + c], o3, __ATOMIC_RELAXED, __HIP_MEMORY_SCOPE_AGENT);
        } else {
            C[(long)(m0 + 0) * ldc + c] = o0;
            C[(long)(m0 + 1) * ldc + c] = o1;
            C[(long)(m0 + 2) * ldc + c] = o2;
            C[(long)(m0 + 3) * ldc + c] = o3;
        }
    }
}

// ---------------- fused head: t12/t12g -> avec/global_out -> base (3 phases) ----------------

struct HeadP {
    const float *img, *ga_w2, *ga_b2, *go_w2, *go_b2;
    const float *ga_w3, *ga_b3, *go_w3, *go_b3;
    const float *ga_pool, *scal, *w_ih, *b_ih, *b_hh;
    float *t12, *t12g, *avec, *hcat, *base;
    int* flags; int p0, p1;
};

__global__ void __launch_bounds__(256) k_head(HeadP P) {
    __shared__ __align__(16) float As[4 * 768];
    int bid = blockIdx.x, tid = threadIdx.x;
    for (int p = P.p0; p <= P.p1; p++) {
        if (p == 1) {
            if (bid < 96) {
                int prob = bid / 48, r = bid % 48, m4 = r / 3, nt = r % 3;
                tgemm(P.img, 901L * 768, prob ? P.go_w2 : P.ga_w2, 768, 0,
                      prob ? P.go_b2 : P.ga_b2, 1.f, 1.f, nullptr, 0,
                      prob ? P.t12g : P.t12, 768, 256, 768, 0, 1, m4 * 4, nt * 256, As, tid);
            }
        } else if (p == 2) {
            if (bid < 96) {
                int prob = bid / 48, r = bid % 48, m4 = r / 3, nt = r % 3;
                float sc = prob ? P.scal[0] : P.ga_pool[0];
                tgemm(prob ? P.t12g : P.t12, 768, prob ? P.go_w3 : P.ga_w3, 768, 0,
                      prob ? P.go_b3 : P.ga_b3, sc, sc, nullptr, 0,
                      prob ? (P.hcat + 768) : P.avec, prob ? 1536 : 768, 256, 768, 0, 1,
                      m4 * 4, nt * 256, As, tid);
            }
        } else if (p == 3) {
            if (bid < 144) {
                int m4 = bid / 9, nt = bid % 9;
                // base = avec @ w_ih^T + b_ih (+ b_hh for first 1536 cols)
                tgemm(P.avec, 768, P.w_ih, 768, 1, P.b_ih, 1.f, 1.f, P.b_hh, 1536,
                      P.base, 2304, 256, 768, 0, 0, m4 * 4, nt * 256, As, tid);
            }
        }
        if (p < P.p1) gbar(P.flags, 144, p, bid, tid);
    }
}

// ---------------- GRU scan: 48 blocks x 192 thr, whh/base/h in LDS, flag barrier ----------------

struct GruP {
    const ushort_t* h0b; const float* h0f; const ushort_t* whh;
    const float* base; const float* bhh; ushort_t* qemb; int* flags;
};

__global__ void __launch_bounds__(192) k_gru_coop(GruP P) {
    __shared__ __align__(16) ushort_t whh_s[3][16][776];
    __shared__ float gs[3][64][20];
    __shared__ float bs[3][64][20];
    __shared__ float h_s[64][20];
    __shared__ float bhh_s[16];
    int tid = threadIdx.x;
    int g = tid >> 6, lane = tid & 63, quad = lane >> 4, l16 = lane & 15;
    int j = blockIdx.x, d0 = j * 16;
    for (int r = 0; r < 16; r++)
        for (int kk = lane * 8; kk < 768; kk += 512)
            *(bf16x8*)&whh_s[g][r][kk] = *(const bf16x8*)&P.whh[(size_t)(g * 768 + d0 + r) * 768 + kk];
    for (int e = tid; e < 3072; e += 192) {
        int g2 = e >> 10, rem = e & 1023, b = rem >> 4, c = rem & 15;
        bs[g2][b][c] = P.base[b * 2304 + g2 * 768 + d0 + c];
    }
    for (int e = tid; e < 1024; e += 192) {
        int b = e >> 4, c = e & 15;
        h_s[b][c] = P.h0f[b * 768 + d0 + c];
    }
    if (tid < 16) bhh_s[tid] = P.bhh[1536 + d0 + tid];
    __syncthreads();
    for (int t = 0; t < 32; t++) {
        const ushort_t* Ap = (t == 0) ? P.h0b : (P.qemb + (size_t)(t - 1) * 768);
        size_t ldA = (t == 0) ? 768 : (size_t)32 * 768;
        f32x4 zz4 = {0.f, 0.f, 0.f, 0.f};
        f32x4 acc[4];
#pragma unroll
        for (int mi = 0; mi < 4; mi++) acc[mi] = zz4;
        for (int kk = 0; kk < 768; kk += 32) {
            bf16x8 bfr = *(const bf16x8*)&whh_s[g][l16][kk + quad * 8];
#pragma unroll
            for (int mi = 0; mi < 4; mi++) {
                bf16x8 af = *(const bf16x8*)(Ap + (size_t)(mi * 16 + l16) * ldA + kk + quad * 8);
                acc[mi] = __builtin_amdgcn_mfma_f32_16x16x32_bf16(af, bfr, acc[mi], 0, 0, 0);
            }
        }
#pragma unroll
        for (int mi = 0; mi < 4; mi++)
#pragma unroll
            for (int r = 0; r < 4; r++)
                gs[g][mi * 16 + quad * 4 + r][l16] = acc[mi][r];
        __syncthreads();
        for (int e = tid; e < 512; e += 192) {
            int b = e >> 3, c0 = (e & 7) * 2;
            float hn[2];
#pragma unroll
            for (int u = 0; u < 2; u++) {
                int c = c0 + u;
                float rr = sigm(gs[0][b][c] + bs[0][b][c]);
                float zg = sigm(gs[1][b][c] + bs[1][b][c]);
                float nn = tanhx(bs[2][b][c] + rr * (gs[2][b][c] + bhh_s[c]));
                float hv = h_s[b][c];
                hn[u] = (1.f - zg) * nn + zg * hv;
                h_s[b][c] = hn[u];
            }
            unsigned int pk = (unsigned int)f2b(hn[0]) | ((unsigned int)f2b(hn[1]) << 16);
            __hip_atomic_store((unsigned int*)&P.qemb[((size_t)b * 32 + t) * 768 + d0 + c0],
                               pk, __ATOMIC_RELAXED, __HIP_MEMORY_SCOPE_AGENT);
        }
        __syncthreads();   // drain agent stores to L3 before flag
        if (t < 31) {
            if (tid == 0)
                __hip_atomic_store(&P.flags[j], t + 1, __ATOMIC_RELAXED, __HIP_MEMORY_SCOPE_AGENT);
            if (tid < 64) {
                for (;;) {
                    int v = (tid < GRU_NB)
                        ? __hip_atomic_load(&P.flags[tid], __ATOMIC_RELAXED, __HIP_MEMORY_SCOPE_AGENT)
                        : 0x7fffffff;
                    if (__all(v > t)) break;
                    __builtin_amdgcn_s_sleep(1);
                }
            }
            __syncthreads();
        }
    }
}

// fallback (non-coop): 32 per-step launches
__global__ void __launch_bounds__(256) k_gru_step(
    int t, const ushort_t* h0b, const ushort_t* whh, const float* base,
    const float* bhh, float* h, ushort_t* qemb)
{
    int wv = threadIdx.x >> 6, lane = threadIdx.x & 63;
    int quad = lane >> 4, l16 = lane & 15;
    int d0 = blockIdx.x * 64 + wv * 16;
    float bhhn = bhh[1536 + d0 + l16];
    const ushort_t* Ap = (t == 0) ? h0b : (qemb + (long)(t - 1) * 768);
    long ldA = (t == 0) ? 768 : 32 * 768;
    int d = d0 + l16;
    f32x4 zz4 = {0.f, 0.f, 0.f, 0.f};
    f32x4 acc[3][4];
#pragma unroll
    for (int g = 0; g < 3; g++)
#pragma unroll
        for (int mi = 0; mi < 4; mi++) acc[g][mi] = zz4;
    for (int kk = 0; kk < 768; kk += 32) {
        bf16x8 af[4];
#pragma unroll
        for (int mi = 0; mi < 4; mi++)
            af[mi] = *(const bf16x8*)(Ap + (long)(mi * 16 + l16) * ldA + kk + quad * 8);
#pragma unroll
        for (int g = 0; g < 3; g++) {
            bf16x8 bfr = *(const bf16x8*)(whh + (long)(g * 768 + d0 + l16) * 768 + kk + quad * 8);
#pragma unroll
            for (int mi = 0; mi < 4; mi++)
                acc[g][mi] = __builtin_amdgcn_mfma_f32_16x16x32_bf16(af[mi], bfr, acc[g][mi], 0, 0, 0);
        }
    }
#pragma unroll
    for (int mi = 0; mi < 4; mi++) {
#pragma unroll
        for (int r = 0; r < 4; r++) {
            int b = mi * 16 + quad * 4 + r;
            const float* bb = base + b * 2304;
            float rr = sigm(acc[0][mi][r] + bb[d]);
            float zg = sigm(acc[1][mi][r] + bb[768 + d]);
            float nn = tanhx(bb[1536 + d] + rr * (acc[2][mi][r] + bhhn));
            float hv = h[b * 768 + d];
            float hnew = (1.f - zg) * nn + zg * hv;
            h[b * 768 + d] = hnew;
            qemb[(long)(b * 32 + t) * 768 + d] = f2b(hnew);
        }
    }
}

// ---------------- generic bf16 MFMA GEMM (64x64 tile) ----------------

__global__ void __launch_bounds__(256) k_gemm_bf16(
    const ushort_t* __restrict__ A, int lda,
    const ushort_t* __restrict__ B, int ldb, int transB,
    const float* __restrict__ bias,
    ushort_t* __restrict__ Cb, int ldc,
    int K, int remap, int rowoff)
{
    __shared__ __align__(16) ushort_t As[64][72];
    __shared__ __align__(16) ushort_t Bs[64][72];
    int tid = threadIdx.x;
    int wv = tid >> 6, lane = tid & 63, quad = lane >> 4, l16 = lane & 15;
    long bm = (long)blockIdx.y * 64, bn = (long)blockIdx.x * 64;
    f32x4 zz4 = {0.f, 0.f, 0.f, 0.f};
    f32x4 acc[4];
#pragma unroll
    for (int mi = 0; mi < 4; mi++) acc[mi] = zz4;
    int row4 = tid >> 2, seg = tid & 3;
    for (int k0 = 0; k0 < K; k0 += 64) {
        {
            const ushort_t* src = A + (bm + row4) * lda + k0 + seg * 16;
            *(bf16x8*)&As[row4][seg * 16] = *(const bf16x8*)src;
            *(bf16x8*)&As[row4][seg * 16 + 8] = *(const bf16x8*)(src + 8);
        }
        if (transB) {
            const ushort_t* src = B + (bn + row4) * ldb + k0 + seg * 16;
            *(bf16x8*)&Bs[row4][seg * 16] = *(const bf16x8*)src;
            *(bf16x8*)&Bs[row4][seg * 16 + 8] = *(const bf16x8*)(src + 8);
        } else {
            const ushort_t* src = B + (long)(k0 + row4) * ldb + bn + seg * 16;
            bf16x8 v0 = *(const bf16x8*)src;
            bf16x8 v1 = *(const bf16x8*)(src + 8);
#pragma unroll
            for (int i = 0; i < 8; i++) {
                Bs[seg * 16 + i][row4] = (ushort_t)v0[i];
                Bs[seg * 16 + 8 + i][row4] = (ushort_t)v1[i];
            }
        }
        __syncthreads();
#pragma unroll
        for (int ks = 0; ks < 64; ks += 32) {
            bf16x8 bfr = *(const bf16x8*)&Bs[wv * 16 + l16][ks + quad * 8];
#pragma unroll
            for (int mi = 0; mi < 4; mi++) {
                bf16x8 af = *(const bf16x8*)&As[mi * 16 + l16][ks + quad * 8];
                acc[mi] = __builtin_amdgcn_mfma_f32_16x16x32_bf16(af, bfr, acc[mi], 0, 0, 0);
            }
        }
        __syncthreads();
    }
    int ncol = (int)bn + wv * 16 + l16;
    float bv = bias ? bias[ncol] : 0.f;
#pragma unroll
    for (int mi = 0; mi < 4; mi++) {
#pragma unroll
        for (int r = 0; r < 4; r++) {
            long row = bm + mi * 16 + quad * 4 + r;
            long orow = remap ? ((row >> 5) * 64 + rowoff + (row & 31)) : row;
            Cb[orow * ldc + ncol] = f2b(acc[mi][r] + bv);
        }
    }
}

// ---------------- fused flash attention, key-split partials (qb folded in) ----------------

__global__ void __launch_bounds__(512) k_flash(
    const float* __restrict__ img, const ushort_t* __restrict__ Qt,
    const ushort_t* __restrict__ Qb, const float* __restrict__ la_b1,
    float* __restrict__ pm, float* __restrict__ pl,
    ushort_t* __restrict__ pacc, int nsplit)
{
    __shared__ __align__(16) ushort_t xs[32][776];
    __shared__ float Sls[64][36];
    __shared__ __align__(16) ushort_t Pls[64][40];
    __shared__ float m_s[64], l_s[64], al_s[64], qb_s[64];
    int b = blockIdx.x;
    int sp = blockIdx.y;
    int tper = (29 + nsplit - 1) / nsplit;
    int tb = sp * tper, te = min(29, tb + tper);
    int tid = threadIdx.x;
    int wv = tid >> 6, lane = tid & 63, quad = lane >> 4, l16 = lane & 15;
    { // qb_s[row] = Q_h[b,q,:] . la_b1_h   (8 lanes per row)
        int row = tid >> 3, sub = tid & 7;
        int hh = row >> 5, q = row & 31;
        const ushort_t* src = Qb + ((size_t)(b * 32 + q)) * 768 + hh * 384 + sub * 48;
        const float* bb = la_b1 + hh * 384 + sub * 48;
        float s = 0.f;
#pragma unroll
        for (int k = 0; k < 48; k++) s += b2f(src[k]) * bb[k];
        s += __shfl_xor(s, 1, 64); s += __shfl_xor(s, 2, 64); s += __shfl_xor(s, 4, 64);
        if (sub == 0) qb_s[row] = s;
    }
    if (tid < 64) { m_s[tid] = -1e30f; l_s[tid] = 0.f; }
    f32x4 zz4 = {0.f, 0.f, 0.f, 0.f};
    f32x4 acc[4][6];
#pragma unroll
    for (int mi = 0; mi < 4; mi++)
#pragma unroll
        for (int nj = 0; nj < 6; nj++) acc[mi][nj] = zz4;
    const float rs = 0.051031036307982884f; // 1/sqrt(384)
    int smi = wv & 3, sni = wv >> 2;
    __syncthreads();
    for (int t0 = tb; t0 < te; t0++) {
        int key0 = t0 * 32;
        { // stage x tile (fp32 global -> bf16 LDS), zero-fill past key 899
            int keyl = tid >> 4, dseg = tid & 15;
            int key = key0 + keyl;
            const float* src = img + ((long)b * 901 + 1 + key) * 768;
            bool ok = key < 900;
#pragma unroll
            for (int c = 0; c < 12; c++) {
                int dd = c * 64 + dseg * 4;
                float x0 = 0, x1 = 0, x2 = 0, x3 = 0;
                if (ok) { float4 v = *(const float4*)(src + dd); x0 = v.x; x1 = v.y; x2 = v.z; x3 = v.w; }
                ushort_t* dst = &xs[keyl][dd];
                dst[0] = f2b(x0); dst[1] = f2b(x1); dst[2] = f2b(x2); dst[3] = f2b(x3);
            }
        }
        __syncthreads();
        { // S = Qt @ x^T
            f32x4 as = zz4;
            const ushort_t* qrow = Qt + (long)(b * 64 + smi * 16 + l16) * 768 + quad * 8;
            const ushort_t* xrow = &xs[sni * 16 + l16][quad * 8];
#pragma unroll
            for (int kk = 0; kk < 768; kk += 32) {
                bf16x8 aq = *(const bf16x8*)(qrow + kk);
                bf16x8 bx = *(const bf16x8*)(xrow + kk);
                as = __builtin_amdgcn_mfma_f32_16x16x32_bf16(aq, bx, as, 0, 0, 0);
            }
#pragma unroll
            for (int r = 0; r < 4; r++) {
                int row = smi * 16 + quad * 4 + r;
                Sls[row][sni * 16 + l16] = (as[r] + qb_s[row]) * rs;
            }
        }
        __syncthreads();
        { // online softmax: 8 threads per row
            int row = tid >> 3, sub = tid & 7;
            float sv[4];
            float mx = -1e30f;
#pragma unroll
            for (int i = 0; i < 4; i++) {
                int kl = sub + i * 8;
                float s = (key0 + kl < 900) ? Sls[row][kl] : -1e30f;
                sv[i] = s; mx = fmaxf(mx, s);
            }
            mx = fmaxf(mx, __shfl_xor(mx, 1, 64));
            mx = fmaxf(mx, __shfl_xor(mx, 2, 64));
            mx = fmaxf(mx, __shfl_xor(mx, 4, 64));
            float mold = m_s[row];
            float mnew = fmaxf(mold, mx);
            float ss = 0.f;
#pragma unroll
            for (int i = 0; i < 4; i++) {
                float p = __expf(sv[i] - mnew);
                ss += p;
                Pls[row][sub + i * 8] = f2b(p);
            }
            ss += __shfl_xor(ss, 1, 64);
            ss += __shfl_xor(ss, 2, 64);
            ss += __shfl_xor(ss, 4, 64);
            if (sub == 0) {
                float alpha = __expf(mold - mnew);
                al_s[row] = alpha;
                l_s[row] = l_s[row] * alpha + ss;
                m_s[row] = mnew;
            }
        }
        __syncthreads();
        { // rescale + acc += P @ x
            bf16x8 pf[4];
#pragma unroll
            for (int mi = 0; mi < 4; mi++)
                pf[mi] = *(const bf16x8*)&Pls[mi * 16 + l16][quad * 8];
#pragma unroll
            for (int mi = 0; mi < 4; mi++) {
#pragma unroll
                for (int r = 0; r < 4; r++) {
                    float a = al_s[mi * 16 + quad * 4 + r];
#pragma unroll
                    for (int nj = 0; nj < 6; nj++) acc[mi][nj][r] *= a;
                }
            }
#pragma unroll
            for (int nj = 0; nj < 6; nj++) {
                int dd = wv * 96 + nj * 16 + l16;
                bf16x8 bx;
#pragma unroll
                for (int j = 0; j < 8; j++) bx[j] = (short)xs[quad * 8 + j][dd];
#pragma unroll
                for (int mi = 0; mi < 4; mi++)
                    acc[mi][nj] = __builtin_amdgcn_mfma_f32_16x16x32_bf16(pf[mi], bx, acc[mi][nj], 0, 0, 0);
            }
        }
        __syncthreads();
    }
    if (tid < 64) {
        pm[(b * nsplit + sp) * 64 + tid] = m_s[tid];
        pl[(b * nsplit + sp) * 64 + tid] = l_s[tid];
    }
#pragma unroll
    for (int mi = 0; mi < 4; mi++) {
#pragma unroll
        for (int r = 0; r < 4; r++) {
            int row = mi * 16 + quad * 4 + r;
            ushort_t* dst = pacc + ((size_t)(b * nsplit + sp) * 64 + row) * 768;
#pragma unroll
            for (int nj = 0; nj < 6; nj++)
                dst[wv * 96 + nj * 16 + l16] = f2b(acc[mi][nj][r]);
        }
    }
}

// ---------------- fused tail: combine+pool -> pc -> local_out -> f1 -> f2 -> f3 ----------------
// NS = nsplit (compile-time: full unroll + batched loads in the combine phase)

struct TailP {
    const float *pm, *pl; const ushort_t* pacc; const float* lp;
    const float *la_w2, *la_b2, *la_w3, *la_b3, *scal;
    float *plX, *pc, *hcat;
    const float *f1w, *f1b, *f2w, *f2b, *f3w, *f3b;
    float *x1, *x2, *out;
    int* flags; int p0, p1, nsplit;
};

template<int NS>
__global__ void __launch_bounds__(256) k_tail(TailP P) {
    __shared__ __align__(16) float As[4 * 1536];
    __shared__ float cw[4][32];
    int bid = blockIdx.x, tid = threadIdx.x;
    float sla = P.scal[1];
    for (int p = P.p0; p <= P.p1; p++) {
        if (p == 0) {
            int b = bid >> 1, half = bid & 1;
            if (tid < 32) {
                int row = half * 32 + tid;
                float ex[4];
                float mmax = -1e30f;
#pragma unroll
                for (int s = 0; s < NS; s++) mmax = fmaxf(mmax, P.pm[(b * NS + s) * 64 + row]);
                float lsum = 0.f;
#pragma unroll
                for (int s = 0; s < NS; s++) {
                    ex[s] = __expf(P.pm[(b * NS + s) * 64 + row] - mmax);
                    lsum += ex[s] * P.pl[(b * NS + s) * 64 + row];
                }
                float sc = P.lp[tid] / lsum;
#pragma unroll
                for (int s = 0; s < NS; s++) cw[s][tid] = ex[s] * sc;
            }
            __syncthreads();
            // accv[jj] = sum_q sum_s cw[s][q] * pacc[b,s,half*32+q, jj*256+tid]
            // batched: 4 q x NS s x 3 jj = up to 48 independent loads in flight
            const ushort_t* pp = P.pacc + (((size_t)(b * NS)) * 64 + half * 32) * 768 + tid;
            float ac[3] = {0.f, 0.f, 0.f};
            for (int q = 0; q < 32; q += 4) {
                float vv[3][4 * NS];
#pragma unroll
                for (int u = 0; u < 4; u++)
#pragma unroll
                    for (int s = 0; s < NS; s++)
#pragma unroll
                        for (int jj = 0; jj < 3; jj++)
                            vv[jj][u * NS + s] = b2f(pp[((size_t)(s * 64 + q + u)) * 768 + jj * 256]);
#pragma unroll
                for (int u = 0; u < 4; u++)
#pragma unroll
                    for (int s = 0; s < NS; s++) {
                        float w = cw[s][q + u];
#pragma unroll
                        for (int jj = 0; jj < 3; jj++) ac[jj] += w * vv[jj][u * NS + s];
                    }
            }
#pragma unroll
            for (int jj = 0; jj < 3; jj++)
                __hip_atomic_store(&P.plX[b * 1536 + half * 768 + jj * 256 + tid], ac[jj],
                                   __ATOMIC_RELAXED, __HIP_MEMORY_SCOPE_AGENT);
        } else if (p == 1) {
            if (bid < 64) {
                int prob = bid >> 5, r = bid & 31, m4 = r >> 1, nt = r & 1;
                tgemm(P.plX + prob * 768, 1536, P.la_w2 + prob * 384, 768, 0,
                      P.la_b2 + prob * 384, 1.f, sla, nullptr, 0,
                      P.pc + prob * 384, 768, nt ? 128 : 256, 768, 0, 1, m4 * 4, nt * 256, As, tid);
            }
        } else if (p == 2) {
            if (bid < 48) {
                int m4 = bid / 3, nt = bid % 3;
                tgemm(P.pc, 768, P.la_w3, 768, 0, P.la_b3, 1.f, sla, nullptr, 0,
                      P.hcat, 1536, 256, 768, 0, 1, m4 * 4, nt * 256, As, tid);
            }
        } else if (p == 3) {
            if (bid < 64) {
                int m4 = bid >> 2, nt = bid & 3;
                tgemm(P.hcat, 1536, P.f1w, 1024, 0, P.f1b, 1.f, 1.f, nullptr, 0,
                      P.x1, 1024, 256, 1536, 0, 1, m4 * 4, nt * 256, As, tid);
            }
        } else if (p == 4) {
            if (bid < 32) {
                int m4 = bid >> 1, nt = bid & 1;
                tgemm(P.x1, 1024, P.f2w, 512, 0, P.f2b, 1.f, 1.f, nullptr, 0,
                      P.x2, 512, 256, 1024, 1, 1, m4 * 4, nt * 256, As, tid);
            }
        } else if (p == 5) {
            if (bid < 64) {
                int m4 = bid >> 2, nt = bid & 3;
                tgemm(P.x2, 512, P.f3w, 1024, 0, P.f3b, 1.f, 1.f, nullptr, 0,
                      P.out, 1024, 256, 512, 0, 0, m4 * 4, nt * 256, As, tid);
            }
        }
        if (p < P.p1) gbar(P.flags, 128, p + 1, bid, tid);
    }
}

// ---------------- host launcher ----------------

extern "C" void kernel_launch(void* const* d_in, const int* in_sizes, int n_in,
                              void* d_out, int out_size, void* d_ws, size_t ws_size,
                              hipStream_t stream)
{
    const float* img  = (const float*)d_in[1];
    const float* h0   = (const float*)d_in[2];
    const float* w_ih = (const float*)d_in[3];
    const float* w_hh = (const float*)d_in[4];
    const float* b_ih = (const float*)d_in[5];
    const float* b_hh = (const float*)d_in[6];
    const float* ga_w = (const float*)d_in[7];
    const float* ga_b = (const float*)d_in[8];
    const float* ga_pool = (const float*)d_in[9];
    const float* la_w = (const float*)d_in[10];
    const float* la_b = (const float*)d_in[11];
    const float* la_pool = (const float*)d_in[12];
    const float* go_w = (const float*)d_in[13];
    const float* go_b = (const float*)d_in[14];
    const float* go_pool = (const float*)d_in[15];
    const float* f1w = (const float*)d_in[16];
    const float* f1b = (const float*)d_in[17];
    const float* f2w = (const float*)d_in[18];
    const float* f2b_ = (const float*)d_in[19];
    const float* f3w = (const float*)d_in[20];
    const float* f3b = (const float*)d_in[21];
    float* out = (float*)d_out;
    (void)in_sizes; (void)n_in; (void)out_size;

    int nsplit = (ws_size >= (size_t)43 * 1024 * 1024) ? 4 : 2;

    char* w = (char*)d_ws;
    auto alloc = [&](size_t bytes) -> char* {
        char* p = w; w += (bytes + 255) & ~(size_t)255; return p;
    };
    // persistent region
    float*    scal  = (float*)alloc(256);                 // [0]=S_go [1]=S_la
    int*      bar   = (int*)alloc(4096);                  // [0..63]=GRU [64..319]=head [320..447]=tail
    ushort_t* law0b = (ushort_t*)alloc((size_t)768 * 768 * 2);
    ushort_t* law1b = (ushort_t*)alloc((size_t)768 * 768 * 2);
    ushort_t* h0b   = (ushort_t*)alloc((size_t)64 * 768 * 2);
    ushort_t* qembb = (ushort_t*)alloc((size_t)2048 * 768 * 2);
    ushort_t* Qb    = (ushort_t*)alloc((size_t)2048 * 768 * 2);
    ushort_t* Qtb   = (ushort_t*)alloc((size_t)4096 * 768 * 2);
    float*    pm    = (float*)alloc((size_t)64 * 4 * 64 * 4);
    float*    pl    = (float*)alloc((size_t)64 * 4 * 64 * 4);
    float*    plX   = (float*)alloc((size_t)64 * 1536 * 4);
    float*    pc    = (float*)alloc((size_t)64 * 768 * 4);
    float*    hcat  = (float*)alloc((size_t)64 * 1536 * 4);
    float*    x1    = (float*)alloc((size_t)64 * 1024 * 4);
    float*    x2    = (float*)alloc((size_t)64 * 512 * 4);
    // union region: [GRU-phase temporaries] overlaid with [flash pacc]
    char* uni = w;
    char* u = uni;
    auto ualloc = [&](size_t bytes) -> char* {
        char* p = u; u += (bytes + 255) & ~(size_t)255; return p;
    };
    ushort_t* whhb  = (ushort_t*)ualloc((size_t)2304 * 768 * 2);
    float*    t12   = (float*)ualloc((size_t)2 * 64 * 768 * 4);
    float*    avec  = (float*)ualloc((size_t)64 * 768 * 4);
    float*    base  = (float*)ualloc((size_t)64 * 2304 * 4);
    float*    hbuf  = (float*)ualloc((size_t)64 * 768 * 4);
    ushort_t* pacc  = (ushort_t*)uni;   // overlays GRU temporaries; used only after GRU done
    float*    t12g  = t12 + 64 * 768;

    const float* ga_w2 = ga_w + 2 * 768 * 768; const float* ga_w3 = ga_w + 3 * 768 * 768;
    const float* ga_b2 = ga_b + 2 * 768;       const float* ga_b3 = ga_b + 3 * 768;
    const float* go_w2 = go_w + 2 * 768 * 768; const float* go_w3 = go_w + 3 * 768 * 768;
    const float* go_b2 = go_b + 2 * 768;       const float* go_b3 = go_b + 3 * 768;
    const float* la_w0 = la_w;                 const float* la_w1 = la_w + 768 * 768;
    const float* la_w2 = la_w + 2 * 768 * 768; const float* la_w3 = la_w + 3 * 768 * 768;
    const float* la_b0 = la_b;                 const float* la_b1 = la_b + 768;
    const float* la_b2 = la_b + 2 * 768;       const float* la_b3 = la_b + 3 * 768;

    dim3 blk(256);
    k_cvt_all<<<11712, blk, 0, stream>>>(w_hh, la_w0, la_w1, h0, go_pool, la_pool,
                                         whhb, law0b, law1b, h0b, hbuf, scal, bar);

    // fused head (coop; fallback: per-phase launches)
    {
        HeadP P;
        P.img = img; P.ga_w2 = ga_w2; P.ga_b2 = ga_b2; P.go_w2 = go_w2; P.go_b2 = go_b2;
        P.ga_w3 = ga_w3; P.ga_b3 = ga_b3; P.go_w3 = go_w3; P.go_b3 = go_b3;
        P.ga_pool = ga_pool; P.scal = scal; P.w_ih = w_ih; P.b_ih = b_ih; P.b_hh = b_hh;
        P.t12 = t12; P.t12g = t12g; P.avec = avec; P.hcat = hcat; P.base = base;
        P.flags = bar + 64; P.p0 = 1; P.p1 = 3;
        void* args[1] = { &P };
        hipError_t e = hipLaunchCooperativeKernel((void*)k_head, dim3(144), blk, args, 0, stream);
        if (e != hipSuccess)
            for (int p = 1; p <= 3; p++) { P.p0 = P.p1 = p; k_head<<<144, blk, 0, stream>>>(P); }
    }

    // GRU scan (coop; fallback: 32 step launches)
    {
        GruP P;
        P.h0b = h0b; P.h0f = h0; P.whh = whhb; P.base = base; P.bhh = b_hh;
        P.qemb = qembb; P.flags = bar;
        void* args[1] = { &P };
        hipError_t e = hipLaunchCooperativeKernel((void*)k_gru_coop, dim3(GRU_NB), dim3(192),
                                                  args, 0, stream);
        if (e != hipSuccess)
            for (int t = 0; t < 32; t++)
                k_gru_step<<<12, blk, 0, stream>>>(t, h0b, whhb, base, b_hh, hbuf, qembb);
    }

    // Q = q_emb @ la_w0 + la_b0 ; Qt_h = Q_h @ W1_h^T (folded-K trick)
    k_gemm_bf16<<<dim3(12, 32), blk, 0, stream>>>(qembb, 768, law0b, 768, 0, la_b0, Qb, 768, 768, 0, 0);
    k_gemm_bf16<<<dim3(12, 32), blk, 0, stream>>>(Qb, 768, law1b, 768, 1, nullptr, Qtb, 768, 384, 1, 0);
    k_gemm_bf16<<<dim3(12, 32), blk, 0, stream>>>(Qb + 384, 768, law1b + 384, 768, 1, nullptr, Qtb, 768, 384, 1, 32);

    // flash attention, key-split
    k_flash<<<dim3(64, nsplit), dim3(512), 0, stream>>>(img, Qtb, Qb, la_b1, pm, pl, pacc, nsplit);

    // fused tail (coop; fallback: per-phase launches)
    {
        TailP P;
        P.pm = pm; P.pl = pl; P.pacc = pacc; P.lp = la_pool;
        P.la_w2 = la_w2; P.la_b2 = la_b2; P.la_w3 = la_w3; P.la_b3 = la_b3; P.scal = scal;
        P.plX = plX; P.pc = pc; P.hcat = hcat;
        P.f1w = f1w; P.f1b = f1b; P.f2w = f2w; P.f2b = f2b_; P.f3w = f3w; P.f3b = f3b;
        P.x1 = x1; P.x2 = x2; P.out = out;
        P.flags = bar + 320; P.p0 = 0; P.p1 = 5; P.nsplit = nsplit;
        void* args[1] = { &P };
        if (nsplit == 4) {
            hipError_t e = hipLaunchCooperativeKernel((void*)k_tail<4>, dim3(128), blk, args, 0, stream);
            if (e != hipSuccess)
                for (int p = 0; p <= 5; p++) { P.p0 = P.p1 = p; k_tail<4><<<128, blk, 0, stream>>>(P); }
        } else {
            hipError_t e = hipLaunchCooperativeKernel((void*)k_tail<2>, dim3(128), blk, args, 0, stream);
            if (e != hipSuccess)
                for (int p = 0; p <= 5; p++) { P.p0 = P.p1 = p; k_tail<2><<<128, blk, 0, stream>>>(P); }
        }
    }
}

// Round 4
// 1340.751 us; speedup vs baseline: 1.2957x; 1.0410x over previous
//
#include <hip/hip_runtime.h>
#include <math.h>

// B=64, T=32, D=768, NH=2, dk=384, N=901 (1 cls + 900 local)

typedef short bf16x8 __attribute__((ext_vector_type(8)));
typedef float f32x4 __attribute__((ext_vector_type(4)));
typedef unsigned short ushort_t;

#define GRU_NB 48

__device__ __forceinline__ unsigned short f2b(float f) {
    unsigned int u = __float_as_uint(f);
    unsigned int r = (u + 0x7FFFu + ((u >> 16) & 1u)) >> 16;
    return (unsigned short)r;
}
__device__ __forceinline__ float b2f(unsigned short s) {
    return __uint_as_float(((unsigned int)s) << 16);
}
__device__ __forceinline__ float sigm(float x) { return 1.f / (1.f + __expf(-x)); }
__device__ __forceinline__ float tanhx(float x) {
    x = fminf(fmaxf(x, -15.f), 15.f);
    float e = __expf(2.f * x);
    return (e - 1.f) / (e + 1.f);
}

// flag barrier: arrival = agent store of monotonically-increasing phase id; poll =
// parallel relaxed agent loads (no RMW contention). Data written before the barrier
// must use agent-scope stores (bypass L2 -> L3) so readers' plain loads (fresh lines)
// see it. flags zeroed by k_cvt_all each launch.
__device__ __forceinline__ void gbar(int* flags, int nb, int phase, int bid, int tid) {
    __syncthreads();   // drains each wave's vmcnt -> agent stores are in L3
    if (tid == 0) __hip_atomic_store(&flags[bid], phase, __ATOMIC_RELAXED, __HIP_MEMORY_SCOPE_AGENT);
    if (tid < 64) {
        for (;;) {
            int v = 0x7fffffff;
            for (int f = tid; f < nb; f += 64)
                v = min(v, __hip_atomic_load(&flags[f], __ATOMIC_RELAXED, __HIP_MEMORY_SCOPE_AGENT));
            if (__all(v >= phase)) break;
            __builtin_amdgcn_s_sleep(1);
        }
    }
    __syncthreads();
}

// ---------------- setup: convert weights to bf16, pool sums, zero flags ----------------

__global__ void k_cvt_all(const float* __restrict__ whh, const float* __restrict__ la0,
                          const float* __restrict__ la1, const float* __restrict__ h0,
                          const float* __restrict__ gp, const float* __restrict__ lp,
                          ushort_t* __restrict__ whhb, ushort_t* __restrict__ law0b,
                          ushort_t* __restrict__ law1b, ushort_t* __restrict__ h0b,
                          float* __restrict__ hbuf, float* __restrict__ scal,
                          int* __restrict__ bar) {
    if (blockIdx.x == 0) {
        int t = threadIdx.x;
        if (t < 64) {
            float v1 = (t < 32) ? gp[t] : 0.f;
            float v2 = (t < 32) ? lp[t] : 0.f;
#pragma unroll
            for (int m = 1; m < 32; m <<= 1) { v1 += __shfl_xor(v1, m, 64); v2 += __shfl_xor(v2, m, 64); }
            if (t == 0) { scal[0] = v1; scal[1] = v2; }
        }
        for (int i = threadIdx.x; i < 1024; i += 256) bar[i] = 0;
    }
    long i = (long)blockIdx.x * 256 + threadIdx.x;
    const long n1 = 2304L * 768, n2 = n1 + 768L * 768, n3 = n2 + 768L * 768, n4 = n3 + 64L * 768;
    if (i < n1) whhb[i] = f2b(whh[i]);
    else if (i < n2) law0b[i - n1] = f2b(la0[i - n1]);
    else if (i < n3) law1b[i - n2] = f2b(la1[i - n2]);
    else if (i < n4) { float v = h0[i - n3]; h0b[i - n3] = f2b(v); hbuf[i - n3] = v; }
}

// ---------------- parallel fp32 tile GEMM: MR rows x 64 cols per block ----------------
// 256 threads = 64 cols x 4 K-chunks; each thread accumulates its K/4 chunk with 8
// independent B-loads in flight; cross-chunk reduction through LDS (aliased onto the
// dead A-tile). out = acc*s1 + bias[c]*s2 (+ bias2[c] if c<b2lim); optional relu,
// optional agent-scope store (for consumers within the same coop kernel).

template<int MR>
__device__ __forceinline__ void tgemm4(
    const float* __restrict__ A, long lda,
    const float* __restrict__ Bm, int ldb, int transB,
    const float* __restrict__ bias, float s1, float s2,
    const float* __restrict__ bias2, int b2lim,
    float* __restrict__ C, int ldc, int K, int relu, int agent,
    int m0, int n0, float* As, int tid)
{
    for (int r = 0; r < MR; r++)
        for (int k = tid; k < K; k += 256)
            As[r * K + k] = A[(long)(m0 + r) * lda + k];
    __syncthreads();
    int cl = tid & 63, kc = tid >> 6;
    int c = n0 + cl;
    int K4 = K >> 2;
    int kb = kc * K4;
    const float* Bp = transB ? (Bm + (long)c * ldb) : (Bm + c);
    float acc[MR];
#pragma unroll
    for (int r = 0; r < MR; r++) acc[r] = 0.f;
    for (int k = kb; k < kb + K4; k += 8) {
        float bv[8];
        if (!transB) {
#pragma unroll
            for (int i = 0; i < 8; i++) bv[i] = Bp[(long)(k + i) * ldb];
        } else {
            float4 q0 = *(const float4*)(Bp + k);
            float4 q1 = *(const float4*)(Bp + k + 4);
            bv[0] = q0.x; bv[1] = q0.y; bv[2] = q0.z; bv[3] = q0.w;
            bv[4] = q1.x; bv[5] = q1.y; bv[6] = q1.z; bv[7] = q1.w;
        }
#pragma unroll
        for (int i = 0; i < 8; i += 4) {
#pragma unroll
            for (int r = 0; r < MR; r++) {
                float4 x = *(const float4*)&As[r * K + k + i];
                acc[r] += x.x * bv[i] + x.y * bv[i + 1] + x.z * bv[i + 2] + x.w * bv[i + 3];
            }
        }
    }
    __syncthreads();           // all As reads done -> safe to alias
    float* Red = As;           // 4*MR*64 floats <= MR*K (K>=256)
#pragma unroll
    for (int r = 0; r < MR; r++) Red[(kc * MR + r) * 64 + cl] = acc[r];
    __syncthreads();
    {
        int rg = tid >> 6;
        float bb = (bias ? bias[c] * s2 : 0.f) + ((bias2 && c < b2lim) ? bias2[c] : 0.f);
#pragma unroll
        for (int i = 0; i < MR / 4; i++) {
            int r = rg + i * 4;
            float sum = (Red[(0 * MR + r) * 64 + cl] + Red[(1 * MR + r) * 64 + cl])
                      + (Red[(2 * MR + r) * 64 + cl] + Red[(3 * MR + r) * 64 + cl]);
            float o = sum * s1 + bb;
            if (relu) o = fmaxf(o, 0.f);
            if (agent) __hip_atomic_store(&C[(long)(m0 + r) * ldc + c], o,
                                          __ATOMIC_RELAXED, __HIP_MEMORY_SCOPE_AGENT);
            else C[(long)(m0 + r) * ldc + c] = o;
        }
    }
}

// ---------------- fused head: t12/t12g -> avec/global_out -> base (3 phases) ----------------
// MR=16 tiles: p1/p2 = 2x4x12 = 96 blocks, p3 = 4x36 = 144 blocks (grid 144)

struct HeadP {
    const float *img, *ga_w2, *ga_b2, *go_w2, *go_b2;
    const float *ga_w3, *ga_b3, *go_w3, *go_b3;
    const float *ga_pool, *scal, *w_ih, *b_ih, *b_hh;
    float *t12, *t12g, *avec, *hcat, *base;
    int* flags; int p0, p1;
};

__global__ void __launch_bounds__(256) k_head(HeadP P) {
    __shared__ __align__(16) float As[16 * 768];
    int bid = blockIdx.x, tid = threadIdx.x;
    for (int p = P.p0; p <= P.p1; p++) {
        if (p == 1) {
            if (bid < 96) {
                int prob = bid / 48, r = bid % 48, m4 = r / 12, ct = r % 12;
                tgemm4<16>(P.img, 901L * 768, prob ? P.go_w2 : P.ga_w2, 768, 0,
                           prob ? P.go_b2 : P.ga_b2, 1.f, 1.f, nullptr, 0,
                           prob ? P.t12g : P.t12, 768, 768, 0, 1, m4 * 16, ct * 64, As, tid);
            }
        } else if (p == 2) {
            if (bid < 96) {
                int prob = bid / 48, r = bid % 48, m4 = r / 12, ct = r % 12;
                float sc = prob ? P.scal[0] : P.ga_pool[0];
                tgemm4<16>(prob ? P.t12g : P.t12, 768, prob ? P.go_w3 : P.ga_w3, 768, 0,
                           prob ? P.go_b3 : P.ga_b3, sc, sc, nullptr, 0,
                           prob ? (P.hcat + 768) : P.avec, prob ? 1536 : 768, 768, 0, 1,
                           m4 * 16, ct * 64, As, tid);
            }
        } else if (p == 3) {
            if (bid < 144) {
                int m4 = bid / 36, ct = bid % 36;
                // base = avec @ w_ih^T + b_ih (+ b_hh for first 1536 cols)
                tgemm4<16>(P.avec, 768, P.w_ih, 768, 1, P.b_ih, 1.f, 1.f, P.b_hh, 1536,
                           P.base, 2304, 768, 0, 0, m4 * 16, ct * 64, As, tid);
            }
        }
        if (p < P.p1) gbar(P.flags, 144, p, bid, tid);
    }
}

// ---------------- GRU scan: 48 blocks x 192 thr, whh/base/h in LDS, flag barrier ----------------

struct GruP {
    const ushort_t* h0b; const float* h0f; const ushort_t* whh;
    const float* base; const float* bhh; ushort_t* qemb; int* flags;
};

__global__ void __launch_bounds__(192) k_gru_coop(GruP P) {
    __shared__ __align__(16) ushort_t whh_s[3][16][776];
    __shared__ float gs[3][64][20];
    __shared__ float bs[3][64][20];
    __shared__ float h_s[64][20];
    __shared__ float bhh_s[16];
    int tid = threadIdx.x;
    int g = tid >> 6, lane = tid & 63, quad = lane >> 4, l16 = lane & 15;
    int j = blockIdx.x, d0 = j * 16;
    for (int r = 0; r < 16; r++)
        for (int kk = lane * 8; kk < 768; kk += 512)
            *(bf16x8*)&whh_s[g][r][kk] = *(const bf16x8*)&P.whh[(size_t)(g * 768 + d0 + r) * 768 + kk];
    for (int e = tid; e < 3072; e += 192) {
        int g2 = e >> 10, rem = e & 1023, b = rem >> 4, c = rem & 15;
        bs[g2][b][c] = P.base[b * 2304 + g2 * 768 + d0 + c];
    }
    for (int e = tid; e < 1024; e += 192) {
        int b = e >> 4, c = e & 15;
        h_s[b][c] = P.h0f[b * 768 + d0 + c];
    }
    if (tid < 16) bhh_s[tid] = P.bhh[1536 + d0 + tid];
    __syncthreads();
    for (int t = 0; t < 32; t++) {
        const ushort_t* Ap = (t == 0) ? P.h0b : (P.qemb + (size_t)(t - 1) * 768);
        size_t ldA = (t == 0) ? 768 : (size_t)32 * 768;
        f32x4 zz4 = {0.f, 0.f, 0.f, 0.f};
        f32x4 acc[4];
#pragma unroll
        for (int mi = 0; mi < 4; mi++) acc[mi] = zz4;
        for (int kk = 0; kk < 768; kk += 32) {
            bf16x8 bfr = *(const bf16x8*)&whh_s[g][l16][kk + quad * 8];
#pragma unroll
            for (int mi = 0; mi < 4; mi++) {
                bf16x8 af = *(const bf16x8*)(Ap + (size_t)(mi * 16 + l16) * ldA + kk + quad * 8);
                acc[mi] = __builtin_amdgcn_mfma_f32_16x16x32_bf16(af, bfr, acc[mi], 0, 0, 0);
            }
        }
#pragma unroll
        for (int mi = 0; mi < 4; mi++)
#pragma unroll
            for (int r = 0; r < 4; r++)
                gs[g][mi * 16 + quad * 4 + r][l16] = acc[mi][r];
        __syncthreads();
        for (int e = tid; e < 512; e += 192) {
            int b = e >> 3, c0 = (e & 7) * 2;
            float hn[2];
#pragma unroll
            for (int u = 0; u < 2; u++) {
                int c = c0 + u;
                float rr = sigm(gs[0][b][c] + bs[0][b][c]);
                float zg = sigm(gs[1][b][c] + bs[1][b][c]);
                float nn = tanhx(bs[2][b][c] + rr * (gs[2][b][c] + bhh_s[c]));
                float hv = h_s[b][c];
                hn[u] = (1.f - zg) * nn + zg * hv;
                h_s[b][c] = hn[u];
            }
            unsigned int pk = (unsigned int)f2b(hn[0]) | ((unsigned int)f2b(hn[1]) << 16);
            __hip_atomic_store((unsigned int*)&P.qemb[((size_t)b * 32 + t) * 768 + d0 + c0],
                               pk, __ATOMIC_RELAXED, __HIP_MEMORY_SCOPE_AGENT);
        }
        __syncthreads();   // drain agent stores to L3 before flag
        if (t < 31) {
            if (tid == 0)
                __hip_atomic_store(&P.flags[j], t + 1, __ATOMIC_RELAXED, __HIP_MEMORY_SCOPE_AGENT);
            if (tid < 64) {
                for (;;) {
                    int v = (tid < GRU_NB)
                        ? __hip_atomic_load(&P.flags[tid], __ATOMIC_RELAXED, __HIP_MEMORY_SCOPE_AGENT)
                        : 0x7fffffff;
                    if (__all(v > t)) break;
                    __builtin_amdgcn_s_sleep(1);
                }
            }
            __syncthreads();
        }
    }
}

// fallback (non-coop): 32 per-step launches
__global__ void __launch_bounds__(256) k_gru_step(
    int t, const ushort_t* h0b, const ushort_t* whh, const float* base,
    const float* bhh, float* h, ushort_t* qemb)
{
    int wv = threadIdx.x >> 6, lane = threadIdx.x & 63;
    int quad = lane >> 4, l16 = lane & 15;
    int d0 = blockIdx.x * 64 + wv * 16;
    float bhhn = bhh[1536 + d0 + l16];
    const ushort_t* Ap = (t == 0) ? h0b : (qemb + (long)(t - 1) * 768);
    long ldA = (t == 0) ? 768 : 32 * 768;
    int d = d0 + l16;
    f32x4 zz4 = {0.f, 0.f, 0.f, 0.f};
    f32x4 acc[3][4];
#pragma unroll
    for (int g = 0; g < 3; g++)
#pragma unroll
        for (int mi = 0; mi < 4; mi++) acc[g][mi] = zz4;
    for (int kk = 0; kk < 768; kk += 32) {
        bf16x8 af[4];
#pragma unroll
        for (int mi = 0; mi < 4; mi++)
            af[mi] = *(const bf16x8*)(Ap + (long)(mi * 16 + l16) * ldA + kk + quad * 8);
#pragma unroll
        for (int g = 0; g < 3; g++) {
            bf16x8 bfr = *(const bf16x8*)(whh + (long)(g * 768 + d0 + l16) * 768 + kk + quad * 8);
#pragma unroll
            for (int mi = 0; mi < 4; mi++)
                acc[g][mi] = __builtin_amdgcn_mfma_f32_16x16x32_bf16(af[mi], bfr, acc[g][mi], 0, 0, 0);
        }
    }
#pragma unroll
    for (int mi = 0; mi < 4; mi++) {
#pragma unroll
        for (int r = 0; r < 4; r++) {
            int b = mi * 16 + quad * 4 + r;
            const float* bb = base + b * 2304;
            float rr = sigm(acc[0][mi][r] + bb[d]);
            float zg = sigm(acc[1][mi][r] + bb[768 + d]);
            float nn = tanhx(bb[1536 + d] + rr * (acc[2][mi][r] + bhhn));
            float hv = h[b * 768 + d];
            float hnew = (1.f - zg) * nn + zg * hv;
            h[b * 768 + d] = hnew;
            qemb[(long)(b * 32 + t) * 768 + d] = f2b(hnew);
        }
    }
}

// ---------------- generic bf16 MFMA GEMM (64x64 tile) ----------------

__global__ void __launch_bounds__(256) k_gemm_bf16(
    const ushort_t* __restrict__ A, int lda,
    const ushort_t* __restrict__ B, int ldb, int transB,
    const float* __restrict__ bias,
    ushort_t* __restrict__ Cb, int ldc,
    int K, int remap, int rowoff)
{
    __shared__ __align__(16) ushort_t As[64][72];
    __shared__ __align__(16) ushort_t Bs[64][72];
    int tid = threadIdx.x;
    int wv = tid >> 6, lane = tid & 63, quad = lane >> 4, l16 = lane & 15;
    long bm = (long)blockIdx.y * 64, bn = (long)blockIdx.x * 64;
    f32x4 zz4 = {0.f, 0.f, 0.f, 0.f};
    f32x4 acc[4];
#pragma unroll
    for (int mi = 0; mi < 4; mi++) acc[mi] = zz4;
    int row4 = tid >> 2, seg = tid & 3;
    for (int k0 = 0; k0 < K; k0 += 64) {
        {
            const ushort_t* src = A + (bm + row4) * lda + k0 + seg * 16;
            *(bf16x8*)&As[row4][seg * 16] = *(const bf16x8*)src;
            *(bf16x8*)&As[row4][seg * 16 + 8] = *(const bf16x8*)(src + 8);
        }
        if (transB) {
            const ushort_t* src = B + (bn + row4) * ldb + k0 + seg * 16;
            *(bf16x8*)&Bs[row4][seg * 16] = *(const bf16x8*)src;
            *(bf16x8*)&Bs[row4][seg * 16 + 8] = *(const bf16x8*)(src + 8);
        } else {
            const ushort_t* src = B + (long)(k0 + row4) * ldb + bn + seg * 16;
            bf16x8 v0 = *(const bf16x8*)src;
            bf16x8 v1 = *(const bf16x8*)(src + 8);
#pragma unroll
            for (int i = 0; i < 8; i++) {
                Bs[seg * 16 + i][row4] = (ushort_t)v0[i];
                Bs[seg * 16 + 8 + i][row4] = (ushort_t)v1[i];
            }
        }
        __syncthreads();
#pragma unroll
        for (int ks = 0; ks < 64; ks += 32) {
            bf16x8 bfr = *(const bf16x8*)&Bs[wv * 16 + l16][ks + quad * 8];
#pragma unroll
            for (int mi = 0; mi < 4; mi++) {
                bf16x8 af = *(const bf16x8*)&As[mi * 16 + l16][ks + quad * 8];
                acc[mi] = __builtin_amdgcn_mfma_f32_16x16x32_bf16(af, bfr, acc[mi], 0, 0, 0);
            }
        }
        __syncthreads();
    }
    int ncol = (int)bn + wv * 16 + l16;
    float bv = bias ? bias[ncol] : 0.f;
#pragma unroll
    for (int mi = 0; mi < 4; mi++) {
#pragma unroll
        for (int r = 0; r < 4; r++) {
            long row = bm + mi * 16 + quad * 4 + r;
            long orow = remap ? ((row >> 5) * 64 + rowoff + (row & 31)) : row;
            Cb[orow * ldc + ncol] = f2b(acc[mi][r] + bv);
        }
    }
}

// ---------------- fused flash attention, key-split partials (qb folded in) ----------------

__global__ void __launch_bounds__(512) k_flash(
    const float* __restrict__ img, const ushort_t* __restrict__ Qt,
    const ushort_t* __restrict__ Qb, const float* __restrict__ la_b1,
    float* __restrict__ pm, float* __restrict__ pl,
    ushort_t* __restrict__ pacc, int nsplit)
{
    __shared__ __align__(16) ushort_t xs[32][776];
    __shared__ float Sls[64][36];
    __shared__ __align__(16) ushort_t Pls[64][40];
    __shared__ float m_s[64], l_s[64], al_s[64], qb_s[64];
    int b = blockIdx.x;
    int sp = blockIdx.y;
    int tper = (29 + nsplit - 1) / nsplit;
    int tb = sp * tper, te = min(29, tb + tper);
    int tid = threadIdx.x;
    int wv = tid >> 6, lane = tid & 63, quad = lane >> 4, l16 = lane & 15;
    { // qb_s[row] = Q_h[b,q,:] . la_b1_h   (8 lanes per row)
        int row = tid >> 3, sub = tid & 7;
        int hh = row >> 5, q = row & 31;
        const ushort_t* src = Qb + ((size_t)(b * 32 + q)) * 768 + hh * 384 + sub * 48;
        const float* bb = la_b1 + hh * 384 + sub * 48;
        float s = 0.f;
#pragma unroll
        for (int k = 0; k < 48; k++) s += b2f(src[k]) * bb[k];
        s += __shfl_xor(s, 1, 64); s += __shfl_xor(s, 2, 64); s += __shfl_xor(s, 4, 64);
        if (sub == 0) qb_s[row] = s;
    }
    if (tid < 64) { m_s[tid] = -1e30f; l_s[tid] = 0.f; }
    f32x4 zz4 = {0.f, 0.f, 0.f, 0.f};
    f32x4 acc[4][6];
#pragma unroll
    for (int mi = 0; mi < 4; mi++)
#pragma unroll
        for (int nj = 0; nj < 6; nj++) acc[mi][nj] = zz4;
    const float rs = 0.051031036307982884f; // 1/sqrt(384)
    int smi = wv & 3, sni = wv >> 2;
    __syncthreads();
    for (int t0 = tb; t0 < te; t0++) {
        int key0 = t0 * 32;
        { // stage x tile (fp32 global -> bf16 LDS), zero-fill past key 899
            int keyl = tid >> 4, dseg = tid & 15;
            int key = key0 + keyl;
            const float* src = img + ((long)b * 901 + 1 + key) * 768;
            bool ok = key < 900;
#pragma unroll
            for (int c = 0; c < 12; c++) {
                int dd = c * 64 + dseg * 4;
                float x0 = 0, x1 = 0, x2 = 0, x3 = 0;
                if (ok) { float4 v = *(const float4*)(src + dd); x0 = v.x; x1 = v.y; x2 = v.z; x3 = v.w; }
                ushort_t* dst = &xs[keyl][dd];
                dst[0] = f2b(x0); dst[1] = f2b(x1); dst[2] = f2b(x2); dst[3] = f2b(x3);
            }
        }
        __syncthreads();
        { // S = Qt @ x^T
            f32x4 as = zz4;
            const ushort_t* qrow = Qt + (long)(b * 64 + smi * 16 + l16) * 768 + quad * 8;
            const ushort_t* xrow = &xs[sni * 16 + l16][quad * 8];
#pragma unroll
            for (int kk = 0; kk < 768; kk += 32) {
                bf16x8 aq = *(const bf16x8*)(qrow + kk);
                bf16x8 bx = *(const bf16x8*)(xrow + kk);
                as = __builtin_amdgcn_mfma_f32_16x16x32_bf16(aq, bx, as, 0, 0, 0);
            }
#pragma unroll
            for (int r = 0; r < 4; r++) {
                int row = smi * 16 + quad * 4 + r;
                Sls[row][sni * 16 + l16] = (as[r] + qb_s[row]) * rs;
            }
        }
        __syncthreads();
        { // online softmax: 8 threads per row
            int row = tid >> 3, sub = tid & 7;
            float sv[4];
            float mx = -1e30f;
#pragma unroll
            for (int i = 0; i < 4; i++) {
                int kl = sub + i * 8;
                float s = (key0 + kl < 900) ? Sls[row][kl] : -1e30f;
                sv[i] = s; mx = fmaxf(mx, s);
            }
            mx = fmaxf(mx, __shfl_xor(mx, 1, 64));
            mx = fmaxf(mx, __shfl_xor(mx, 2, 64));
            mx = fmaxf(mx, __shfl_xor(mx, 4, 64));
            float mold = m_s[row];
            float mnew = fmaxf(mold, mx);
            float ss = 0.f;
#pragma unroll
            for (int i = 0; i < 4; i++) {
                float p = __expf(sv[i] - mnew);
                ss += p;
                Pls[row][sub + i * 8] = f2b(p);
            }
            ss += __shfl_xor(ss, 1, 64);
            ss += __shfl_xor(ss, 2, 64);
            ss += __shfl_xor(ss, 4, 64);
            if (sub == 0) {
                float alpha = __expf(mold - mnew);
                al_s[row] = alpha;
                l_s[row] = l_s[row] * alpha + ss;
                m_s[row] = mnew;
            }
        }
        __syncthreads();
        { // rescale + acc += P @ x
            bf16x8 pf[4];
#pragma unroll
            for (int mi = 0; mi < 4; mi++)
                pf[mi] = *(const bf16x8*)&Pls[mi * 16 + l16][quad * 8];
#pragma unroll
            for (int mi = 0; mi < 4; mi++) {
#pragma unroll
                for (int r = 0; r < 4; r++) {
                    float a = al_s[mi * 16 + quad * 4 + r];
#pragma unroll
                    for (int nj = 0; nj < 6; nj++) acc[mi][nj][r] *= a;
                }
            }
#pragma unroll
            for (int nj = 0; nj < 6; nj++) {
                int dd = wv * 96 + nj * 16 + l16;
                bf16x8 bx;
#pragma unroll
                for (int j = 0; j < 8; j++) bx[j] = (short)xs[quad * 8 + j][dd];
#pragma unroll
                for (int mi = 0; mi < 4; mi++)
                    acc[mi][nj] = __builtin_amdgcn_mfma_f32_16x16x32_bf16(pf[mi], bx, acc[mi][nj], 0, 0, 0);
            }
        }
        __syncthreads();
    }
    if (tid < 64) {
        pm[(b * nsplit + sp) * 64 + tid] = m_s[tid];
        pl[(b * nsplit + sp) * 64 + tid] = l_s[tid];
    }
#pragma unroll
    for (int mi = 0; mi < 4; mi++) {
#pragma unroll
        for (int r = 0; r < 4; r++) {
            int row = mi * 16 + quad * 4 + r;
            ushort_t* dst = pacc + ((size_t)(b * nsplit + sp) * 64 + row) * 768;
#pragma unroll
            for (int nj = 0; nj < 6; nj++)
                dst[wv * 96 + nj * 16 + l16] = f2b(acc[mi][nj][r]);
        }
    }
}

// ---------------- fused tail: combine+pool -> pc -> local_out -> f1 -> f2 -> f3 ----------------
// MR=8 tiles; grids per phase: 128, 96, 96, 128, 64, 128 (coop grid 128)

struct TailP {
    const float *pm, *pl; const ushort_t* pacc; const float* lp;
    const float *la_w2, *la_b2, *la_w3, *la_b3, *scal;
    float *plX, *pc, *hcat;
    const float *f1w, *f1b, *f2w, *f2b, *f3w, *f3b;
    float *x1, *x2, *out;
    int* flags; int p0, p1, nsplit;
};

template<int NS>
__global__ void __launch_bounds__(256) k_tail(TailP P) {
    __shared__ __align__(16) float As[8 * 1536];
    __shared__ float cw[4][32];
    int bid = blockIdx.x, tid = threadIdx.x;
    float sla = P.scal[1];
    for (int p = P.p0; p <= P.p1; p++) {
        if (p == 0) {
            int b = bid >> 1, half = bid & 1;
            if (tid < 32) {
                int row = half * 32 + tid;
                float ex[4];
                float mmax = -1e30f;
#pragma unroll
                for (int s = 0; s < NS; s++) mmax = fmaxf(mmax, P.pm[(b * NS + s) * 64 + row]);
                float lsum = 0.f;
#pragma unroll
                for (int s = 0; s < NS; s++) {
                    ex[s] = __expf(P.pm[(b * NS + s) * 64 + row] - mmax);
                    lsum += ex[s] * P.pl[(b * NS + s) * 64 + row];
                }
                float sc = P.lp[tid] / lsum;
#pragma unroll
                for (int s = 0; s < NS; s++) cw[s][tid] = ex[s] * sc;
            }
            __syncthreads();
            // ac[jj] = sum_q sum_s cw[s][q] * pacc[b,s,half*32+q, jj*256+tid]
            // batched 2 q x NS x 3 jj = <=24 independent loads in flight (no spill)
            const ushort_t* pp = P.pacc + (((size_t)(b * NS)) * 64 + half * 32) * 768 + tid;
            float ac[3] = {0.f, 0.f, 0.f};
            for (int q = 0; q < 32; q += 2) {
                float vv[2][NS][3];
#pragma unroll
                for (int u = 0; u < 2; u++)
#pragma unroll
                    for (int s = 0; s < NS; s++)
#pragma unroll
                        for (int jj = 0; jj < 3; jj++)
                            vv[u][s][jj] = b2f(pp[((size_t)(s * 64 + q + u)) * 768 + jj * 256]);
#pragma unroll
                for (int u = 0; u < 2; u++)
#pragma unroll
                    for (int s = 0; s < NS; s++) {
                        float w = cw[s][q + u];
#pragma unroll
                        for (int jj = 0; jj < 3; jj++) ac[jj] += w * vv[u][s][jj];
                    }
            }
#pragma unroll
            for (int jj = 0; jj < 3; jj++)
                __hip_atomic_store(&P.plX[b * 1536 + half * 768 + jj * 256 + tid], ac[jj],
                                   __ATOMIC_RELAXED, __HIP_MEMORY_SCOPE_AGENT);
        } else if (p == 1) {
            if (bid < 96) {
                int m4 = bid / 12, ct = bid % 12, prob = ct / 6;
                tgemm4<8>(P.plX + prob * 768, 1536, P.la_w2, 768, 0,
                          P.la_b2, 1.f, sla, nullptr, 0,
                          P.pc, 768, 768, 0, 1, m4 * 8, ct * 64, As, tid);
            }
        } else if (p == 2) {
            if (bid < 96) {
                int m4 = bid / 12, ct = bid % 12;
                tgemm4<8>(P.pc, 768, P.la_w3, 768, 0, P.la_b3, 1.f, sla, nullptr, 0,
                          P.hcat, 1536, 768, 0, 1, m4 * 8, ct * 64, As, tid);
            }
        } else if (p == 3) {
            if (bid < 128) {
                int m4 = bid / 16, ct = bid % 16;
                tgemm4<8>(P.hcat, 1536, P.f1w, 1024, 0, P.f1b, 1.f, 1.f, nullptr, 0,
                          P.x1, 1024, 1536, 0, 1, m4 * 8, ct * 64, As, tid);
            }
        } else if (p == 4) {
            if (bid < 64) {
                int m4 = bid / 8, ct = bid % 8;
                tgemm4<8>(P.x1, 1024, P.f2w, 512, 0, P.f2b, 1.f, 1.f, nullptr, 0,
                          P.x2, 512, 1024, 1, 1, m4 * 8, ct * 64, As, tid);
            }
        } else if (p == 5) {
            if (bid < 128) {
                int m4 = bid / 16, ct = bid % 16;
                tgemm4<8>(P.x2, 512, P.f3w, 1024, 0, P.f3b, 1.f, 1.f, nullptr, 0,
                          P.out, 1024, 512, 0, 0, m4 * 8, ct * 64, As, tid);
            }
        }
        if (p < P.p1) gbar(P.flags, 128, p + 1, bid, tid);
    }
}

// ---------------- host launcher ----------------

extern "C" void kernel_launch(void* const* d_in, const int* in_sizes, int n_in,
                              void* d_out, int out_size, void* d_ws, size_t ws_size,
                              hipStream_t stream)
{
    const float* img  = (const float*)d_in[1];
    const float* h0   = (const float*)d_in[2];
    const float* w_ih = (const float*)d_in[3];
    const float* w_hh = (const float*)d_in[4];
    const float* b_ih = (const float*)d_in[5];
    const float* b_hh = (const float*)d_in[6];
    const float* ga_w = (const float*)d_in[7];
    const float* ga_b = (const float*)d_in[8];
    const float* ga_pool = (const float*)d_in[9];
    const float* la_w = (const float*)d_in[10];
    const float* la_b = (const float*)d_in[11];
    const float* la_pool = (const float*)d_in[12];
    const float* go_w = (const float*)d_in[13];
    const float* go_b = (const float*)d_in[14];
    const float* go_pool = (const float*)d_in[15];
    const float* f1w = (const float*)d_in[16];
    const float* f1b = (const float*)d_in[17];
    const float* f2w = (const float*)d_in[18];
    const float* f2b_ = (const float*)d_in[19];
    const float* f3w = (const float*)d_in[20];
    const float* f3b = (const float*)d_in[21];
    float* out = (float*)d_out;
    (void)in_sizes; (void)n_in; (void)out_size;

    int nsplit = (ws_size >= (size_t)43 * 1024 * 1024) ? 4 : 2;

    char* w = (char*)d_ws;
    auto alloc = [&](size_t bytes) -> char* {
        char* p = w; w += (bytes + 255) & ~(size_t)255; return p;
    };
    // persistent region
    float*    scal  = (float*)alloc(256);                 // [0]=S_go [1]=S_la
    int*      bar   = (int*)alloc(4096);                  // [0..63]=GRU [64..319]=head [320..447]=tail
    ushort_t* law0b = (ushort_t*)alloc((size_t)768 * 768 * 2);
    ushort_t* law1b = (ushort_t*)alloc((size_t)768 * 768 * 2);
    ushort_t* h0b   = (ushort_t*)alloc((size_t)64 * 768 * 2);
    ushort_t* qembb = (ushort_t*)alloc((size_t)2048 * 768 * 2);
    ushort_t* Qb    = (ushort_t*)alloc((size_t)2048 * 768 * 2);
    ushort_t* Qtb   = (ushort_t*)alloc((size_t)4096 * 768 * 2);
    float*    pm    = (float*)alloc((size_t)64 * 4 * 64 * 4);
    float*    pl    = (float*)alloc((size_t)64 * 4 * 64 * 4);
    float*    plX   = (float*)alloc((size_t)64 * 1536 * 4);
    float*    pc    = (float*)alloc((size_t)64 * 768 * 4);
    float*    hcat  = (float*)alloc((size_t)64 * 1536 * 4);
    float*    x1    = (float*)alloc((size_t)64 * 1024 * 4);
    float*    x2    = (float*)alloc((size_t)64 * 512 * 4);
    // union region: [GRU-phase temporaries] overlaid with [flash pacc]
    char* uni = w;
    char* u = uni;
    auto ualloc = [&](size_t bytes) -> char* {
        char* p = u; u += (bytes + 255) & ~(size_t)255; return p;
    };
    ushort_t* whhb  = (ushort_t*)ualloc((size_t)2304 * 768 * 2);
    float*    t12   = (float*)ualloc((size_t)2 * 64 * 768 * 4);
    float*    avec  = (float*)ualloc((size_t)64 * 768 * 4);
    float*    base  = (float*)ualloc((size_t)64 * 2304 * 4);
    float*    hbuf  = (float*)ualloc((size_t)64 * 768 * 4);
    ushort_t* pacc  = (ushort_t*)uni;   // overlays GRU temporaries; used only after GRU done
    float*    t12g  = t12 + 64 * 768;

    const float* ga_w2 = ga_w + 2 * 768 * 768; const float* ga_w3 = ga_w + 3 * 768 * 768;
    const float* ga_b2 = ga_b + 2 * 768;       const float* ga_b3 = ga_b + 3 * 768;
    const float* go_w2 = go_w + 2 * 768 * 768; const float* go_w3 = go_w + 3 * 768 * 768;
    const float* go_b2 = go_b + 2 * 768;       const float* go_b3 = go_b + 3 * 768;
    const float* la_w0 = la_w;                 const float* la_w1 = la_w + 768 * 768;
    const float* la_w2 = la_w + 2 * 768 * 768; const float* la_w3 = la_w + 3 * 768 * 768;
    const float* la_b0 = la_b;                 const float* la_b1 = la_b + 768;
    const float* la_b2 = la_b + 2 * 768;       const float* la_b3 = la_b + 3 * 768;

    dim3 blk(256);
    k_cvt_all<<<11712, blk, 0, stream>>>(w_hh, la_w0, la_w1, h0, go_pool, la_pool,
                                         whhb, law0b, law1b, h0b, hbuf, scal, bar);

    // fused head (coop; fallback: per-phase launches)
    {
        HeadP P;
        P.img = img; P.ga_w2 = ga_w2; P.ga_b2 = ga_b2; P.go_w2 = go_w2; P.go_b2 = go_b2;
        P.ga_w3 = ga_w3; P.ga_b3 = ga_b3; P.go_w3 = go_w3; P.go_b3 = go_b3;
        P.ga_pool = ga_pool; P.scal = scal; P.w_ih = w_ih; P.b_ih = b_ih; P.b_hh = b_hh;
        P.t12 = t12; P.t12g = t12g; P.avec = avec; P.hcat = hcat; P.base = base;
        P.flags = bar + 64; P.p0 = 1; P.p1 = 3;
        void* args[1] = { &P };
        hipError_t e = hipLaunchCooperativeKernel((void*)k_head, dim3(144), blk, args, 0, stream);
        if (e != hipSuccess)
            for (int p = 1; p <= 3; p++) { P.p0 = P.p1 = p; k_head<<<144, blk, 0, stream>>>(P); }
    }

    // GRU scan (coop; fallback: 32 step launches)
    {
        GruP P;
        P.h0b = h0b; P.h0f = h0; P.whh = whhb; P.base = base; P.bhh = b_hh;
        P.qemb = qembb; P.flags = bar;
        void* args[1] = { &P };
        hipError_t e = hipLaunchCooperativeKernel((void*)k_gru_coop, dim3(GRU_NB), dim3(192),
                                                  args, 0, stream);
        if (e != hipSuccess)
            for (int t = 0; t < 32; t++)
                k_gru_step<<<12, blk, 0, stream>>>(t, h0b, whhb, base, b_hh, hbuf, qembb);
    }

    // Q = q_emb @ la_w0 + la_b0 ; Qt_h = Q_h @ W1_h^T (folded-K trick)
    k_gemm_bf16<<<dim3(12, 32), blk, 0, stream>>>(qembb, 768, law0b, 768, 0, la_b0, Qb, 768, 768, 0, 0);
    k_gemm_bf16<<<dim3(12, 32), blk, 0, stream>>>(Qb, 768, law1b, 768, 1, nullptr, Qtb, 768, 384, 1, 0);
    k_gemm_bf16<<<dim3(12, 32), blk, 0, stream>>>(Qb + 384, 768, law1b + 384, 768, 1, nullptr, Qtb, 768, 384, 1, 32);

    // flash attention, key-split
    k_flash<<<dim3(64, nsplit), dim3(512), 0, stream>>>(img, Qtb, Qb, la_b1, pm, pl, pacc, nsplit);

    // fused tail (coop; fallback: per-phase launches)
    {
        TailP P;
        P.pm = pm; P.pl = pl; P.pacc = pacc; P.lp = la_pool;
        P.la_w2 = la_w2; P.la_b2 = la_b2; P.la_w3 = la_w3; P.la_b3 = la_b3; P.scal = scal;
        P.plX = plX; P.pc = pc; P.hcat = hcat;
        P.f1w = f1w; P.f1b = f1b; P.f2w = f2w; P.f2b = f2b_; P.f3w = f3w; P.f3b = f3b;
        P.x1 = x1; P.x2 = x2; P.out = out;
        P.flags = bar + 320; P.p0 = 0; P.p1 = 5; P.nsplit = nsplit;
        void* args[1] = { &P };
        if (nsplit == 4) {
            hipError_t e = hipLaunchCooperativeKernel((void*)k_tail<4>, dim3(128), blk, args, 0, stream);
            if (e != hipSuccess)
                for (int p = 0; p <= 5; p++) { P.p0 = P.p1 = p; k_tail<4><<<128, blk, 0, stream>>>(P); }
        } else {
            hipError_t e = hipLaunchCooperativeKernel((void*)k_tail<2>, dim3(128), blk, args, 0, stream);
            if (e != hipSuccess)
                for (int p = 0; p <= 5; p++) { P.p0 = P.p1 = p; k_tail<2><<<128, blk, 0, stream>>>(P); }
        }
    }
}

// Round 5
// 1146.773 us; speedup vs baseline: 1.5149x; 1.1692x over previous
//
#include <hip/hip_runtime.h>
#include <math.h>

// B=64, T=32, D=768, NH=2, dk=384, N=901 (1 cls + 900 local)

typedef short bf16x8 __attribute__((ext_vector_type(8)));
typedef float f32x4 __attribute__((ext_vector_type(4)));
typedef unsigned short ushort_t;

#define GRU_NB 48

__device__ __forceinline__ unsigned short f2b(float f) {
    unsigned int u = __float_as_uint(f);
    unsigned int r = (u + 0x7FFFu + ((u >> 16) & 1u)) >> 16;
    return (unsigned short)r;
}
__device__ __forceinline__ float b2f(unsigned short s) {
    return __uint_as_float(((unsigned int)s) << 16);
}
__device__ __forceinline__ float sigm(float x) { return 1.f / (1.f + __expf(-x)); }
__device__ __forceinline__ float tanhx(float x) {
    x = fminf(fmaxf(x, -15.f), 15.f);
    float e = __expf(2.f * x);
    return (e - 1.f) / (e + 1.f);
}

// flag barrier: arrival = agent store of monotonically-increasing phase id; poll =
// parallel relaxed agent loads (no RMW contention). Data written before the barrier
// must use agent-scope stores (bypass L2 -> L3) so readers' plain loads (fresh lines)
// see it. flags zeroed by k_cvt_all each launch.
__device__ __forceinline__ void gbar(int* flags, int nb, int phase, int bid, int tid) {
    __syncthreads();   // drains each wave's vmcnt -> agent stores are in L3
    if (tid == 0) __hip_atomic_store(&flags[bid], phase, __ATOMIC_RELAXED, __HIP_MEMORY_SCOPE_AGENT);
    if (tid < 64) {
        for (;;) {
            int v = 0x7fffffff;
            for (int f = tid; f < nb; f += 64)
                v = min(v, __hip_atomic_load(&flags[f], __ATOMIC_RELAXED, __HIP_MEMORY_SCOPE_AGENT));
            if (__all(v >= phase)) break;
            __builtin_amdgcn_s_sleep(1);
        }
    }
    __syncthreads();
}

// ---------------- setup: convert weights to bf16, pool sums, zero flags ----------------

__global__ void k_cvt_all(const float* __restrict__ whh, const float* __restrict__ la0,
                          const float* __restrict__ la1, const float* __restrict__ h0,
                          const float* __restrict__ gp, const float* __restrict__ lp,
                          ushort_t* __restrict__ whhb, ushort_t* __restrict__ law0b,
                          ushort_t* __restrict__ law1b, ushort_t* __restrict__ h0b,
                          float* __restrict__ hbuf, float* __restrict__ scal,
                          int* __restrict__ bar) {
    if (blockIdx.x == 0) {
        int t = threadIdx.x;
        if (t < 64) {
            float v1 = (t < 32) ? gp[t] : 0.f;
            float v2 = (t < 32) ? lp[t] : 0.f;
#pragma unroll
            for (int m = 1; m < 32; m <<= 1) { v1 += __shfl_xor(v1, m, 64); v2 += __shfl_xor(v2, m, 64); }
            if (t == 0) { scal[0] = v1; scal[1] = v2; }
        }
        for (int i = threadIdx.x; i < 1024; i += 256) bar[i] = 0;
    }
    long i = (long)blockIdx.x * 256 + threadIdx.x;
    const long n1 = 2304L * 768, n2 = n1 + 768L * 768, n3 = n2 + 768L * 768, n4 = n3 + 64L * 768;
    if (i < n1) whhb[i] = f2b(whh[i]);
    else if (i < n2) law0b[i - n1] = f2b(la0[i - n1]);
    else if (i < n3) law1b[i - n2] = f2b(la1[i - n2]);
    else if (i < n4) { float v = h0[i - n3]; h0b[i - n3] = f2b(v); hbuf[i - n3] = v; }
}

// ---------------- parallel fp32 tile GEMM: MR rows x 64 cols per block ----------------
// 256 threads = 64 cols x 4 K-chunks; each thread accumulates its K/4 chunk with 8
// independent B-loads in flight; cross-chunk reduction through LDS (aliased onto the
// dead A-tile). out = acc*s1 + bias[c]*s2 (+ bias2[c] if c<b2lim); optional relu,
// optional agent-scope store. Register-light by design (acc[MR]+bv[8]): no spill.

template<int MR>
__device__ __forceinline__ void tgemm4(
    const float* __restrict__ A, long lda,
    const float* __restrict__ Bm, int ldb, int transB,
    const float* __restrict__ bias, float s1, float s2,
    const float* __restrict__ bias2, int b2lim,
    float* __restrict__ C, int ldc, int K, int relu, int agent,
    int m0, int n0, float* As, int tid)
{
    for (int r = 0; r < MR; r++)
        for (int k = tid; k < K; k += 256)
            As[r * K + k] = A[(long)(m0 + r) * lda + k];
    __syncthreads();
    int cl = tid & 63, kc = tid >> 6;
    int c = n0 + cl;
    int K4 = K >> 2;
    int kb = kc * K4;
    const float* Bp = transB ? (Bm + (long)c * ldb) : (Bm + c);
    float acc[MR];
#pragma unroll
    for (int r = 0; r < MR; r++) acc[r] = 0.f;
    for (int k = kb; k < kb + K4; k += 8) {
        float bv[8];
        if (!transB) {
#pragma unroll
            for (int i = 0; i < 8; i++) bv[i] = Bp[(long)(k + i) * ldb];
        } else {
            float4 q0 = *(const float4*)(Bp + k);
            float4 q1 = *(const float4*)(Bp + k + 4);
            bv[0] = q0.x; bv[1] = q0.y; bv[2] = q0.z; bv[3] = q0.w;
            bv[4] = q1.x; bv[5] = q1.y; bv[6] = q1.z; bv[7] = q1.w;
        }
#pragma unroll
        for (int i = 0; i < 8; i += 4) {
#pragma unroll
            for (int r = 0; r < MR; r++) {
                float4 x = *(const float4*)&As[r * K + k + i];
                acc[r] += x.x * bv[i] + x.y * bv[i + 1] + x.z * bv[i + 2] + x.w * bv[i + 3];
            }
        }
    }
    __syncthreads();           // all As reads done -> safe to alias
    float* Red = As;           // 4*MR*64 floats <= MR*K (K>=256)
#pragma unroll
    for (int r = 0; r < MR; r++) Red[(kc * MR + r) * 64 + cl] = acc[r];
    __syncthreads();
    {
        int rg = tid >> 6;
        float bb = (bias ? bias[c] * s2 : 0.f) + ((bias2 && c < b2lim) ? bias2[c] : 0.f);
#pragma unroll
        for (int i = 0; i < MR / 4; i++) {
            int r = rg + i * 4;
            float sum = (Red[(0 * MR + r) * 64 + cl] + Red[(1 * MR + r) * 64 + cl])
                      + (Red[(2 * MR + r) * 64 + cl] + Red[(3 * MR + r) * 64 + cl]);
            float o = sum * s1 + bb;
            if (relu) o = fmaxf(o, 0.f);
            if (agent) __hip_atomic_store(&C[(long)(m0 + r) * ldc + c], o,
                                          __ATOMIC_RELAXED, __HIP_MEMORY_SCOPE_AGENT);
            else C[(long)(m0 + r) * ldc + c] = o;
        }
    }
}

// ---------------- fused head: t12/t12g -> avec/global_out -> base (3 phases) ----------------
// grid 192: p1/p2 = 2x8x12 = 192 blocks (MR=8), p3 = 4x36 = 144 blocks (MR=16)

struct HeadP {
    const float *img, *ga_w2, *ga_b2, *go_w2, *go_b2;
    const float *ga_w3, *ga_b3, *go_w3, *go_b3;
    const float *ga_pool, *scal, *w_ih, *b_ih, *b_hh;
    float *t12, *t12g, *avec, *hcat, *base;
    int* flags; int p0, p1;
};

__global__ void __launch_bounds__(256) k_head(HeadP P) {
    __shared__ __align__(16) float As[16 * 768];
    int bid = blockIdx.x, tid = threadIdx.x;
    for (int p = P.p0; p <= P.p1; p++) {
        if (p == 1) {
            if (bid < 192) {
                int prob = bid / 96, r = bid % 96, m8 = r / 12, ct = r % 12;
                tgemm4<8>(P.img, 901L * 768, prob ? P.go_w2 : P.ga_w2, 768, 0,
                          prob ? P.go_b2 : P.ga_b2, 1.f, 1.f, nullptr, 0,
                          prob ? P.t12g : P.t12, 768, 768, 0, 1, m8 * 8, ct * 64, As, tid);
            }
        } else if (p == 2) {
            if (bid < 192) {
                int prob = bid / 96, r = bid % 96, m8 = r / 12, ct = r % 12;
                float sc = prob ? P.scal[0] : P.ga_pool[0];
                tgemm4<8>(prob ? P.t12g : P.t12, 768, prob ? P.go_w3 : P.ga_w3, 768, 0,
                          prob ? P.go_b3 : P.ga_b3, sc, sc, nullptr, 0,
                          prob ? (P.hcat + 768) : P.avec, prob ? 1536 : 768, 768, 0, 1,
                          m8 * 8, ct * 64, As, tid);
            }
        } else if (p == 3) {
            if (bid < 144) {
                int m4 = bid / 36, ct = bid % 36;
                // base = avec @ w_ih^T + b_ih (+ b_hh for first 1536 cols)
                tgemm4<16>(P.avec, 768, P.w_ih, 768, 1, P.b_ih, 1.f, 1.f, P.b_hh, 1536,
                           P.base, 2304, 768, 0, 0, m4 * 16, ct * 64, As, tid);
            }
        }
        if (p < P.p1) gbar(P.flags, 192, p, bid, tid);
    }
}

// ---------------- GRU scan: 48 blocks x 192 thr, whh/base/h in LDS, flag barrier ----------------

struct GruP {
    const ushort_t* h0b; const float* h0f; const ushort_t* whh;
    const float* base; const float* bhh; ushort_t* qemb; int* flags;
};

__global__ void __launch_bounds__(192) k_gru_coop(GruP P) {
    __shared__ __align__(16) ushort_t whh_s[3][16][776];
    __shared__ float gs[3][64][20];
    __shared__ float bs[3][64][20];
    __shared__ float h_s[64][20];
    __shared__ float bhh_s[16];
    int tid = threadIdx.x;
    int g = tid >> 6, lane = tid & 63, quad = lane >> 4, l16 = lane & 15;
    int j = blockIdx.x, d0 = j * 16;
    for (int r = 0; r < 16; r++)
        for (int kk = lane * 8; kk < 768; kk += 512)
            *(bf16x8*)&whh_s[g][r][kk] = *(const bf16x8*)&P.whh[(size_t)(g * 768 + d0 + r) * 768 + kk];
    for (int e = tid; e < 3072; e += 192) {
        int g2 = e >> 10, rem = e & 1023, b = rem >> 4, c = rem & 15;
        bs[g2][b][c] = P.base[b * 2304 + g2 * 768 + d0 + c];
    }
    for (int e = tid; e < 1024; e += 192) {
        int b = e >> 4, c = e & 15;
        h_s[b][c] = P.h0f[b * 768 + d0 + c];
    }
    if (tid < 16) bhh_s[tid] = P.bhh[1536 + d0 + tid];
    __syncthreads();
    for (int t = 0; t < 32; t++) {
        const ushort_t* Ap = (t == 0) ? P.h0b : (P.qemb + (size_t)(t - 1) * 768);
        size_t ldA = (t == 0) ? 768 : (size_t)32 * 768;
        f32x4 zz4 = {0.f, 0.f, 0.f, 0.f};
        f32x4 acc[4];
#pragma unroll
        for (int mi = 0; mi < 4; mi++) acc[mi] = zz4;
        for (int kk = 0; kk < 768; kk += 32) {
            bf16x8 bfr = *(const bf16x8*)&whh_s[g][l16][kk + quad * 8];
#pragma unroll
            for (int mi = 0; mi < 4; mi++) {
                bf16x8 af = *(const bf16x8*)(Ap + (size_t)(mi * 16 + l16) * ldA + kk + quad * 8);
                acc[mi] = __builtin_amdgcn_mfma_f32_16x16x32_bf16(af, bfr, acc[mi], 0, 0, 0);
            }
        }
#pragma unroll
        for (int mi = 0; mi < 4; mi++)
#pragma unroll
            for (int r = 0; r < 4; r++)
                gs[g][mi * 16 + quad * 4 + r][l16] = acc[mi][r];
        __syncthreads();
        for (int e = tid; e < 512; e += 192) {
            int b = e >> 3, c0 = (e & 7) * 2;
            float hn[2];
#pragma unroll
            for (int u = 0; u < 2; u++) {
                int c = c0 + u;
                float rr = sigm(gs[0][b][c] + bs[0][b][c]);
                float zg = sigm(gs[1][b][c] + bs[1][b][c]);
                float nn = tanhx(bs[2][b][c] + rr * (gs[2][b][c] + bhh_s[c]));
                float hv = h_s[b][c];
                hn[u] = (1.f - zg) * nn + zg * hv;
                h_s[b][c] = hn[u];
            }
            unsigned int pk = (unsigned int)f2b(hn[0]) | ((unsigned int)f2b(hn[1]) << 16);
            __hip_atomic_store((unsigned int*)&P.qemb[((size_t)b * 32 + t) * 768 + d0 + c0],
                               pk, __ATOMIC_RELAXED, __HIP_MEMORY_SCOPE_AGENT);
        }
        __syncthreads();   // drain agent stores to L3 before flag
        if (t < 31) {
            if (tid == 0)
                __hip_atomic_store(&P.flags[j], t + 1, __ATOMIC_RELAXED, __HIP_MEMORY_SCOPE_AGENT);
            if (tid < 64) {
                for (;;) {
                    int v = (tid < GRU_NB)
                        ? __hip_atomic_load(&P.flags[tid], __ATOMIC_RELAXED, __HIP_MEMORY_SCOPE_AGENT)
                        : 0x7fffffff;
                    if (__all(v > t)) break;
                    __builtin_amdgcn_s_sleep(1);
                }
            }
            __syncthreads();
        }
    }
}

// fallback (non-coop): 32 per-step launches
__global__ void __launch_bounds__(256) k_gru_step(
    int t, const ushort_t* h0b, const ushort_t* whh, const float* base,
    const float* bhh, float* h, ushort_t* qemb)
{
    int wv = threadIdx.x >> 6, lane = threadIdx.x & 63;
    int quad = lane >> 4, l16 = lane & 15;
    int d0 = blockIdx.x * 64 + wv * 16;
    float bhhn = bhh[1536 + d0 + l16];
    const ushort_t* Ap = (t == 0) ? h0b : (qemb + (long)(t - 1) * 768);
    long ldA = (t == 0) ? 768 : 32 * 768;
    int d = d0 + l16;
    f32x4 zz4 = {0.f, 0.f, 0.f, 0.f};
    f32x4 acc[3][4];
#pragma unroll
    for (int g = 0; g < 3; g++)
#pragma unroll
        for (int mi = 0; mi < 4; mi++) acc[g][mi] = zz4;
    for (int kk = 0; kk < 768; kk += 32) {
        bf16x8 af[4];
#pragma unroll
        for (int mi = 0; mi < 4; mi++)
            af[mi] = *(const bf16x8*)(Ap + (long)(mi * 16 + l16) * ldA + kk + quad * 8);
#pragma unroll
        for (int g = 0; g < 3; g++) {
            bf16x8 bfr = *(const bf16x8*)(whh + (long)(g * 768 + d0 + l16) * 768 + kk + quad * 8);
#pragma unroll
            for (int mi = 0; mi < 4; mi++)
                acc[g][mi] = __builtin_amdgcn_mfma_f32_16x16x32_bf16(af[mi], bfr, acc[g][mi], 0, 0, 0);
        }
    }
#pragma unroll
    for (int mi = 0; mi < 4; mi++) {
#pragma unroll
        for (int r = 0; r < 4; r++) {
            int b = mi * 16 + quad * 4 + r;
            const float* bb = base + b * 2304;
            float rr = sigm(acc[0][mi][r] + bb[d]);
            float zg = sigm(acc[1][mi][r] + bb[768 + d]);
            float nn = tanhx(bb[1536 + d] + rr * (acc[2][mi][r] + bhhn));
            float hv = h[b * 768 + d];
            float hnew = (1.f - zg) * nn + zg * hv;
            h[b * 768 + d] = hnew;
            qemb[(long)(b * 32 + t) * 768 + d] = f2b(hnew);
        }
    }
}

// ---------------- generic bf16 MFMA GEMM (64x64 tile) ----------------

__global__ void __launch_bounds__(256) k_gemm_bf16(
    const ushort_t* __restrict__ A, int lda,
    const ushort_t* __restrict__ B, int ldb, int transB,
    const float* __restrict__ bias,
    ushort_t* __restrict__ Cb, int ldc,
    int K, int remap, int rowoff)
{
    __shared__ __align__(16) ushort_t As[64][72];
    __shared__ __align__(16) ushort_t Bs[64][72];
    int tid = threadIdx.x;
    int wv = tid >> 6, lane = tid & 63, quad = lane >> 4, l16 = lane & 15;
    long bm = (long)blockIdx.y * 64, bn = (long)blockIdx.x * 64;
    f32x4 zz4 = {0.f, 0.f, 0.f, 0.f};
    f32x4 acc[4];
#pragma unroll
    for (int mi = 0; mi < 4; mi++) acc[mi] = zz4;
    int row4 = tid >> 2, seg = tid & 3;
    for (int k0 = 0; k0 < K; k0 += 64) {
        {
            const ushort_t* src = A + (bm + row4) * lda + k0 + seg * 16;
            *(bf16x8*)&As[row4][seg * 16] = *(const bf16x8*)src;
            *(bf16x8*)&As[row4][seg * 16 + 8] = *(const bf16x8*)(src + 8);
        }
        if (transB) {
            const ushort_t* src = B + (bn + row4) * ldb + k0 + seg * 16;
            *(bf16x8*)&Bs[row4][seg * 16] = *(const bf16x8*)src;
            *(bf16x8*)&Bs[row4][seg * 16 + 8] = *(const bf16x8*)(src + 8);
        } else {
            const ushort_t* src = B + (long)(k0 + row4) * ldb + bn + seg * 16;
            bf16x8 v0 = *(const bf16x8*)src;
            bf16x8 v1 = *(const bf16x8*)(src + 8);
#pragma unroll
            for (int i = 0; i < 8; i++) {
                Bs[seg * 16 + i][row4] = (ushort_t)v0[i];
                Bs[seg * 16 + 8 + i][row4] = (ushort_t)v1[i];
            }
        }
        __syncthreads();
#pragma unroll
        for (int ks = 0; ks < 64; ks += 32) {
            bf16x8 bfr = *(const bf16x8*)&Bs[wv * 16 + l16][ks + quad * 8];
#pragma unroll
            for (int mi = 0; mi < 4; mi++) {
                bf16x8 af = *(const bf16x8*)&As[mi * 16 + l16][ks + quad * 8];
                acc[mi] = __builtin_amdgcn_mfma_f32_16x16x32_bf16(af, bfr, acc[mi], 0, 0, 0);
            }
        }
        __syncthreads();
    }
    int ncol = (int)bn + wv * 16 + l16;
    float bv = bias ? bias[ncol] : 0.f;
#pragma unroll
    for (int mi = 0; mi < 4; mi++) {
#pragma unroll
        for (int r = 0; r < 4; r++) {
            long row = bm + mi * 16 + quad * 4 + r;
            long orow = remap ? ((row >> 5) * 64 + rowoff + (row & 31)) : row;
            Cb[orow * ldc + ncol] = f2b(acc[mi][r] + bv);
        }
    }
}

// ---------------- fused flash attention, key-split partials (qb folded in) ----------------

__global__ void __launch_bounds__(512) k_flash(
    const float* __restrict__ img, const ushort_t* __restrict__ Qt,
    const ushort_t* __restrict__ Qb, const float* __restrict__ la_b1,
    float* __restrict__ pm, float* __restrict__ pl,
    ushort_t* __restrict__ pacc, int nsplit)
{
    __shared__ __align__(16) ushort_t xs[32][776];
    __shared__ float Sls[64][36];
    __shared__ __align__(16) ushort_t Pls[64][40];
    __shared__ float m_s[64], l_s[64], al_s[64], qb_s[64];
    int b = blockIdx.x;
    int sp = blockIdx.y;
    int tper = (29 + nsplit - 1) / nsplit;
    int tb = sp * tper, te = min(29, tb + tper);
    int tid = threadIdx.x;
    int wv = tid >> 6, lane = tid & 63, quad = lane >> 4, l16 = lane & 15;
    { // qb_s[row] = Q_h[b,q,:] . la_b1_h   (8 lanes per row)
        int row = tid >> 3, sub = tid & 7;
        int hh = row >> 5, q = row & 31;
        const ushort_t* src = Qb + ((size_t)(b * 32 + q)) * 768 + hh * 384 + sub * 48;
        const float* bb = la_b1 + hh * 384 + sub * 48;
        float s = 0.f;
#pragma unroll
        for (int k = 0; k < 48; k++) s += b2f(src[k]) * bb[k];
        s += __shfl_xor(s, 1, 64); s += __shfl_xor(s, 2, 64); s += __shfl_xor(s, 4, 64);
        if (sub == 0) qb_s[row] = s;
    }
    if (tid < 64) { m_s[tid] = -1e30f; l_s[tid] = 0.f; }
    f32x4 zz4 = {0.f, 0.f, 0.f, 0.f};
    f32x4 acc[4][6];
#pragma unroll
    for (int mi = 0; mi < 4; mi++)
#pragma unroll
        for (int nj = 0; nj < 6; nj++) acc[mi][nj] = zz4;
    const float rs = 0.051031036307982884f; // 1/sqrt(384)
    int smi = wv & 3, sni = wv >> 2;
    __syncthreads();
    for (int t0 = tb; t0 < te; t0++) {
        int key0 = t0 * 32;
        { // stage x tile (fp32 global -> bf16 LDS), zero-fill past key 899
            int keyl = tid >> 4, dseg = tid & 15;
            int key = key0 + keyl;
            const float* src = img + ((long)b * 901 + 1 + key) * 768;
            bool ok = key < 900;
#pragma unroll
            for (int c = 0; c < 12; c++) {
                int dd = c * 64 + dseg * 4;
                float x0 = 0, x1 = 0, x2 = 0, x3 = 0;
                if (ok) { float4 v = *(const float4*)(src + dd); x0 = v.x; x1 = v.y; x2 = v.z; x3 = v.w; }
                ushort_t* dst = &xs[keyl][dd];
                dst[0] = f2b(x0); dst[1] = f2b(x1); dst[2] = f2b(x2); dst[3] = f2b(x3);
            }
        }
        __syncthreads();
        { // S = Qt @ x^T
            f32x4 as = zz4;
            const ushort_t* qrow = Qt + (long)(b * 64 + smi * 16 + l16) * 768 + quad * 8;
            const ushort_t* xrow = &xs[sni * 16 + l16][quad * 8];
#pragma unroll
            for (int kk = 0; kk < 768; kk += 32) {
                bf16x8 aq = *(const bf16x8*)(qrow + kk);
                bf16x8 bx = *(const bf16x8*)(xrow + kk);
                as = __builtin_amdgcn_mfma_f32_16x16x32_bf16(aq, bx, as, 0, 0, 0);
            }
#pragma unroll
            for (int r = 0; r < 4; r++) {
                int row = smi * 16 + quad * 4 + r;
                Sls[row][sni * 16 + l16] = (as[r] + qb_s[row]) * rs;
            }
        }
        __syncthreads();
        { // online softmax: 8 threads per row
            int row = tid >> 3, sub = tid & 7;
            float sv[4];
            float mx = -1e30f;
#pragma unroll
            for (int i = 0; i < 4; i++) {
                int kl = sub + i * 8;
                float s = (key0 + kl < 900) ? Sls[row][kl] : -1e30f;
                sv[i] = s; mx = fmaxf(mx, s);
            }
            mx = fmaxf(mx, __shfl_xor(mx, 1, 64));
            mx = fmaxf(mx, __shfl_xor(mx, 2, 64));
            mx = fmaxf(mx, __shfl_xor(mx, 4, 64));
            float mold = m_s[row];
            float mnew = fmaxf(mold, mx);
            float ss = 0.f;
#pragma unroll
            for (int i = 0; i < 4; i++) {
                float p = __expf(sv[i] - mnew);
                ss += p;
                Pls[row][sub + i * 8] = f2b(p);
            }
            ss += __shfl_xor(ss, 1, 64);
            ss += __shfl_xor(ss, 2, 64);
            ss += __shfl_xor(ss, 4, 64);
            if (sub == 0) {
                float alpha = __expf(mold - mnew);
                al_s[row] = alpha;
                l_s[row] = l_s[row] * alpha + ss;
                m_s[row] = mnew;
            }
        }
        __syncthreads();
        { // rescale + acc += P @ x
            bf16x8 pf[4];
#pragma unroll
            for (int mi = 0; mi < 4; mi++)
                pf[mi] = *(const bf16x8*)&Pls[mi * 16 + l16][quad * 8];
#pragma unroll
            for (int mi = 0; mi < 4; mi++) {
#pragma unroll
                for (int r = 0; r < 4; r++) {
                    float a = al_s[mi * 16 + quad * 4 + r];
#pragma unroll
                    for (int nj = 0; nj < 6; nj++) acc[mi][nj][r] *= a;
                }
            }
#pragma unroll
            for (int nj = 0; nj < 6; nj++) {
                int dd = wv * 96 + nj * 16 + l16;
                bf16x8 bx;
#pragma unroll
                for (int j = 0; j < 8; j++) bx[j] = (short)xs[quad * 8 + j][dd];
#pragma unroll
                for (int mi = 0; mi < 4; mi++)
                    acc[mi][nj] = __builtin_amdgcn_mfma_f32_16x16x32_bf16(pf[mi], bx, acc[mi][nj], 0, 0, 0);
            }
        }
        __syncthreads();
    }
    if (tid < 64) {
        pm[(b * nsplit + sp) * 64 + tid] = m_s[tid];
        pl[(b * nsplit + sp) * 64 + tid] = l_s[tid];
    }
#pragma unroll
    for (int mi = 0; mi < 4; mi++) {
#pragma unroll
        for (int r = 0; r < 4; r++) {
            int row = mi * 16 + quad * 4 + r;
            ushort_t* dst = pacc + ((size_t)(b * nsplit + sp) * 64 + row) * 768;
#pragma unroll
            for (int nj = 0; nj < 6; nj++)
                dst[wv * 96 + nj * 16 + l16] = f2b(acc[mi][nj][r]);
        }
    }
}

// ---------------- fused tail: combine+pool -> pc -> local_out -> f1 -> f2 -> f3 ----------------
// grid 256; phases: p0 192 (64b x 3 col-chunks, both halves), p1/p2 192 (MR=4),
// p3 256, p4 128, p5 256

struct TailP {
    const float *pm, *pl; const ushort_t* pacc; const float* lp;
    const float *la_w2, *la_b2, *la_w3, *la_b3, *scal;
    float *plX, *pc, *hcat;
    const float *f1w, *f1b, *f2w, *f2b, *f3w, *f3b;
    float *x1, *x2, *out;
    int* flags; int p0, p1, nsplit;
};

template<int NS>
__global__ void __launch_bounds__(256) k_tail(TailP P) {
    __shared__ __align__(16) float As[4 * 1536];
    __shared__ float cw[NS][64];
    int bid = blockIdx.x, tid = threadIdx.x;
    float sla = P.scal[1];
    for (int p = P.p0; p <= P.p1; p++) {
        if (p == 0) {
            // 192 blocks = 64 batches x 3 col-chunks of 256; each thread handles one
            // column for BOTH row-halves: <=16 independent loads in flight, no spill.
            if (bid < 192) {
                int b = bid / 3, jj = bid % 3;
                if (tid < 64) {
                    int row = tid;
                    float ex[NS];
                    float mmax = -1e30f;
#pragma unroll
                    for (int s = 0; s < NS; s++) mmax = fmaxf(mmax, P.pm[(b * NS + s) * 64 + row]);
                    float lsum = 0.f;
#pragma unroll
                    for (int s = 0; s < NS; s++) {
                        ex[s] = __expf(P.pm[(b * NS + s) * 64 + row] - mmax);
                        lsum += ex[s] * P.pl[(b * NS + s) * 64 + row];
                    }
                    float sc = P.lp[row & 31] / lsum;
#pragma unroll
                    for (int s = 0; s < NS; s++) cw[s][row] = ex[s] * sc;
                }
                __syncthreads();
                int col = jj * 256 + tid;
                const ushort_t* pp = P.pacc + ((size_t)(b * NS)) * 64 * 768 + col;
                float ac0 = 0.f, ac1 = 0.f;
                for (int q = 0; q < 32; q += 2) {
                    float vv[2][NS][2];
#pragma unroll
                    for (int u = 0; u < 2; u++)
#pragma unroll
                        for (int s = 0; s < NS; s++) {
                            vv[u][s][0] = b2f(pp[((size_t)(s * 64 + q + u)) * 768]);
                            vv[u][s][1] = b2f(pp[((size_t)(s * 64 + 32 + q + u)) * 768]);
                        }
#pragma unroll
                    for (int u = 0; u < 2; u++)
#pragma unroll
                        for (int s = 0; s < NS; s++) {
                            ac0 += cw[s][q + u] * vv[u][s][0];
                            ac1 += cw[s][32 + q + u] * vv[u][s][1];
                        }
                }
                __hip_atomic_store(&P.plX[b * 1536 + col], ac0,
                                   __ATOMIC_RELAXED, __HIP_MEMORY_SCOPE_AGENT);
                __hip_atomic_store(&P.plX[b * 1536 + 768 + col], ac1,
                                   __ATOMIC_RELAXED, __HIP_MEMORY_SCOPE_AGENT);
            }
        } else if (p == 1) {
            if (bid < 192) {
                int m4 = bid / 12, ct = bid % 12, prob = ct / 6;
                tgemm4<4>(P.plX + prob * 768, 1536, P.la_w2, 768, 0,
                          P.la_b2, 1.f, sla, nullptr, 0,
                          P.pc, 768, 768, 0, 1, m4 * 4, ct * 64, As, tid);
            }
        } else if (p == 2) {
            if (bid < 192) {
                int m4 = bid / 12, ct = bid % 12;
                tgemm4<4>(P.pc, 768, P.la_w3, 768, 0, P.la_b3, 1.f, sla, nullptr, 0,
                          P.hcat, 1536, 768, 0, 1, m4 * 4, ct * 64, As, tid);
            }
        } else if (p == 3) {
            if (bid < 256) {
                int m4 = bid / 16, ct = bid % 16;
                tgemm4<4>(P.hcat, 1536, P.f1w, 1024, 0, P.f1b, 1.f, 1.f, nullptr, 0,
                          P.x1, 1024, 1536, 0, 1, m4 * 4, ct * 64, As, tid);
            }
        } else if (p == 4) {
            if (bid < 128) {
                int m4 = bid / 8, ct = bid % 8;
                tgemm4<4>(P.x1, 1024, P.f2w, 512, 0, P.f2b, 1.f, 1.f, nullptr, 0,
                          P.x2, 512, 1024, 1, 1, m4 * 4, ct * 64, As, tid);
            }
        } else if (p == 5) {
            if (bid < 256) {
                int m4 = bid / 16, ct = bid % 16;
                tgemm4<4>(P.x2, 512, P.f3w, 1024, 0, P.f3b, 1.f, 1.f, nullptr, 0,
                          P.out, 1024, 512, 0, 0, m4 * 4, ct * 64, As, tid);
            }
        }
        if (p < P.p1) gbar(P.flags, 256, p + 1, bid, tid);
    }
}

// ---------------- host launcher ----------------

extern "C" void kernel_launch(void* const* d_in, const int* in_sizes, int n_in,
                              void* d_out, int out_size, void* d_ws, size_t ws_size,
                              hipStream_t stream)
{
    const float* img  = (const float*)d_in[1];
    const float* h0   = (const float*)d_in[2];
    const float* w_ih = (const float*)d_in[3];
    const float* w_hh = (const float*)d_in[4];
    const float* b_ih = (const float*)d_in[5];
    const float* b_hh = (const float*)d_in[6];
    const float* ga_w = (const float*)d_in[7];
    const float* ga_b = (const float*)d_in[8];
    const float* ga_pool = (const float*)d_in[9];
    const float* la_w = (const float*)d_in[10];
    const float* la_b = (const float*)d_in[11];
    const float* la_pool = (const float*)d_in[12];
    const float* go_w = (const float*)d_in[13];
    const float* go_b = (const float*)d_in[14];
    const float* go_pool = (const float*)d_in[15];
    const float* f1w = (const float*)d_in[16];
    const float* f1b = (const float*)d_in[17];
    const float* f2w = (const float*)d_in[18];
    const float* f2b_ = (const float*)d_in[19];
    const float* f3w = (const float*)d_in[20];
    const float* f3b = (const float*)d_in[21];
    float* out = (float*)d_out;
    (void)in_sizes; (void)n_in; (void)out_size;

    int nsplit = (ws_size >= (size_t)43 * 1024 * 1024) ? 4 : 2;

    char* w = (char*)d_ws;
    auto alloc = [&](size_t bytes) -> char* {
        char* p = w; w += (bytes + 255) & ~(size_t)255; return p;
    };
    // persistent region
    float*    scal  = (float*)alloc(256);                 // [0]=S_go [1]=S_la
    int*      bar   = (int*)alloc(4096);                  // [0..47]=GRU [64..255]=head [320..575]=tail
    ushort_t* law0b = (ushort_t*)alloc((size_t)768 * 768 * 2);
    ushort_t* law1b = (ushort_t*)alloc((size_t)768 * 768 * 2);
    ushort_t* h0b   = (ushort_t*)alloc((size_t)64 * 768 * 2);
    ushort_t* qembb = (ushort_t*)alloc((size_t)2048 * 768 * 2);
    ushort_t* Qb    = (ushort_t*)alloc((size_t)2048 * 768 * 2);
    ushort_t* Qtb   = (ushort_t*)alloc((size_t)4096 * 768 * 2);
    float*    pm    = (float*)alloc((size_t)64 * 4 * 64 * 4);
    float*    pl    = (float*)alloc((size_t)64 * 4 * 64 * 4);
    float*    plX   = (float*)alloc((size_t)64 * 1536 * 4);
    float*    pc    = (float*)alloc((size_t)64 * 768 * 4);
    float*    hcat  = (float*)alloc((size_t)64 * 1536 * 4);
    float*    x1    = (float*)alloc((size_t)64 * 1024 * 4);
    float*    x2    = (float*)alloc((size_t)64 * 512 * 4);
    // union region: [GRU-phase temporaries] overlaid with [flash pacc]
    char* uni = w;
    char* u = uni;
    auto ualloc = [&](size_t bytes) -> char* {
        char* p = u; u += (bytes + 255) & ~(size_t)255; return p;
    };
    ushort_t* whhb  = (ushort_t*)ualloc((size_t)2304 * 768 * 2);
    float*    t12   = (float*)ualloc((size_t)2 * 64 * 768 * 4);
    float*    avec  = (float*)ualloc((size_t)64 * 768 * 4);
    float*    base  = (float*)ualloc((size_t)64 * 2304 * 4);
    float*    hbuf  = (float*)ualloc((size_t)64 * 768 * 4);
    ushort_t* pacc  = (ushort_t*)uni;   // overlays GRU temporaries; used only after GRU done
    float*    t12g  = t12 + 64 * 768;

    const float* ga_w2 = ga_w + 2 * 768 * 768; const float* ga_w3 = ga_w + 3 * 768 * 768;
    const float* ga_b2 = ga_b + 2 * 768;       const float* ga_b3 = ga_b + 3 * 768;
    const float* go_w2 = go_w + 2 * 768 * 768; const float* go_w3 = go_w + 3 * 768 * 768;
    const float* go_b2 = go_b + 2 * 768;       const float* go_b3 = go_b + 3 * 768;
    const float* la_w0 = la_w;                 const float* la_w1 = la_w + 768 * 768;
    const float* la_w2 = la_w + 2 * 768 * 768; const float* la_w3 = la_w + 3 * 768 * 768;
    const float* la_b0 = la_b;                 const float* la_b1 = la_b + 768;
    const float* la_b2 = la_b + 2 * 768;       const float* la_b3 = la_b + 3 * 768;

    dim3 blk(256);
    k_cvt_all<<<11712, blk, 0, stream>>>(w_hh, la_w0, la_w1, h0, go_pool, la_pool,
                                         whhb, law0b, law1b, h0b, hbuf, scal, bar);

    // fused head (coop, grid 192 <= 256 so always co-residable; fallback: per-phase)
    {
        HeadP P;
        P.img = img; P.ga_w2 = ga_w2; P.ga_b2 = ga_b2; P.go_w2 = go_w2; P.go_b2 = go_b2;
        P.ga_w3 = ga_w3; P.ga_b3 = ga_b3; P.go_w3 = go_w3; P.go_b3 = go_b3;
        P.ga_pool = ga_pool; P.scal = scal; P.w_ih = w_ih; P.b_ih = b_ih; P.b_hh = b_hh;
        P.t12 = t12; P.t12g = t12g; P.avec = avec; P.hcat = hcat; P.base = base;
        P.flags = bar + 64; P.p0 = 1; P.p1 = 3;
        void* args[1] = { &P };
        hipError_t e = hipLaunchCooperativeKernel((void*)k_head, dim3(192), blk, args, 0, stream);
        if (e != hipSuccess)
            for (int p = 1; p <= 3; p++) { P.p0 = P.p1 = p; k_head<<<192, blk, 0, stream>>>(P); }
    }

    // GRU scan (coop; fallback: 32 step launches)
    {
        GruP P;
        P.h0b = h0b; P.h0f = h0; P.whh = whhb; P.base = base; P.bhh = b_hh;
        P.qemb = qembb; P.flags = bar;
        void* args[1] = { &P };
        hipError_t e = hipLaunchCooperativeKernel((void*)k_gru_coop, dim3(GRU_NB), dim3(192),
                                                  args, 0, stream);
        if (e != hipSuccess)
            for (int t = 0; t < 32; t++)
                k_gru_step<<<12, blk, 0, stream>>>(t, h0b, whhb, base, b_hh, hbuf, qembb);
    }

    // Q = q_emb @ la_w0 + la_b0 ; Qt_h = Q_h @ W1_h^T (folded-K trick)
    k_gemm_bf16<<<dim3(12, 32), blk, 0, stream>>>(qembb, 768, law0b, 768, 0, la_b0, Qb, 768, 768, 0, 0);
    k_gemm_bf16<<<dim3(12, 32), blk, 0, stream>>>(Qb, 768, law1b, 768, 1, nullptr, Qtb, 768, 384, 1, 0);
    k_gemm_bf16<<<dim3(12, 32), blk, 0, stream>>>(Qb + 384, 768, law1b + 384, 768, 1, nullptr, Qtb, 768, 384, 1, 32);

    // flash attention, key-split
    k_flash<<<dim3(64, nsplit), dim3(512), 0, stream>>>(img, Qtb, Qb, la_b1, pm, pl, pacc, nsplit);

    // fused tail (coop, grid 256 <= 256 so always co-residable; fallback: per-phase)
    {
        TailP P;
        P.pm = pm; P.pl = pl; P.pacc = pacc; P.lp = la_pool;
        P.la_w2 = la_w2; P.la_b2 = la_b2; P.la_w3 = la_w3; P.la_b3 = la_b3; P.scal = scal;
        P.plX = plX; P.pc = pc; P.hcat = hcat;
        P.f1w = f1w; P.f1b = f1b; P.f2w = f2w; P.f2b = f2b_; P.f3w = f3w; P.f3b = f3b;
        P.x1 = x1; P.x2 = x2; P.out = out;
        P.flags = bar + 320; P.p0 = 0; P.p1 = 5; P.nsplit = nsplit;
        void* args[1] = { &P };
        if (nsplit == 4) {
            hipError_t e = hipLaunchCooperativeKernel((void*)k_tail<4>, dim3(256), blk, args, 0, stream);
            if (e != hipSuccess)
                for (int p = 0; p <= 5; p++) { P.p0 = P.p1 = p; k_tail<4><<<256, blk, 0, stream>>>(P); }
        } else {
            hipError_t e = hipLaunchCooperativeKernel((void*)k_tail<2>, dim3(256), blk, args, 0, stream);
            if (e != hipSuccess)
                for (int p = 0; p <= 5; p++) { P.p0 = P.p1 = p; k_tail<2><<<256, blk, 0, stream>>>(P); }
        }
    }
}

// Round 6
// 1137.650 us; speedup vs baseline: 1.5270x; 1.0080x over previous
//
#include <hip/hip_runtime.h>
#include <math.h>

// B=64, T=32, D=768, NH=2, dk=384, N=901 (1 cls + 900 local)

typedef short bf16x8 __attribute__((ext_vector_type(8)));
typedef float f32x4 __attribute__((ext_vector_type(4)));
typedef unsigned short ushort_t;

#define GRU_NB 48

__device__ __forceinline__ unsigned short f2b(float f) {
    unsigned int u = __float_as_uint(f);
    unsigned int r = (u + 0x7FFFu + ((u >> 16) & 1u)) >> 16;
    return (unsigned short)r;
}
__device__ __forceinline__ float b2f(unsigned short s) {
    return __uint_as_float(((unsigned int)s) << 16);
}
__device__ __forceinline__ float sigm(float x) { return 1.f / (1.f + __expf(-x)); }
__device__ __forceinline__ float tanhx(float x) {
    x = fminf(fmaxf(x, -15.f), 15.f);
    float e = __expf(2.f * x);
    return (e - 1.f) / (e + 1.f);
}

// flag barrier: arrival = agent store of monotonically-increasing phase id; poll =
// parallel relaxed agent loads (no RMW contention). Data written before the barrier
// must use agent-scope stores (bypass L2 -> L3) so readers' plain loads (fresh lines)
// see it. flags zeroed by k_cvt_all each launch.
__device__ __forceinline__ void gbar(int* flags, int nb, int phase, int bid, int tid) {
    __syncthreads();   // drains each wave's vmcnt -> agent stores are in L3
    if (tid == 0) __hip_atomic_store(&flags[bid], phase, __ATOMIC_RELAXED, __HIP_MEMORY_SCOPE_AGENT);
    if (tid < 64) {
        for (;;) {
            int v = 0x7fffffff;
            for (int f = tid; f < nb; f += 64)
                v = min(v, __hip_atomic_load(&flags[f], __ATOMIC_RELAXED, __HIP_MEMORY_SCOPE_AGENT));
            if (__all(v >= phase)) break;
            __builtin_amdgcn_s_sleep(1);
        }
    }
    __syncthreads();
}

// ---------------- setup: convert weights to bf16, pool sums, zero flags ----------------

__global__ void k_cvt_all(const float* __restrict__ whh, const float* __restrict__ la0,
                          const float* __restrict__ la1, const float* __restrict__ h0,
                          const float* __restrict__ gp, const float* __restrict__ lp,
                          ushort_t* __restrict__ whhb, ushort_t* __restrict__ law0b,
                          ushort_t* __restrict__ law1b, ushort_t* __restrict__ h0b,
                          float* __restrict__ hbuf, float* __restrict__ scal,
                          int* __restrict__ bar) {
    if (blockIdx.x == 0) {
        int t = threadIdx.x;
        if (t < 64) {
            float v1 = (t < 32) ? gp[t] : 0.f;
            float v2 = (t < 32) ? lp[t] : 0.f;
#pragma unroll
            for (int m = 1; m < 32; m <<= 1) { v1 += __shfl_xor(v1, m, 64); v2 += __shfl_xor(v2, m, 64); }
            if (t == 0) { scal[0] = v1; scal[1] = v2; }
        }
        for (int i = threadIdx.x; i < 1024; i += 256) bar[i] = 0;
    }
    long i = (long)blockIdx.x * 256 + threadIdx.x;
    const long n1 = 2304L * 768, n2 = n1 + 768L * 768, n3 = n2 + 768L * 768, n4 = n3 + 64L * 768;
    if (i < n1) whhb[i] = f2b(whh[i]);
    else if (i < n2) law0b[i - n1] = f2b(la0[i - n1]);
    else if (i < n3) law1b[i - n2] = f2b(la1[i - n2]);
    else if (i < n4) { float v = h0[i - n3]; h0b[i - n3] = f2b(v); hbuf[i - n3] = v; }
}

// ---------------- parallel fp32 tile GEMM: MR rows x 64 cols per block ----------------
// 256 threads = 64 cols x 4 K-chunks; each thread accumulates its K/4 chunk with 8
// independent B-loads in flight; cross-chunk reduction through LDS (aliased onto the
// dead A-tile). out = acc*s1 + bias[c]*s2 (+ bias2[c] if c<b2lim); optional relu,
// optional agent-scope store. Register-light by design (acc[MR]+bv[8]): no spill.

template<int MR>
__device__ __forceinline__ void tgemm4(
    const float* __restrict__ A, long lda,
    const float* __restrict__ Bm, int ldb, int transB,
    const float* __restrict__ bias, float s1, float s2,
    const float* __restrict__ bias2, int b2lim,
    float* __restrict__ C, int ldc, int K, int relu, int agent,
    int m0, int n0, float* As, int tid)
{
    for (int r = 0; r < MR; r++)
        for (int k = tid; k < K; k += 256)
            As[r * K + k] = A[(long)(m0 + r) * lda + k];
    __syncthreads();
    int cl = tid & 63, kc = tid >> 6;
    int c = n0 + cl;
    int K4 = K >> 2;
    int kb = kc * K4;
    const float* Bp = transB ? (Bm + (long)c * ldb) : (Bm + c);
    float acc[MR];
#pragma unroll
    for (int r = 0; r < MR; r++) acc[r] = 0.f;
    for (int k = kb; k < kb + K4; k += 8) {
        float bv[8];
        if (!transB) {
#pragma unroll
            for (int i = 0; i < 8; i++) bv[i] = Bp[(long)(k + i) * ldb];
        } else {
            float4 q0 = *(const float4*)(Bp + k);
            float4 q1 = *(const float4*)(Bp + k + 4);
            bv[0] = q0.x; bv[1] = q0.y; bv[2] = q0.z; bv[3] = q0.w;
            bv[4] = q1.x; bv[5] = q1.y; bv[6] = q1.z; bv[7] = q1.w;
        }
#pragma unroll
        for (int i = 0; i < 8; i += 4) {
#pragma unroll
            for (int r = 0; r < MR; r++) {
                float4 x = *(const float4*)&As[r * K + k + i];
                acc[r] += x.x * bv[i] + x.y * bv[i + 1] + x.z * bv[i + 2] + x.w * bv[i + 3];
            }
        }
    }
    __syncthreads();           // all As reads done -> safe to alias
    float* Red = As;           // 4*MR*64 floats <= MR*K (K>=256)
#pragma unroll
    for (int r = 0; r < MR; r++) Red[(kc * MR + r) * 64 + cl] = acc[r];
    __syncthreads();
    {
        int rg = tid >> 6;
        float bb = (bias ? bias[c] * s2 : 0.f) + ((bias2 && c < b2lim) ? bias2[c] : 0.f);
#pragma unroll
        for (int i = 0; i < MR / 4; i++) {
            int r = rg + i * 4;
            float sum = (Red[(0 * MR + r) * 64 + cl] + Red[(1 * MR + r) * 64 + cl])
                      + (Red[(2 * MR + r) * 64 + cl] + Red[(3 * MR + r) * 64 + cl]);
            float o = sum * s1 + bb;
            if (relu) o = fmaxf(o, 0.f);
            if (agent) __hip_atomic_store(&C[(long)(m0 + r) * ldc + c], o,
                                          __ATOMIC_RELAXED, __HIP_MEMORY_SCOPE_AGENT);
            else C[(long)(m0 + r) * ldc + c] = o;
        }
    }
}

// ---------------- fused head: t12/t12g -> avec/global_out -> base (3 phases) ----------------
// grid 192: p1/p2 = 2x8x12 = 192 blocks (MR=8), p3 = 4x36 = 144 blocks (MR=16)

struct HeadP {
    const float *img, *ga_w2, *ga_b2, *go_w2, *go_b2;
    const float *ga_w3, *ga_b3, *go_w3, *go_b3;
    const float *ga_pool, *scal, *w_ih, *b_ih, *b_hh;
    float *t12, *t12g, *avec, *hcat, *base;
    int* flags; int p0, p1;
};

__global__ void __launch_bounds__(256) k_head(HeadP P) {
    __shared__ __align__(16) float As[16 * 768];
    int bid = blockIdx.x, tid = threadIdx.x;
    for (int p = P.p0; p <= P.p1; p++) {
        if (p == 1) {
            if (bid < 192) {
                int prob = bid / 96, r = bid % 96, m8 = r / 12, ct = r % 12;
                tgemm4<8>(P.img, 901L * 768, prob ? P.go_w2 : P.ga_w2, 768, 0,
                          prob ? P.go_b2 : P.ga_b2, 1.f, 1.f, nullptr, 0,
                          prob ? P.t12g : P.t12, 768, 768, 0, 1, m8 * 8, ct * 64, As, tid);
            }
        } else if (p == 2) {
            if (bid < 192) {
                int prob = bid / 96, r = bid % 96, m8 = r / 12, ct = r % 12;
                float sc = prob ? P.scal[0] : P.ga_pool[0];
                tgemm4<8>(prob ? P.t12g : P.t12, 768, prob ? P.go_w3 : P.ga_w3, 768, 0,
                          prob ? P.go_b3 : P.ga_b3, sc, sc, nullptr, 0,
                          prob ? (P.hcat + 768) : P.avec, prob ? 1536 : 768, 768, 0, 1,
                          m8 * 8, ct * 64, As, tid);
            }
        } else if (p == 3) {
            if (bid < 144) {
                int m4 = bid / 36, ct = bid % 36;
                // base = avec @ w_ih^T + b_ih (+ b_hh for first 1536 cols)
                tgemm4<16>(P.avec, 768, P.w_ih, 768, 1, P.b_ih, 1.f, 1.f, P.b_hh, 1536,
                           P.base, 2304, 768, 0, 0, m4 * 16, ct * 64, As, tid);
            }
        }
        if (p < P.p1) gbar(P.flags, 192, p, bid, tid);
    }
}

// ---------------- GRU scan: 48 blocks x 384 thr (6 waves = 3 gates x 2 K-halves) ----------------
// whh/base/h in LDS; per-wave A-load count halved vs 3-wave version (latency hiding);
// K-half partials reduced through ps[] in LDS; flag barrier across 48 blocks.

struct GruP {
    const ushort_t* h0b; const float* h0f; const ushort_t* whh;
    const float* base; const float* bhh; ushort_t* qemb; int* flags;
};

__global__ void __launch_bounds__(384) k_gru_coop(GruP P) {
    __shared__ __align__(16) ushort_t whh_s[3][16][776];
    __shared__ float ps[2][3][64][20];
    __shared__ float bs[3][64][20];
    __shared__ float h_s[64][20];
    __shared__ float bhh_s[16];
    int tid = threadIdx.x;
    int wid = tid >> 6, lane = tid & 63, quad = lane >> 4, l16 = lane & 15;
    int g = wid >> 1, kh = wid & 1;          // gate, K-half
    int j = blockIdx.x, d0 = j * 16;
    {   // stage whh: waves 0-2 -> gate wid rows 0-7; waves 3-5 -> gate wid-3 rows 8-15
        int gS = (wid < 3) ? wid : wid - 3;
        int r0 = (wid < 3) ? 0 : 8;
        for (int r = r0; r < r0 + 8; r++)
            for (int kk = lane * 8; kk < 768; kk += 512)
                *(bf16x8*)&whh_s[gS][r][kk] = *(const bf16x8*)&P.whh[(size_t)(gS * 768 + d0 + r) * 768 + kk];
    }
    for (int e = tid; e < 3072; e += 384) {
        int g2 = e >> 10, rem = e & 1023, b = rem >> 4, c = rem & 15;
        bs[g2][b][c] = P.base[b * 2304 + g2 * 768 + d0 + c];
    }
    for (int e = tid; e < 1024; e += 384) {
        int b = e >> 4, c = e & 15;
        h_s[b][c] = P.h0f[b * 768 + d0 + c];
    }
    if (tid < 16) bhh_s[tid] = P.bhh[1536 + d0 + tid];
    __syncthreads();
    for (int t = 0; t < 32; t++) {
        const ushort_t* Ap = (t == 0) ? P.h0b : (P.qemb + (size_t)(t - 1) * 768);
        size_t ldA = (t == 0) ? 768 : (size_t)32 * 768;
        f32x4 zz4 = {0.f, 0.f, 0.f, 0.f};
        f32x4 acc[4];
#pragma unroll
        for (int mi = 0; mi < 4; mi++) acc[mi] = zz4;
        int kbase = kh * 384;
        for (int kk = kbase; kk < kbase + 384; kk += 32) {
            bf16x8 bfr = *(const bf16x8*)&whh_s[g][l16][kk + quad * 8];
#pragma unroll
            for (int mi = 0; mi < 4; mi++) {
                bf16x8 af = *(const bf16x8*)(Ap + (size_t)(mi * 16 + l16) * ldA + kk + quad * 8);
                acc[mi] = __builtin_amdgcn_mfma_f32_16x16x32_bf16(af, bfr, acc[mi], 0, 0, 0);
            }
        }
#pragma unroll
        for (int mi = 0; mi < 4; mi++)
#pragma unroll
            for (int r = 0; r < 4; r++)
                ps[kh][g][mi * 16 + quad * 4 + r][l16] = acc[mi][r];
        __syncthreads();
        for (int e = tid; e < 512; e += 384) {
            int b = e >> 3, c0 = (e & 7) * 2;
            float hn[2];
#pragma unroll
            for (int u = 0; u < 2; u++) {
                int c = c0 + u;
                float g0 = ps[0][0][b][c] + ps[1][0][b][c];
                float g1 = ps[0][1][b][c] + ps[1][1][b][c];
                float g2v = ps[0][2][b][c] + ps[1][2][b][c];
                float rr = sigm(g0 + bs[0][b][c]);
                float zg = sigm(g1 + bs[1][b][c]);
                float nn = tanhx(bs[2][b][c] + rr * (g2v + bhh_s[c]));
                float hv = h_s[b][c];
                hn[u] = (1.f - zg) * nn + zg * hv;
                h_s[b][c] = hn[u];
            }
            unsigned int pk = (unsigned int)f2b(hn[0]) | ((unsigned int)f2b(hn[1]) << 16);
            __hip_atomic_store((unsigned int*)&P.qemb[((size_t)b * 32 + t) * 768 + d0 + c0],
                               pk, __ATOMIC_RELAXED, __HIP_MEMORY_SCOPE_AGENT);
        }
        __syncthreads();   // drain agent stores to L3 before flag
        if (t < 31) {
            if (tid == 0)
                __hip_atomic_store(&P.flags[j], t + 1, __ATOMIC_RELAXED, __HIP_MEMORY_SCOPE_AGENT);
            if (tid < 64) {
                for (;;) {
                    int v = (tid < GRU_NB)
                        ? __hip_atomic_load(&P.flags[tid], __ATOMIC_RELAXED, __HIP_MEMORY_SCOPE_AGENT)
                        : 0x7fffffff;
                    if (__all(v > t)) break;
                    __builtin_amdgcn_s_sleep(1);
                }
            }
            __syncthreads();
        }
    }
}

// fallback (non-coop): 32 per-step launches
__global__ void __launch_bounds__(256) k_gru_step(
    int t, const ushort_t* h0b, const ushort_t* whh, const float* base,
    const float* bhh, float* h, ushort_t* qemb)
{
    int wv = threadIdx.x >> 6, lane = threadIdx.x & 63;
    int quad = lane >> 4, l16 = lane & 15;
    int d0 = blockIdx.x * 64 + wv * 16;
    float bhhn = bhh[1536 + d0 + l16];
    const ushort_t* Ap = (t == 0) ? h0b : (qemb + (long)(t - 1) * 768);
    long ldA = (t == 0) ? 768 : 32 * 768;
    int d = d0 + l16;
    f32x4 zz4 = {0.f, 0.f, 0.f, 0.f};
    f32x4 acc[3][4];
#pragma unroll
    for (int g = 0; g < 3; g++)
#pragma unroll
        for (int mi = 0; mi < 4; mi++) acc[g][mi] = zz4;
    for (int kk = 0; kk < 768; kk += 32) {
        bf16x8 af[4];
#pragma unroll
        for (int mi = 0; mi < 4; mi++)
            af[mi] = *(const bf16x8*)(Ap + (long)(mi * 16 + l16) * ldA + kk + quad * 8);
#pragma unroll
        for (int g = 0; g < 3; g++) {
            bf16x8 bfr = *(const bf16x8*)(whh + (long)(g * 768 + d0 + l16) * 768 + kk + quad * 8);
#pragma unroll
            for (int mi = 0; mi < 4; mi++)
                acc[g][mi] = __builtin_amdgcn_mfma_f32_16x16x32_bf16(af[mi], bfr, acc[g][mi], 0, 0, 0);
        }
    }
#pragma unroll
    for (int mi = 0; mi < 4; mi++) {
#pragma unroll
        for (int r = 0; r < 4; r++) {
            int b = mi * 16 + quad * 4 + r;
            const float* bb = base + b * 2304;
            float rr = sigm(acc[0][mi][r] + bb[d]);
            float zg = sigm(acc[1][mi][r] + bb[768 + d]);
            float nn = tanhx(bb[1536 + d] + rr * (acc[2][mi][r] + bhhn));
            float hv = h[b * 768 + d];
            float hnew = (1.f - zg) * nn + zg * hv;
            h[b * 768 + d] = hnew;
            qemb[(long)(b * 32 + t) * 768 + d] = f2b(hnew);
        }
    }
}

// ---------------- generic bf16 MFMA GEMM (64x64 tile) ----------------

__global__ void __launch_bounds__(256) k_gemm_bf16(
    const ushort_t* __restrict__ A, int lda,
    const ushort_t* __restrict__ B, int ldb, int transB,
    const float* __restrict__ bias,
    ushort_t* __restrict__ Cb, int ldc,
    int K, int remap, int rowoff)
{
    __shared__ __align__(16) ushort_t As[64][72];
    __shared__ __align__(16) ushort_t Bs[64][72];
    int tid = threadIdx.x;
    int wv = tid >> 6, lane = tid & 63, quad = lane >> 4, l16 = lane & 15;
    long bm = (long)blockIdx.y * 64, bn = (long)blockIdx.x * 64;
    f32x4 zz4 = {0.f, 0.f, 0.f, 0.f};
    f32x4 acc[4];
#pragma unroll
    for (int mi = 0; mi < 4; mi++) acc[mi] = zz4;
    int row4 = tid >> 2, seg = tid & 3;
    for (int k0 = 0; k0 < K; k0 += 64) {
        {
            const ushort_t* src = A + (bm + row4) * lda + k0 + seg * 16;
            *(bf16x8*)&As[row4][seg * 16] = *(const bf16x8*)src;
            *(bf16x8*)&As[row4][seg * 16 + 8] = *(const bf16x8*)(src + 8);
        }
        if (transB) {
            const ushort_t* src = B + (bn + row4) * ldb + k0 + seg * 16;
            *(bf16x8*)&Bs[row4][seg * 16] = *(const bf16x8*)src;
            *(bf16x8*)&Bs[row4][seg * 16 + 8] = *(const bf16x8*)(src + 8);
        } else {
            const ushort_t* src = B + (long)(k0 + row4) * ldb + bn + seg * 16;
            bf16x8 v0 = *(const bf16x8*)src;
            bf16x8 v1 = *(const bf16x8*)(src + 8);
#pragma unroll
            for (int i = 0; i < 8; i++) {
                Bs[seg * 16 + i][row4] = (ushort_t)v0[i];
                Bs[seg * 16 + 8 + i][row4] = (ushort_t)v1[i];
            }
        }
        __syncthreads();
#pragma unroll
        for (int ks = 0; ks < 64; ks += 32) {
            bf16x8 bfr = *(const bf16x8*)&Bs[wv * 16 + l16][ks + quad * 8];
#pragma unroll
            for (int mi = 0; mi < 4; mi++) {
                bf16x8 af = *(const bf16x8*)&As[mi * 16 + l16][ks + quad * 8];
                acc[mi] = __builtin_amdgcn_mfma_f32_16x16x32_bf16(af, bfr, acc[mi], 0, 0, 0);
            }
        }
        __syncthreads();
    }
    int ncol = (int)bn + wv * 16 + l16;
    float bv = bias ? bias[ncol] : 0.f;
#pragma unroll
    for (int mi = 0; mi < 4; mi++) {
#pragma unroll
        for (int r = 0; r < 4; r++) {
            long row = bm + mi * 16 + quad * 4 + r;
            long orow = remap ? ((row >> 5) * 64 + rowoff + (row & 31)) : row;
            Cb[orow * ldc + ncol] = f2b(acc[mi][r] + bv);
        }
    }
}

// ---------------- fused flash attention, key-split partials (qb folded in) ----------------

__global__ void __launch_bounds__(512) k_flash(
    const float* __restrict__ img, const ushort_t* __restrict__ Qt,
    const ushort_t* __restrict__ Qb, const float* __restrict__ la_b1,
    float* __restrict__ pm, float* __restrict__ pl,
    ushort_t* __restrict__ pacc, int nsplit)
{
    __shared__ __align__(16) ushort_t xs[32][776];
    __shared__ float Sls[64][36];
    __shared__ __align__(16) ushort_t Pls[64][40];
    __shared__ float m_s[64], l_s[64], al_s[64], qb_s[64];
    int b = blockIdx.x;
    int sp = blockIdx.y;
    int tper = (29 + nsplit - 1) / nsplit;
    int tb = sp * tper, te = min(29, tb + tper);
    int tid = threadIdx.x;
    int wv = tid >> 6, lane = tid & 63, quad = lane >> 4, l16 = lane & 15;
    { // qb_s[row] = Q_h[b,q,:] . la_b1_h   (8 lanes per row)
        int row = tid >> 3, sub = tid & 7;
        int hh = row >> 5, q = row & 31;
        const ushort_t* src = Qb + ((size_t)(b * 32 + q)) * 768 + hh * 384 + sub * 48;
        const float* bb = la_b1 + hh * 384 + sub * 48;
        float s = 0.f;
#pragma unroll
        for (int k = 0; k < 48; k++) s += b2f(src[k]) * bb[k];
        s += __shfl_xor(s, 1, 64); s += __shfl_xor(s, 2, 64); s += __shfl_xor(s, 4, 64);
        if (sub == 0) qb_s[row] = s;
    }
    if (tid < 64) { m_s[tid] = -1e30f; l_s[tid] = 0.f; }
    f32x4 zz4 = {0.f, 0.f, 0.f, 0.f};
    f32x4 acc[4][6];
#pragma unroll
    for (int mi = 0; mi < 4; mi++)
#pragma unroll
        for (int nj = 0; nj < 6; nj++) acc[mi][nj] = zz4;
    const float rs = 0.051031036307982884f; // 1/sqrt(384)
    int smi = wv & 3, sni = wv >> 2;
    __syncthreads();
    for (int t0 = tb; t0 < te; t0++) {
        int key0 = t0 * 32;
        { // stage x tile (fp32 global -> bf16 LDS), zero-fill past key 899
            int keyl = tid >> 4, dseg = tid & 15;
            int key = key0 + keyl;
            const float* src = img + ((long)b * 901 + 1 + key) * 768;
            bool ok = key < 900;
#pragma unroll
            for (int c = 0; c < 12; c++) {
                int dd = c * 64 + dseg * 4;
                float x0 = 0, x1 = 0, x2 = 0, x3 = 0;
                if (ok) { float4 v = *(const float4*)(src + dd); x0 = v.x; x1 = v.y; x2 = v.z; x3 = v.w; }
                ushort_t* dst = &xs[keyl][dd];
                dst[0] = f2b(x0); dst[1] = f2b(x1); dst[2] = f2b(x2); dst[3] = f2b(x3);
            }
        }
        __syncthreads();
        { // S = Qt @ x^T
            f32x4 as = zz4;
            const ushort_t* qrow = Qt + (long)(b * 64 + smi * 16 + l16) * 768 + quad * 8;
            const ushort_t* xrow = &xs[sni * 16 + l16][quad * 8];
#pragma unroll
            for (int kk = 0; kk < 768; kk += 32) {
                bf16x8 aq = *(const bf16x8*)(qrow + kk);
                bf16x8 bx = *(const bf16x8*)(xrow + kk);
                as = __builtin_amdgcn_mfma_f32_16x16x32_bf16(aq, bx, as, 0, 0, 0);
            }
#pragma unroll
            for (int r = 0; r < 4; r++) {
                int row = smi * 16 + quad * 4 + r;
                Sls[row][sni * 16 + l16] = (as[r] + qb_s[row]) * rs;
            }
        }
        __syncthreads();
        { // online softmax: 8 threads per row
            int row = tid >> 3, sub = tid & 7;
            float sv[4];
            float mx = -1e30f;
#pragma unroll
            for (int i = 0; i < 4; i++) {
                int kl = sub + i * 8;
                float s = (key0 + kl < 900) ? Sls[row][kl] : -1e30f;
                sv[i] = s; mx = fmaxf(mx, s);
            }
            mx = fmaxf(mx, __shfl_xor(mx, 1, 64));
            mx = fmaxf(mx, __shfl_xor(mx, 2, 64));
            mx = fmaxf(mx, __shfl_xor(mx, 4, 64));
            float mold = m_s[row];
            float mnew = fmaxf(mold, mx);
            float ss = 0.f;
#pragma unroll
            for (int i = 0; i < 4; i++) {
                float p = __expf(sv[i] - mnew);
                ss += p;
                Pls[row][sub + i * 8] = f2b(p);
            }
            ss += __shfl_xor(ss, 1, 64);
            ss += __shfl_xor(ss, 2, 64);
            ss += __shfl_xor(ss, 4, 64);
            if (sub == 0) {
                float alpha = __expf(mold - mnew);
                al_s[row] = alpha;
                l_s[row] = l_s[row] * alpha + ss;
                m_s[row] = mnew;
            }
        }
        __syncthreads();
        { // rescale + acc += P @ x
            bf16x8 pf[4];
#pragma unroll
            for (int mi = 0; mi < 4; mi++)
                pf[mi] = *(const bf16x8*)&Pls[mi * 16 + l16][quad * 8];
#pragma unroll
            for (int mi = 0; mi < 4; mi++) {
#pragma unroll
                for (int r = 0; r < 4; r++) {
                    float a = al_s[mi * 16 + quad * 4 + r];
#pragma unroll
                    for (int nj = 0; nj < 6; nj++) acc[mi][nj][r] *= a;
                }
            }
#pragma unroll
            for (int nj = 0; nj < 6; nj++) {
                int dd = wv * 96 + nj * 16 + l16;
                bf16x8 bx;
#pragma unroll
                for (int j = 0; j < 8; j++) bx[j] = (short)xs[quad * 8 + j][dd];
#pragma unroll
                for (int mi = 0; mi < 4; mi++)
                    acc[mi][nj] = __builtin_amdgcn_mfma_f32_16x16x32_bf16(pf[mi], bx, acc[mi][nj], 0, 0, 0);
            }
        }
        __syncthreads();
    }
    if (tid < 64) {
        pm[(b * nsplit + sp) * 64 + tid] = m_s[tid];
        pl[(b * nsplit + sp) * 64 + tid] = l_s[tid];
    }
#pragma unroll
    for (int mi = 0; mi < 4; mi++) {
#pragma unroll
        for (int r = 0; r < 4; r++) {
            int row = mi * 16 + quad * 4 + r;
            ushort_t* dst = pacc + ((size_t)(b * nsplit + sp) * 64 + row) * 768;
#pragma unroll
            for (int nj = 0; nj < 6; nj++)
                dst[wv * 96 + nj * 16 + l16] = f2b(acc[mi][nj][r]);
        }
    }
}

// ---------------- fused tail: combine+pool -> pc -> local_out -> f1 -> f2 -> f3 ----------------
// grid 256; phases: p0 192 (64b x 3 col-chunks, both halves), p1/p2 192 (MR=4),
// p3 256, p4 128, p5 256

struct TailP {
    const float *pm, *pl; const ushort_t* pacc; const float* lp;
    const float *la_w2, *la_b2, *la_w3, *la_b3, *scal;
    float *plX, *pc, *hcat;
    const float *f1w, *f1b, *f2w, *f2b, *f3w, *f3b;
    float *x1, *x2, *out;
    int* flags; int p0, p1, nsplit;
};

template<int NS>
__global__ void __launch_bounds__(256) k_tail(TailP P) {
    __shared__ __align__(16) float As[4 * 1536];
    __shared__ float cw[NS][64];
    int bid = blockIdx.x, tid = threadIdx.x;
    float sla = P.scal[1];
    for (int p = P.p0; p <= P.p1; p++) {
        if (p == 0) {
            // 192 blocks = 64 batches x 3 col-chunks of 256; each thread handles one
            // column for BOTH row-halves: <=16 independent loads in flight, no spill.
            if (bid < 192) {
                int b = bid / 3, jj = bid % 3;
                if (tid < 64) {
                    int row = tid;
                    float ex[NS];
                    float mmax = -1e30f;
#pragma unroll
                    for (int s = 0; s < NS; s++) mmax = fmaxf(mmax, P.pm[(b * NS + s) * 64 + row]);
                    float lsum = 0.f;
#pragma unroll
                    for (int s = 0; s < NS; s++) {
                        ex[s] = __expf(P.pm[(b * NS + s) * 64 + row] - mmax);
                        lsum += ex[s] * P.pl[(b * NS + s) * 64 + row];
                    }
                    float sc = P.lp[row & 31] / lsum;
#pragma unroll
                    for (int s = 0; s < NS; s++) cw[s][row] = ex[s] * sc;
                }
                __syncthreads();
                int col = jj * 256 + tid;
                const ushort_t* pp = P.pacc + ((size_t)(b * NS)) * 64 * 768 + col;
                float ac0 = 0.f, ac1 = 0.f;
                for (int q = 0; q < 32; q += 2) {
                    float vv[2][NS][2];
#pragma unroll
                    for (int u = 0; u < 2; u++)
#pragma unroll
                        for (int s = 0; s < NS; s++) {
                            vv[u][s][0] = b2f(pp[((size_t)(s * 64 + q + u)) * 768]);
                            vv[u][s][1] = b2f(pp[((size_t)(s * 64 + 32 + q + u)) * 768]);
                        }
#pragma unroll
                    for (int u = 0; u < 2; u++)
#pragma unroll
                        for (int s = 0; s < NS; s++) {
                            ac0 += cw[s][q + u] * vv[u][s][0];
                            ac1 += cw[s][32 + q + u] * vv[u][s][1];
                        }
                }
                __hip_atomic_store(&P.plX[b * 1536 + col], ac0,
                                   __ATOMIC_RELAXED, __HIP_MEMORY_SCOPE_AGENT);
                __hip_atomic_store(&P.plX[b * 1536 + 768 + col], ac1,
                                   __ATOMIC_RELAXED, __HIP_MEMORY_SCOPE_AGENT);
            }
        } else if (p == 1) {
            if (bid < 192) {
                int m4 = bid / 12, ct = bid % 12, prob = ct / 6;
                tgemm4<4>(P.plX + prob * 768, 1536, P.la_w2, 768, 0,
                          P.la_b2, 1.f, sla, nullptr, 0,
                          P.pc, 768, 768, 0, 1, m4 * 4, ct * 64, As, tid);
            }
        } else if (p == 2) {
            if (bid < 192) {
                int m4 = bid / 12, ct = bid % 12;
                tgemm4<4>(P.pc, 768, P.la_w3, 768, 0, P.la_b3, 1.f, sla, nullptr, 0,
                          P.hcat, 1536, 768, 0, 1, m4 * 4, ct * 64, As, tid);
            }
        } else if (p == 3) {
            if (bid < 256) {
                int m4 = bid / 16, ct = bid % 16;
                tgemm4<4>(P.hcat, 1536, P.f1w, 1024, 0, P.f1b, 1.f, 1.f, nullptr, 0,
                          P.x1, 1024, 1536, 0, 1, m4 * 4, ct * 64, As, tid);
            }
        } else if (p == 4) {
            if (bid < 128) {
                int m4 = bid / 8, ct = bid % 8;
                tgemm4<4>(P.x1, 1024, P.f2w, 512, 0, P.f2b, 1.f, 1.f, nullptr, 0,
                          P.x2, 512, 1024, 1, 1, m4 * 4, ct * 64, As, tid);
            }
        } else if (p == 5) {
            if (bid < 256) {
                int m4 = bid / 16, ct = bid % 16;
                tgemm4<4>(P.x2, 512, P.f3w, 1024, 0, P.f3b, 1.f, 1.f, nullptr, 0,
                          P.out, 1024, 512, 0, 0, m4 * 4, ct * 64, As, tid);
            }
        }
        if (p < P.p1) gbar(P.flags, 256, p + 1, bid, tid);
    }
}

// ---------------- host launcher ----------------

extern "C" void kernel_launch(void* const* d_in, const int* in_sizes, int n_in,
                              void* d_out, int out_size, void* d_ws, size_t ws_size,
                              hipStream_t stream)
{
    const float* img  = (const float*)d_in[1];
    const float* h0   = (const float*)d_in[2];
    const float* w_ih = (const float*)d_in[3];
    const float* w_hh = (const float*)d_in[4];
    const float* b_ih = (const float*)d_in[5];
    const float* b_hh = (const float*)d_in[6];
    const float* ga_w = (const float*)d_in[7];
    const float* ga_b = (const float*)d_in[8];
    const float* ga_pool = (const float*)d_in[9];
    const float* la_w = (const float*)d_in[10];
    const float* la_b = (const float*)d_in[11];
    const float* la_pool = (const float*)d_in[12];
    const float* go_w = (const float*)d_in[13];
    const float* go_b = (const float*)d_in[14];
    const float* go_pool = (const float*)d_in[15];
    const float* f1w = (const float*)d_in[16];
    const float* f1b = (const float*)d_in[17];
    const float* f2w = (const float*)d_in[18];
    const float* f2b_ = (const float*)d_in[19];
    const float* f3w = (const float*)d_in[20];
    const float* f3b = (const float*)d_in[21];
    float* out = (float*)d_out;
    (void)in_sizes; (void)n_in; (void)out_size;

    int nsplit = (ws_size >= (size_t)43 * 1024 * 1024) ? 4 : 2;

    char* w = (char*)d_ws;
    auto alloc = [&](size_t bytes) -> char* {
        char* p = w; w += (bytes + 255) & ~(size_t)255; return p;
    };
    // persistent region
    float*    scal  = (float*)alloc(256);                 // [0]=S_go [1]=S_la
    int*      bar   = (int*)alloc(4096);                  // [0..47]=GRU [64..255]=head [320..575]=tail
    ushort_t* law0b = (ushort_t*)alloc((size_t)768 * 768 * 2);
    ushort_t* law1b = (ushort_t*)alloc((size_t)768 * 768 * 2);
    ushort_t* h0b   = (ushort_t*)alloc((size_t)64 * 768 * 2);
    ushort_t* qembb = (ushort_t*)alloc((size_t)2048 * 768 * 2);
    ushort_t* Qb    = (ushort_t*)alloc((size_t)2048 * 768 * 2);
    ushort_t* Qtb   = (ushort_t*)alloc((size_t)4096 * 768 * 2);
    float*    pm    = (float*)alloc((size_t)64 * 4 * 64 * 4);
    float*    pl    = (float*)alloc((size_t)64 * 4 * 64 * 4);
    float*    plX   = (float*)alloc((size_t)64 * 1536 * 4);
    float*    pc    = (float*)alloc((size_t)64 * 768 * 4);
    float*    hcat  = (float*)alloc((size_t)64 * 1536 * 4);
    float*    x1    = (float*)alloc((size_t)64 * 1024 * 4);
    float*    x2    = (float*)alloc((size_t)64 * 512 * 4);
    // union region: [GRU-phase temporaries] overlaid with [flash pacc]
    char* uni = w;
    char* u = uni;
    auto ualloc = [&](size_t bytes) -> char* {
        char* p = u; u += (bytes + 255) & ~(size_t)255; return p;
    };
    ushort_t* whhb  = (ushort_t*)ualloc((size_t)2304 * 768 * 2);
    float*    t12   = (float*)ualloc((size_t)2 * 64 * 768 * 4);
    float*    avec  = (float*)ualloc((size_t)64 * 768 * 4);
    float*    base  = (float*)ualloc((size_t)64 * 2304 * 4);
    float*    hbuf  = (float*)ualloc((size_t)64 * 768 * 4);
    ushort_t* pacc  = (ushort_t*)uni;   // overlays GRU temporaries; used only after GRU done
    float*    t12g  = t12 + 64 * 768;

    const float* ga_w2 = ga_w + 2 * 768 * 768; const float* ga_w3 = ga_w + 3 * 768 * 768;
    const float* ga_b2 = ga_b + 2 * 768;       const float* ga_b3 = ga_b + 3 * 768;
    const float* go_w2 = go_w + 2 * 768 * 768; const float* go_w3 = go_w + 3 * 768 * 768;
    const float* go_b2 = go_b + 2 * 768;       const float* go_b3 = go_b + 3 * 768;
    const float* la_w0 = la_w;                 const float* la_w1 = la_w + 768 * 768;
    const float* la_w2 = la_w + 2 * 768 * 768; const float* la_w3 = la_w + 3 * 768 * 768;
    const float* la_b0 = la_b;                 const float* la_b1 = la_b + 768;
    const float* la_b2 = la_b + 2 * 768;       const float* la_b3 = la_b + 3 * 768;

    dim3 blk(256);
    k_cvt_all<<<11712, blk, 0, stream>>>(w_hh, la_w0, la_w1, h0, go_pool, la_pool,
                                         whhb, law0b, law1b, h0b, hbuf, scal, bar);

    // fused head (coop, grid 192 <= 256 so always co-residable; fallback: per-phase)
    {
        HeadP P;
        P.img = img; P.ga_w2 = ga_w2; P.ga_b2 = ga_b2; P.go_w2 = go_w2; P.go_b2 = go_b2;
        P.ga_w3 = ga_w3; P.ga_b3 = ga_b3; P.go_w3 = go_w3; P.go_b3 = go_b3;
        P.ga_pool = ga_pool; P.scal = scal; P.w_ih = w_ih; P.b_ih = b_ih; P.b_hh = b_hh;
        P.t12 = t12; P.t12g = t12g; P.avec = avec; P.hcat = hcat; P.base = base;
        P.flags = bar + 64; P.p0 = 1; P.p1 = 3;
        void* args[1] = { &P };
        hipError_t e = hipLaunchCooperativeKernel((void*)k_head, dim3(192), blk, args, 0, stream);
        if (e != hipSuccess)
            for (int p = 1; p <= 3; p++) { P.p0 = P.p1 = p; k_head<<<192, blk, 0, stream>>>(P); }
    }

    // GRU scan (coop, 48 blocks x 384 thr; fallback: 32 step launches)
    {
        GruP P;
        P.h0b = h0b; P.h0f = h0; P.whh = whhb; P.base = base; P.bhh = b_hh;
        P.qemb = qembb; P.flags = bar;
        void* args[1] = { &P };
        hipError_t e = hipLaunchCooperativeKernel((void*)k_gru_coop, dim3(GRU_NB), dim3(384),
                                                  args, 0, stream);
        if (e != hipSuccess)
            for (int t = 0; t < 32; t++)
                k_gru_step<<<12, blk, 0, stream>>>(t, h0b, whhb, base, b_hh, hbuf, qembb);
    }

    // Q = q_emb @ la_w0 + la_b0 ; Qt_h = Q_h @ W1_h^T (folded-K trick)
    k_gemm_bf16<<<dim3(12, 32), blk, 0, stream>>>(qembb, 768, law0b, 768, 0, la_b0, Qb, 768, 768, 0, 0);
    k_gemm_bf16<<<dim3(12, 32), blk, 0, stream>>>(Qb, 768, law1b, 768, 1, nullptr, Qtb, 768, 384, 1, 0);
    k_gemm_bf16<<<dim3(12, 32), blk, 0, stream>>>(Qb + 384, 768, law1b + 384, 768, 1, nullptr, Qtb, 768, 384, 1, 32);

    // flash attention, key-split
    k_flash<<<dim3(64, nsplit), dim3(512), 0, stream>>>(img, Qtb, Qb, la_b1, pm, pl, pacc, nsplit);

    // fused tail (coop, grid 256 <= 256 so always co-residable; fallback: per-phase)
    {
        TailP P;
        P.pm = pm; P.pl = pl; P.pacc = pacc; P.lp = la_pool;
        P.la_w2 = la_w2; P.la_b2 = la_b2; P.la_w3 = la_w3; P.la_b3 = la_b3; P.scal = scal;
        P.plX = plX; P.pc = pc; P.hcat = hcat;
        P.f1w = f1w; P.f1b = f1b; P.f2w = f2w; P.f2b = f2b_; P.f3w = f3w; P.f3b = f3b;
        P.x1 = x1; P.x2 = x2; P.out = out;
        P.flags = bar + 320; P.p0 = 0; P.p1 = 5; P.nsplit = nsplit;
        void* args[1] = { &P };
        if (nsplit == 4) {
            hipError_t e = hipLaunchCooperativeKernel((void*)k_tail<4>, dim3(256), blk, args, 0, stream);
            if (e != hipSuccess)
                for (int p = 0; p <= 5; p++) { P.p0 = P.p1 = p; k_tail<4><<<256, blk, 0, stream>>>(P); }
        } else {
            hipError_t e = hipLaunchCooperativeKernel((void*)k_tail<2>, dim3(256), blk, args, 0, stream);
            if (e != hipSuccess)
                for (int p = 0; p <= 5; p++) { P.p0 = P.p1 = p; k_tail<2><<<256, blk, 0, stream>>>(P); }
        }
    }
}

// Round 8
// 1005.613 us; speedup vs baseline: 1.7275x; 1.1313x over previous
//
#include <hip/hip_runtime.h>
#include <math.h>

// B=64, T=32, D=768, NH=2, dk=384, N=901 (1 cls + 900 local)

typedef short bf16x8 __attribute__((ext_vector_type(8)));
typedef float f32x4 __attribute__((ext_vector_type(4)));
typedef unsigned short ushort_t;

#define GRU_NB 48

__device__ __forceinline__ unsigned short f2b(float f) {
    unsigned int u = __float_as_uint(f);
    unsigned int r = (u + 0x7FFFu + ((u >> 16) & 1u)) >> 16;
    return (unsigned short)r;
}
__device__ __forceinline__ float b2f(unsigned short s) {
    return __uint_as_float(((unsigned int)s) << 16);
}
__device__ __forceinline__ float sigm(float x) { return 1.f / (1.f + __expf(-x)); }
__device__ __forceinline__ float tanhx(float x) {
    x = fminf(fmaxf(x, -15.f), 15.f);
    float e = __expf(2.f * x);
    return (e - 1.f) / (e + 1.f);
}

// flag barrier: arrival = agent store of monotonically-increasing phase id; poll =
// parallel relaxed agent loads (no RMW contention). Data written before the barrier
// must use agent-scope stores (bypass L2 -> L3) so readers' plain loads (fresh lines)
// see it. flags zeroed by k_cvt_all each launch.
__device__ __forceinline__ void gbar(int* flags, int nb, int phase, int bid, int tid) {
    __syncthreads();   // drains each wave's vmcnt -> agent stores are in L3
    if (tid == 0) __hip_atomic_store(&flags[bid], phase, __ATOMIC_RELAXED, __HIP_MEMORY_SCOPE_AGENT);
    if (tid < 64) {
        for (;;) {
            int v = 0x7fffffff;
            for (int f = tid; f < nb; f += 64)
                v = min(v, __hip_atomic_load(&flags[f], __ATOMIC_RELAXED, __HIP_MEMORY_SCOPE_AGENT));
            if (__all(v >= phase)) break;
            __builtin_amdgcn_s_sleep(1);
        }
    }
    __syncthreads();
}

// ---------------- setup: convert weights to bf16, pool sums, zero flags ----------------

__global__ void k_cvt_all(const float* __restrict__ whh, const float* __restrict__ la0,
                          const float* __restrict__ la1, const float* __restrict__ h0,
                          const float* __restrict__ gp, const float* __restrict__ lp,
                          ushort_t* __restrict__ whhb, ushort_t* __restrict__ law0b,
                          ushort_t* __restrict__ law1b, ushort_t* __restrict__ h0b,
                          float* __restrict__ hbuf, float* __restrict__ scal,
                          int* __restrict__ bar) {
    if (blockIdx.x == 0) {
        int t = threadIdx.x;
        if (t < 64) {
            float v1 = (t < 32) ? gp[t] : 0.f;
            float v2 = (t < 32) ? lp[t] : 0.f;
#pragma unroll
            for (int m = 1; m < 32; m <<= 1) { v1 += __shfl_xor(v1, m, 64); v2 += __shfl_xor(v2, m, 64); }
            if (t == 0) { scal[0] = v1; scal[1] = v2; }
        }
        for (int i = threadIdx.x; i < 1024; i += 256) bar[i] = 0;
    }
    long i = (long)blockIdx.x * 256 + threadIdx.x;
    const long n1 = 2304L * 768, n2 = n1 + 768L * 768, n3 = n2 + 768L * 768, n4 = n3 + 64L * 768;
    if (i < n1) whhb[i] = f2b(whh[i]);
    else if (i < n2) law0b[i - n1] = f2b(la0[i - n1]);
    else if (i < n3) law1b[i - n2] = f2b(la1[i - n2]);
    else if (i < n4) { float v = h0[i - n3]; h0b[i - n3] = f2b(v); hbuf[i - n3] = v; }
}

// ---------------- parallel fp32 tile GEMM: MR rows x 64 cols per block ----------------
// 256 threads = 64 cols x 4 K-chunks; each thread accumulates its K/4 chunk with 8
// independent B-loads in flight; cross-chunk reduction through LDS (aliased onto the
// dead A-tile). out = acc*s1 + bias[c]*s2 (+ bias2[c] if c<b2lim); optional relu,
// optional agent-scope store. Register-light by design (acc[MR]+bv[8]): no spill.

template<int MR>
__device__ __forceinline__ void tgemm4(
    const float* __restrict__ A, long lda,
    const float* __restrict__ Bm, int ldb, int transB,
    const float* __restrict__ bias, float s1, float s2,
    const float* __restrict__ bias2, int b2lim,
    float* __restrict__ C, int ldc, int K, int relu, int agent,
    int m0, int n0, float* As, int tid)
{
    for (int r = 0; r < MR; r++)
        for (int k = tid; k < K; k += 256)
            As[r * K + k] = A[(long)(m0 + r) * lda + k];
    __syncthreads();
    int cl = tid & 63, kc = tid >> 6;
    int c = n0 + cl;
    int K4 = K >> 2;
    int kb = kc * K4;
    const float* Bp = transB ? (Bm + (long)c * ldb) : (Bm + c);
    float acc[MR];
#pragma unroll
    for (int r = 0; r < MR; r++) acc[r] = 0.f;
    for (int k = kb; k < kb + K4; k += 8) {
        float bv[8];
        if (!transB) {
#pragma unroll
            for (int i = 0; i < 8; i++) bv[i] = Bp[(long)(k + i) * ldb];
        } else {
            float4 q0 = *(const float4*)(Bp + k);
            float4 q1 = *(const float4*)(Bp + k + 4);
            bv[0] = q0.x; bv[1] = q0.y; bv[2] = q0.z; bv[3] = q0.w;
            bv[4] = q1.x; bv[5] = q1.y; bv[6] = q1.z; bv[7] = q1.w;
        }
#pragma unroll
        for (int i = 0; i < 8; i += 4) {
#pragma unroll
            for (int r = 0; r < MR; r++) {
                float4 x = *(const float4*)&As[r * K + k + i];
                acc[r] += x.x * bv[i] + x.y * bv[i + 1] + x.z * bv[i + 2] + x.w * bv[i + 3];
            }
        }
    }
    __syncthreads();           // all As reads done -> safe to alias
    float* Red = As;           // 4*MR*64 floats <= MR*K (K>=256)
#pragma unroll
    for (int r = 0; r < MR; r++) Red[(kc * MR + r) * 64 + cl] = acc[r];
    __syncthreads();
    {
        int rg = tid >> 6;
        float bb = (bias ? bias[c] * s2 : 0.f) + ((bias2 && c < b2lim) ? bias2[c] : 0.f);
#pragma unroll
        for (int i = 0; i < MR / 4; i++) {
            int r = rg + i * 4;
            float sum = (Red[(0 * MR + r) * 64 + cl] + Red[(1 * MR + r) * 64 + cl])
                      + (Red[(2 * MR + r) * 64 + cl] + Red[(3 * MR + r) * 64 + cl]);
            float o = sum * s1 + bb;
            if (relu) o = fmaxf(o, 0.f);
            if (agent) __hip_atomic_store(&C[(long)(m0 + r) * ldc + c], o,
                                          __ATOMIC_RELAXED, __HIP_MEMORY_SCOPE_AGENT);
            else C[(long)(m0 + r) * ldc + c] = o;
        }
    }
}

// ---------------- fused head: t12/t12g -> avec/global_out -> base (3 phases) ----------------
// grid 192: p1/p2 = 2x8x12 = 192 blocks (MR=8), p3 = 4x36 = 144 blocks (MR=16)

struct HeadP {
    const float *img, *ga_w2, *ga_b2, *go_w2, *go_b2;
    const float *ga_w3, *ga_b3, *go_w3, *go_b3;
    const float *ga_pool, *scal, *w_ih, *b_ih, *b_hh;
    float *t12, *t12g, *avec, *hcat, *base;
    int* flags; int p0, p1;
};

__global__ void __launch_bounds__(256) k_head(HeadP P) {
    __shared__ __align__(16) float As[16 * 768];
    int bid = blockIdx.x, tid = threadIdx.x;
    for (int p = P.p0; p <= P.p1; p++) {
        if (p == 1) {
            if (bid < 192) {
                int prob = bid / 96, r = bid % 96, m8 = r / 12, ct = r % 12;
                tgemm4<8>(P.img, 901L * 768, prob ? P.go_w2 : P.ga_w2, 768, 0,
                          prob ? P.go_b2 : P.ga_b2, 1.f, 1.f, nullptr, 0,
                          prob ? P.t12g : P.t12, 768, 768, 0, 1, m8 * 8, ct * 64, As, tid);
            }
        } else if (p == 2) {
            if (bid < 192) {
                int prob = bid / 96, r = bid % 96, m8 = r / 12, ct = r % 12;
                float sc = prob ? P.scal[0] : P.ga_pool[0];
                tgemm4<8>(prob ? P.t12g : P.t12, 768, prob ? P.go_w3 : P.ga_w3, 768, 0,
                          prob ? P.go_b3 : P.ga_b3, sc, sc, nullptr, 0,
                          prob ? (P.hcat + 768) : P.avec, prob ? 1536 : 768, 768, 0, 1,
                          m8 * 8, ct * 64, As, tid);
            }
        } else if (p == 3) {
            if (bid < 144) {
                int m4 = bid / 36, ct = bid % 36;
                // base = avec @ w_ih^T + b_ih (+ b_hh for first 1536 cols)
                tgemm4<16>(P.avec, 768, P.w_ih, 768, 1, P.b_ih, 1.f, 1.f, P.b_hh, 1536,
                           P.base, 2304, 768, 0, 0, m4 * 16, ct * 64, As, tid);
            }
        }
        if (p < P.p1) gbar(P.flags, 192, p, bid, tid);
    }
}

// ---------------- GRU scan: 48 blocks x 384 thr (6 waves = 3 gates x 2 M-halves) ----------------
// A staged into LDS in K-quarters (coalesced, each byte fetched ONCE per block per
// step) -> kills the scattered per-wave global reads that were transaction-bound.
// gs (gate partials) aliased onto the dead A-tile region to stay <= 121 KB LDS
// (proven-safe; the 160 KB variant failed to run). Flag barrier across 48 blocks.

struct GruP {
    const ushort_t* h0b; const float* h0f; const ushort_t* whh;
    const float* base; const float* bhh; ushort_t* qemb; int* flags;
};

__global__ void __launch_bounds__(384) k_gru_coop(GruP P) {
    __shared__ __align__(16) ushort_t whh_s[3][16][776];
    __shared__ __align__(16) ushort_t as_s[64][200];   // A quarter-tile (K=192), padded
    __shared__ float bs[3][64][20];
    __shared__ float h_s[64][20];
    __shared__ float bhh_s[16];
    float* gs = (float*)&as_s[0][0];                   // gs[3][64][20] = 15360B <= 25600B
    int tid = threadIdx.x;
    int wid = tid >> 6, lane = tid & 63, quad = lane >> 4, l16 = lane & 15;
    int g = wid >> 1, mh = wid & 1;          // gate, M-half (rows mh*32..mh*32+31)
    int j = blockIdx.x, d0 = j * 16;
    {   // stage whh: waves 0-2 -> gate wid rows 0-7; waves 3-5 -> gate wid-3 rows 8-15
        int gS = (wid < 3) ? wid : wid - 3;
        int r0 = (wid < 3) ? 0 : 8;
        for (int r = r0; r < r0 + 8; r++)
            for (int kk = lane * 8; kk < 768; kk += 512)
                *(bf16x8*)&whh_s[gS][r][kk] = *(const bf16x8*)&P.whh[(size_t)(gS * 768 + d0 + r) * 768 + kk];
    }
    for (int e = tid; e < 3072; e += 384) {
        int g2 = e >> 10, rem = e & 1023, b = rem >> 4, c = rem & 15;
        bs[g2][b][c] = P.base[b * 2304 + g2 * 768 + d0 + c];
    }
    for (int e = tid; e < 1024; e += 384) {
        int b = e >> 4, c = e & 15;
        h_s[b][c] = P.h0f[b * 768 + d0 + c];
    }
    if (tid < 16) bhh_s[tid] = P.bhh[1536 + d0 + tid];
    __syncthreads();
    for (int t = 0; t < 32; t++) {
        const ushort_t* Ap = (t == 0) ? P.h0b : (P.qemb + (size_t)(t - 1) * 768);
        size_t ldA = (t == 0) ? 768 : (size_t)32 * 768;
        f32x4 zz4 = {0.f, 0.f, 0.f, 0.f};
        f32x4 acc[2];
        acc[0] = zz4; acc[1] = zz4;
        for (int kq = 0; kq < 4; kq++) {
            __syncthreads();   // prior readers of as_s (compute / elementwise-gs) done
            // stage A quarter-tile: 64 rows x 192 bf16, 16B chunks, coalesced in-row
#pragma unroll
            for (int i = 0; i < 4; i++) {
                int id = i * 384 + tid;        // 0..1535
                int row = id / 24, c = id % 24;
                *(bf16x8*)&as_s[row][c * 8] =
                    *(const bf16x8*)(Ap + (size_t)row * ldA + kq * 192 + c * 8);
            }
            __syncthreads();
            // compute: wave (g, mh) does rows mh*32..+31, gate g, this K-quarter
            for (int kk = 0; kk < 192; kk += 32) {
                bf16x8 bfr = *(const bf16x8*)&whh_s[g][l16][kq * 192 + kk + quad * 8];
#pragma unroll
                for (int mi = 0; mi < 2; mi++) {
                    bf16x8 af = *(const bf16x8*)&as_s[mh * 32 + mi * 16 + l16][kk + quad * 8];
                    acc[mi] = __builtin_amdgcn_mfma_f32_16x16x32_bf16(af, bfr, acc[mi], 0, 0, 0);
                }
            }
        }
        __syncthreads();       // all computes done -> safe to overwrite as_s with gs
#pragma unroll
        for (int mi = 0; mi < 2; mi++)
#pragma unroll
            for (int r = 0; r < 4; r++)
                gs[((size_t)g * 64 + mh * 32 + mi * 16 + quad * 4 + r) * 20 + l16] = acc[mi][r];
        __syncthreads();
        for (int e = tid; e < 512; e += 384) {
            int b = e >> 3, c0 = (e & 7) * 2;
            float hn[2];
#pragma unroll
            for (int u = 0; u < 2; u++) {
                int c = c0 + u;
                float g0 = gs[((size_t)0 * 64 + b) * 20 + c];
                float g1 = gs[((size_t)1 * 64 + b) * 20 + c];
                float g2v = gs[((size_t)2 * 64 + b) * 20 + c];
                float rr = sigm(g0 + bs[0][b][c]);
                float zg = sigm(g1 + bs[1][b][c]);
                float nn = tanhx(bs[2][b][c] + rr * (g2v + bhh_s[c]));
                float hv = h_s[b][c];
                hn[u] = (1.f - zg) * nn + zg * hv;
                h_s[b][c] = hn[u];
            }
            unsigned int pk = (unsigned int)f2b(hn[0]) | ((unsigned int)f2b(hn[1]) << 16);
            __hip_atomic_store((unsigned int*)&P.qemb[((size_t)b * 32 + t) * 768 + d0 + c0],
                               pk, __ATOMIC_RELAXED, __HIP_MEMORY_SCOPE_AGENT);
        }
        __syncthreads();   // drain agent stores to L3 before flag; gs reads done
        if (t < 31) {
            if (tid == 0)
                __hip_atomic_store(&P.flags[j], t + 1, __ATOMIC_RELAXED, __HIP_MEMORY_SCOPE_AGENT);
            if (tid < 64) {
                for (;;) {
                    int v = (tid < GRU_NB)
                        ? __hip_atomic_load(&P.flags[tid], __ATOMIC_RELAXED, __HIP_MEMORY_SCOPE_AGENT)
                        : 0x7fffffff;
                    if (__all(v > t)) break;
                    __builtin_amdgcn_s_sleep(1);
                }
            }
            __syncthreads();
        }
    }
}

// fallback (non-coop): 32 per-step launches
__global__ void __launch_bounds__(256) k_gru_step(
    int t, const ushort_t* h0b, const ushort_t* whh, const float* base,
    const float* bhh, float* h, ushort_t* qemb)
{
    int wv = threadIdx.x >> 6, lane = threadIdx.x & 63;
    int quad = lane >> 4, l16 = lane & 15;
    int d0 = blockIdx.x * 64 + wv * 16;
    float bhhn = bhh[1536 + d0 + l16];
    const ushort_t* Ap = (t == 0) ? h0b : (qemb + (long)(t - 1) * 768);
    long ldA = (t == 0) ? 768 : 32 * 768;
    int d = d0 + l16;
    f32x4 zz4 = {0.f, 0.f, 0.f, 0.f};
    f32x4 acc[3][4];
#pragma unroll
    for (int g = 0; g < 3; g++)
#pragma unroll
        for (int mi = 0; mi < 4; mi++) acc[g][mi] = zz4;
    for (int kk = 0; kk < 768; kk += 32) {
        bf16x8 af[4];
#pragma unroll
        for (int mi = 0; mi < 4; mi++)
            af[mi] = *(const bf16x8*)(Ap + (long)(mi * 16 + l16) * ldA + kk + quad * 8);
#pragma unroll
        for (int g = 0; g < 3; g++) {
            bf16x8 bfr = *(const bf16x8*)(whh + (long)(g * 768 + d0 + l16) * 768 + kk + quad * 8);
#pragma unroll
            for (int mi = 0; mi < 4; mi++)
                acc[g][mi] = __builtin_amdgcn_mfma_f32_16x16x32_bf16(af[mi], bfr, acc[g][mi], 0, 0, 0);
        }
    }
#pragma unroll
    for (int mi = 0; mi < 4; mi++) {
#pragma unroll
        for (int r = 0; r < 4; r++) {
            int b = mi * 16 + quad * 4 + r;
            const float* bb = base + b * 2304;
            float rr = sigm(acc[0][mi][r] + bb[d]);
            float zg = sigm(acc[1][mi][r] + bb[768 + d]);
            float nn = tanhx(bb[1536 + d] + rr * (acc[2][mi][r] + bhhn));
            float hv = h[b * 768 + d];
            float hnew = (1.f - zg) * nn + zg * hv;
            h[b * 768 + d] = hnew;
            qemb[(long)(b * 32 + t) * 768 + d] = f2b(hnew);
        }
    }
}

// ---------------- generic bf16 MFMA GEMM (64x64 tile) ----------------

__global__ void __launch_bounds__(256) k_gemm_bf16(
    const ushort_t* __restrict__ A, int lda,
    const ushort_t* __restrict__ B, int ldb, int transB,
    const float* __restrict__ bias,
    ushort_t* __restrict__ Cb, int ldc,
    int K, int remap, int rowoff)
{
    __shared__ __align__(16) ushort_t As[64][72];
    __shared__ __align__(16) ushort_t Bs[64][72];
    int tid = threadIdx.x;
    int wv = tid >> 6, lane = tid & 63, quad = lane >> 4, l16 = lane & 15;
    long bm = (long)blockIdx.y * 64, bn = (long)blockIdx.x * 64;
    f32x4 zz4 = {0.f, 0.f, 0.f, 0.f};
    f32x4 acc[4];
#pragma unroll
    for (int mi = 0; mi < 4; mi++) acc[mi] = zz4;
    int row4 = tid >> 2, seg = tid & 3;
    for (int k0 = 0; k0 < K; k0 += 64) {
        {
            const ushort_t* src = A + (bm + row4) * lda + k0 + seg * 16;
            *(bf16x8*)&As[row4][seg * 16] = *(const bf16x8*)src;
            *(bf16x8*)&As[row4][seg * 16 + 8] = *(const bf16x8*)(src + 8);
        }
        if (transB) {
            const ushort_t* src = B + (bn + row4) * ldb + k0 + seg * 16;
            *(bf16x8*)&Bs[row4][seg * 16] = *(const bf16x8*)src;
            *(bf16x8*)&Bs[row4][seg * 16 + 8] = *(const bf16x8*)(src + 8);
        } else {
            const ushort_t* src = B + (long)(k0 + row4) * ldb + bn + seg * 16;
            bf16x8 v0 = *(const bf16x8*)src;
            bf16x8 v1 = *(const bf16x8*)(src + 8);
#pragma unroll
            for (int i = 0; i < 8; i++) {
                Bs[seg * 16 + i][row4] = (ushort_t)v0[i];
                Bs[seg * 16 + 8 + i][row4] = (ushort_t)v1[i];
            }
        }
        __syncthreads();
#pragma unroll
        for (int ks = 0; ks < 64; ks += 32) {
            bf16x8 bfr = *(const bf16x8*)&Bs[wv * 16 + l16][ks + quad * 8];
#pragma unroll
            for (int mi = 0; mi < 4; mi++) {
                bf16x8 af = *(const bf16x8*)&As[mi * 16 + l16][ks + quad * 8];
                acc[mi] = __builtin_amdgcn_mfma_f32_16x16x32_bf16(af, bfr, acc[mi], 0, 0, 0);
            }
        }
        __syncthreads();
    }
    int ncol = (int)bn + wv * 16 + l16;
    float bv = bias ? bias[ncol] : 0.f;
#pragma unroll
    for (int mi = 0; mi < 4; mi++) {
#pragma unroll
        for (int r = 0; r < 4; r++) {
            long row = bm + mi * 16 + quad * 4 + r;
            long orow = remap ? ((row >> 5) * 64 + rowoff + (row & 31)) : row;
            Cb[orow * ldc + ncol] = f2b(acc[mi][r] + bv);
        }
    }
}

// ---------------- fused flash attention, key-split partials (qb folded in) ----------------

__global__ void __launch_bounds__(512) k_flash(
    const float* __restrict__ img, const ushort_t* __restrict__ Qt,
    const ushort_t* __restrict__ Qb, const float* __restrict__ la_b1,
    float* __restrict__ pm, float* __restrict__ pl,
    ushort_t* __restrict__ pacc, int nsplit)
{
    __shared__ __align__(16) ushort_t xs[32][776];
    __shared__ float Sls[64][36];
    __shared__ __align__(16) ushort_t Pls[64][40];
    __shared__ float m_s[64], l_s[64], al_s[64], qb_s[64];
    int b = blockIdx.x;
    int sp = blockIdx.y;
    int tper = (29 + nsplit - 1) / nsplit;
    int tb = sp * tper, te = min(29, tb + tper);
    int tid = threadIdx.x;
    int wv = tid >> 6, lane = tid & 63, quad = lane >> 4, l16 = lane & 15;
    { // qb_s[row] = Q_h[b,q,:] . la_b1_h   (8 lanes per row)
        int row = tid >> 3, sub = tid & 7;
        int hh = row >> 5, q = row & 31;
        const ushort_t* src = Qb + ((size_t)(b * 32 + q)) * 768 + hh * 384 + sub * 48;
        const float* bb = la_b1 + hh * 384 + sub * 48;
        float s = 0.f;
#pragma unroll
        for (int k = 0; k < 48; k++) s += b2f(src[k]) * bb[k];
        s += __shfl_xor(s, 1, 64); s += __shfl_xor(s, 2, 64); s += __shfl_xor(s, 4, 64);
        if (sub == 0) qb_s[row] = s;
    }
    if (tid < 64) { m_s[tid] = -1e30f; l_s[tid] = 0.f; }
    f32x4 zz4 = {0.f, 0.f, 0.f, 0.f};
    f32x4 acc[4][6];
#pragma unroll
    for (int mi = 0; mi < 4; mi++)
#pragma unroll
        for (int nj = 0; nj < 6; nj++) acc[mi][nj] = zz4;
    const float rs = 0.051031036307982884f; // 1/sqrt(384)
    int smi = wv & 3, sni = wv >> 2;
    __syncthreads();
    for (int t0 = tb; t0 < te; t0++) {
        int key0 = t0 * 32;
        { // stage x tile (fp32 global -> bf16 LDS), zero-fill past key 899
            int keyl = tid >> 4, dseg = tid & 15;
            int key = key0 + keyl;
            const float* src = img + ((long)b * 901 + 1 + key) * 768;
            bool ok = key < 900;
#pragma unroll
            for (int c = 0; c < 12; c++) {
                int dd = c * 64 + dseg * 4;
                float x0 = 0, x1 = 0, x2 = 0, x3 = 0;
                if (ok) { float4 v = *(const float4*)(src + dd); x0 = v.x; x1 = v.y; x2 = v.z; x3 = v.w; }
                ushort_t* dst = &xs[keyl][dd];
                dst[0] = f2b(x0); dst[1] = f2b(x1); dst[2] = f2b(x2); dst[3] = f2b(x3);
            }
        }
        __syncthreads();
        { // S = Qt @ x^T
            f32x4 as = zz4;
            const ushort_t* qrow = Qt + (long)(b * 64 + smi * 16 + l16) * 768 + quad * 8;
            const ushort_t* xrow = &xs[sni * 16 + l16][quad * 8];
#pragma unroll
            for (int kk = 0; kk < 768; kk += 32) {
                bf16x8 aq = *(const bf16x8*)(qrow + kk);
                bf16x8 bx = *(const bf16x8*)(xrow + kk);
                as = __builtin_amdgcn_mfma_f32_16x16x32_bf16(aq, bx, as, 0, 0, 0);
            }
#pragma unroll
            for (int r = 0; r < 4; r++) {
                int row = smi * 16 + quad * 4 + r;
                Sls[row][sni * 16 + l16] = (as[r] + qb_s[row]) * rs;
            }
        }
        __syncthreads();
        { // online softmax: 8 threads per row
            int row = tid >> 3, sub = tid & 7;
            float sv[4];
            float mx = -1e30f;
#pragma unroll
            for (int i = 0; i < 4; i++) {
                int kl = sub + i * 8;
                float s = (key0 + kl < 900) ? Sls[row][kl] : -1e30f;
                sv[i] = s; mx = fmaxf(mx, s);
            }
            mx = fmaxf(mx, __shfl_xor(mx, 1, 64));
            mx = fmaxf(mx, __shfl_xor(mx, 2, 64));
            mx = fmaxf(mx, __shfl_xor(mx, 4, 64));
            float mold = m_s[row];
            float mnew = fmaxf(mold, mx);
            float ss = 0.f;
#pragma unroll
            for (int i = 0; i < 4; i++) {
                float p = __expf(sv[i] - mnew);
                ss += p;
                Pls[row][sub + i * 8] = f2b(p);
            }
            ss += __shfl_xor(ss, 1, 64);
            ss += __shfl_xor(ss, 2, 64);
            ss += __shfl_xor(ss, 4, 64);
            if (sub == 0) {
                float alpha = __expf(mold - mnew);
                al_s[row] = alpha;
                l_s[row] = l_s[row] * alpha + ss;
                m_s[row] = mnew;
            }
        }
        __syncthreads();
        { // rescale + acc += P @ x
            bf16x8 pf[4];
#pragma unroll
            for (int mi = 0; mi < 4; mi++)
                pf[mi] = *(const bf16x8*)&Pls[mi * 16 + l16][quad * 8];
#pragma unroll
            for (int mi = 0; mi < 4; mi++) {
#pragma unroll
                for (int r = 0; r < 4; r++) {
                    float a = al_s[mi * 16 + quad * 4 + r];
#pragma unroll
                    for (int nj = 0; nj < 6; nj++) acc[mi][nj][r] *= a;
                }
            }
#pragma unroll
            for (int nj = 0; nj < 6; nj++) {
                int dd = wv * 96 + nj * 16 + l16;
                bf16x8 bx;
#pragma unroll
                for (int j = 0; j < 8; j++) bx[j] = (short)xs[quad * 8 + j][dd];
#pragma unroll
                for (int mi = 0; mi < 4; mi++)
                    acc[mi][nj] = __builtin_amdgcn_mfma_f32_16x16x32_bf16(pf[mi], bx, acc[mi][nj], 0, 0, 0);
            }
        }
        __syncthreads();
    }
    if (tid < 64) {
        pm[(b * nsplit + sp) * 64 + tid] = m_s[tid];
        pl[(b * nsplit + sp) * 64 + tid] = l_s[tid];
    }
#pragma unroll
    for (int mi = 0; mi < 4; mi++) {
#pragma unroll
        for (int r = 0; r < 4; r++) {
            int row = mi * 16 + quad * 4 + r;
            ushort_t* dst = pacc + ((size_t)(b * nsplit + sp) * 64 + row) * 768;
#pragma unroll
            for (int nj = 0; nj < 6; nj++)
                dst[wv * 96 + nj * 16 + l16] = f2b(acc[mi][nj][r]);
        }
    }
}

// ---------------- fused tail: combine+pool -> pc -> local_out -> f1 -> f2 -> f3 ----------------
// grid 256; phases: p0 192 (64b x 3 col-chunks, both halves), p1/p2 192 (MR=4),
// p3 256, p4 128, p5 256

struct TailP {
    const float *pm, *pl; const ushort_t* pacc; const float* lp;
    const float *la_w2, *la_b2, *la_w3, *la_b3, *scal;
    float *plX, *pc, *hcat;
    const float *f1w, *f1b, *f2w, *f2b, *f3w, *f3b;
    float *x1, *x2, *out;
    int* flags; int p0, p1, nsplit;
};

template<int NS>
__global__ void __launch_bounds__(256) k_tail(TailP P) {
    __shared__ __align__(16) float As[4 * 1536];
    __shared__ float cw[NS][64];
    int bid = blockIdx.x, tid = threadIdx.x;
    float sla = P.scal[1];
    for (int p = P.p0; p <= P.p1; p++) {
        if (p == 0) {
            // 192 blocks = 64 batches x 3 col-chunks of 256; each thread handles one
            // column for BOTH row-halves: <=16 independent loads in flight, no spill.
            if (bid < 192) {
                int b = bid / 3, jj = bid % 3;
                if (tid < 64) {
                    int row = tid;
                    float ex[NS];
                    float mmax = -1e30f;
#pragma unroll
                    for (int s = 0; s < NS; s++) mmax = fmaxf(mmax, P.pm[(b * NS + s) * 64 + row]);
                    float lsum = 0.f;
#pragma unroll
                    for (int s = 0; s < NS; s++) {
                        ex[s] = __expf(P.pm[(b * NS + s) * 64 + row] - mmax);
                        lsum += ex[s] * P.pl[(b * NS + s) * 64 + row];
                    }
                    float sc = P.lp[row & 31] / lsum;
#pragma unroll
                    for (int s = 0; s < NS; s++) cw[s][row] = ex[s] * sc;
                }
                __syncthreads();
                int col = jj * 256 + tid;
                const ushort_t* pp = P.pacc + ((size_t)(b * NS)) * 64 * 768 + col;
                float ac0 = 0.f, ac1 = 0.f;
                for (int q = 0; q < 32; q += 2) {
                    float vv[2][NS][2];
#pragma unroll
                    for (int u = 0; u < 2; u++)
#pragma unroll
                        for (int s = 0; s < NS; s++) {
                            vv[u][s][0] = b2f(pp[((size_t)(s * 64 + q + u)) * 768]);
                            vv[u][s][1] = b2f(pp[((size_t)(s * 64 + 32 + q + u)) * 768]);
                        }
#pragma unroll
                    for (int u = 0; u < 2; u++)
#pragma unroll
                        for (int s = 0; s < NS; s++) {
                            ac0 += cw[s][q + u] * vv[u][s][0];
                            ac1 += cw[s][32 + q + u] * vv[u][s][1];
                        }
                }
                __hip_atomic_store(&P.plX[b * 1536 + col], ac0,
                                   __ATOMIC_RELAXED, __HIP_MEMORY_SCOPE_AGENT);
                __hip_atomic_store(&P.plX[b * 1536 + 768 + col], ac1,
                                   __ATOMIC_RELAXED, __HIP_MEMORY_SCOPE_AGENT);
            }
        } else if (p == 1) {
            if (bid < 192) {
                int m4 = bid / 12, ct = bid % 12, prob = ct / 6;
                tgemm4<4>(P.plX + prob * 768, 1536, P.la_w2, 768, 0,
                          P.la_b2, 1.f, sla, nullptr, 0,
                          P.pc, 768, 768, 0, 1, m4 * 4, ct * 64, As, tid);
            }
        } else if (p == 2) {
            if (bid < 192) {
                int m4 = bid / 12, ct = bid % 12;
                tgemm4<4>(P.pc, 768, P.la_w3, 768, 0, P.la_b3, 1.f, sla, nullptr, 0,
                          P.hcat, 1536, 768, 0, 1, m4 * 4, ct * 64, As, tid);
            }
        } else if (p == 3) {
            if (bid < 256) {
                int m4 = bid / 16, ct = bid % 16;
                tgemm4<4>(P.hcat, 1536, P.f1w, 1024, 0, P.f1b, 1.f, 1.f, nullptr, 0,
                          P.x1, 1024, 1536, 0, 1, m4 * 4, ct * 64, As, tid);
            }
        } else if (p == 4) {
            if (bid < 128) {
                int m4 = bid / 8, ct = bid % 8;
                tgemm4<4>(P.x1, 1024, P.f2w, 512, 0, P.f2b, 1.f, 1.f, nullptr, 0,
                          P.x2, 512, 1024, 1, 1, m4 * 4, ct * 64, As, tid);
            }
        } else if (p == 5) {
            if (bid < 256) {
                int m4 = bid / 16, ct = bid % 16;
                tgemm4<4>(P.x2, 512, P.f3w, 1024, 0, P.f3b, 1.f, 1.f, nullptr, 0,
                          P.out, 1024, 512, 0, 0, m4 * 4, ct * 64, As, tid);
            }
        }
        if (p < P.p1) gbar(P.flags, 256, p + 1, bid, tid);
    }
}

// ---------------- host launcher ----------------

extern "C" void kernel_launch(void* const* d_in, const int* in_sizes, int n_in,
                              void* d_out, int out_size, void* d_ws, size_t ws_size,
                              hipStream_t stream)
{
    const float* img  = (const float*)d_in[1];
    const float* h0   = (const float*)d_in[2];
    const float* w_ih = (const float*)d_in[3];
    const float* w_hh = (const float*)d_in[4];
    const float* b_ih = (const float*)d_in[5];
    const float* b_hh = (const float*)d_in[6];
    const float* ga_w = (const float*)d_in[7];
    const float* ga_b = (const float*)d_in[8];
    const float* ga_pool = (const float*)d_in[9];
    const float* la_w = (const float*)d_in[10];
    const float* la_b = (const float*)d_in[11];
    const float* la_pool = (const float*)d_in[12];
    const float* go_w = (const float*)d_in[13];
    const float* go_b = (const float*)d_in[14];
    const float* go_pool = (const float*)d_in[15];
    const float* f1w = (const float*)d_in[16];
    const float* f1b = (const float*)d_in[17];
    const float* f2w = (const float*)d_in[18];
    const float* f2b_ = (const float*)d_in[19];
    const float* f3w = (const float*)d_in[20];
    const float* f3b = (const float*)d_in[21];
    float* out = (float*)d_out;
    (void)in_sizes; (void)n_in; (void)out_size;

    int nsplit = (ws_size >= (size_t)43 * 1024 * 1024) ? 4 : 2;

    char* w = (char*)d_ws;
    auto alloc = [&](size_t bytes) -> char* {
        char* p = w; w += (bytes + 255) & ~(size_t)255; return p;
    };
    // persistent region
    float*    scal  = (float*)alloc(256);                 // [0]=S_go [1]=S_la
    int*      bar   = (int*)alloc(4096);                  // [0..47]=GRU [64..255]=head [320..575]=tail
    ushort_t* law0b = (ushort_t*)alloc((size_t)768 * 768 * 2);
    ushort_t* law1b = (ushort_t*)alloc((size_t)768 * 768 * 2);
    ushort_t* h0b   = (ushort_t*)alloc((size_t)64 * 768 * 2);
    ushort_t* qembb = (ushort_t*)alloc((size_t)2048 * 768 * 2);
    ushort_t* Qb    = (ushort_t*)alloc((size_t)2048 * 768 * 2);
    ushort_t* Qtb   = (ushort_t*)alloc((size_t)4096 * 768 * 2);
    float*    pm    = (float*)alloc((size_t)64 * 4 * 64 * 4);
    float*    pl    = (float*)alloc((size_t)64 * 4 * 64 * 4);
    float*    plX   = (float*)alloc((size_t)64 * 1536 * 4);
    float*    pc    = (float*)alloc((size_t)64 * 768 * 4);
    float*    hcat  = (float*)alloc((size_t)64 * 1536 * 4);
    float*    x1    = (float*)alloc((size_t)64 * 1024 * 4);
    float*    x2    = (float*)alloc((size_t)64 * 512 * 4);
    // union region: [GRU-phase temporaries] overlaid with [flash pacc]
    char* uni = w;
    char* u = uni;
    auto ualloc = [&](size_t bytes) -> char* {
        char* p = u; u += (bytes + 255) & ~(size_t)255; return p;
    };
    ushort_t* whhb  = (ushort_t*)ualloc((size_t)2304 * 768 * 2);
    float*    t12   = (float*)ualloc((size_t)2 * 64 * 768 * 4);
    float*    avec  = (float*)ualloc((size_t)64 * 768 * 4);
    float*    base  = (float*)ualloc((size_t)64 * 2304 * 4);
    float*    hbuf  = (float*)ualloc((size_t)64 * 768 * 4);
    ushort_t* pacc  = (ushort_t*)uni;   // overlays GRU temporaries; used only after GRU done
    float*    t12g  = t12 + 64 * 768;

    const float* ga_w2 = ga_w + 2 * 768 * 768; const float* ga_w3 = ga_w + 3 * 768 * 768;
    const float* ga_b2 = ga_b + 2 * 768;       const float* ga_b3 = ga_b + 3 * 768;
    const float* go_w2 = go_w + 2 * 768 * 768; const float* go_w3 = go_w + 3 * 768 * 768;
    const float* go_b2 = go_b + 2 * 768;       const float* go_b3 = go_b + 3 * 768;
    const float* la_w0 = la_w;                 const float* la_w1 = la_w + 768 * 768;
    const float* la_w2 = la_w + 2 * 768 * 768; const float* la_w3 = la_w + 3 * 768 * 768;
    const float* la_b0 = la_b;                 const float* la_b1 = la_b + 768;
    const float* la_b2 = la_b + 2 * 768;       const float* la_b3 = la_b + 3 * 768;

    dim3 blk(256);
    k_cvt_all<<<11712, blk, 0, stream>>>(w_hh, la_w0, la_w1, h0, go_pool, la_pool,
                                         whhb, law0b, law1b, h0b, hbuf, scal, bar);

    // fused head (coop, grid 192 <= 256 so always co-residable; fallback: per-phase)
    {
        HeadP P;
        P.img = img; P.ga_w2 = ga_w2; P.ga_b2 = ga_b2; P.go_w2 = go_w2; P.go_b2 = go_b2;
        P.ga_w3 = ga_w3; P.ga_b3 = ga_b3; P.go_w3 = go_w3; P.go_b3 = go_b3;
        P.ga_pool = ga_pool; P.scal = scal; P.w_ih = w_ih; P.b_ih = b_ih; P.b_hh = b_hh;
        P.t12 = t12; P.t12g = t12g; P.avec = avec; P.hcat = hcat; P.base = base;
        P.flags = bar + 64; P.p0 = 1; P.p1 = 3;
        void* args[1] = { &P };
        hipError_t e = hipLaunchCooperativeKernel((void*)k_head, dim3(192), blk, args, 0, stream);
        if (e != hipSuccess)
            for (int p = 1; p <= 3; p++) { P.p0 = P.p1 = p; k_head<<<192, blk, 0, stream>>>(P); }
    }

    // GRU scan (coop, 48 blocks x 384 thr; fallback: 32 step launches)
    {
        GruP P;
        P.h0b = h0b; P.h0f = h0; P.whh = whhb; P.base = base; P.bhh = b_hh;
        P.qemb = qembb; P.flags = bar;
        void* args[1] = { &P };
        hipError_t e = hipLaunchCooperativeKernel((void*)k_gru_coop, dim3(GRU_NB), dim3(384),
                                                  args, 0, stream);
        if (e != hipSuccess)
            for (int t = 0; t < 32; t++)
                k_gru_step<<<12, blk, 0, stream>>>(t, h0b, whhb, base, b_hh, hbuf, qembb);
    }

    // Q = q_emb @ la_w0 + la_b0 ; Qt_h = Q_h @ W1_h^T (folded-K trick)
    k_gemm_bf16<<<dim3(12, 32), blk, 0, stream>>>(qembb, 768, law0b, 768, 0, la_b0, Qb, 768, 768, 0, 0);
    k_gemm_bf16<<<dim3(12, 32), blk, 0, stream>>>(Qb, 768, law1b, 768, 1, nullptr, Qtb, 768, 384, 1, 0);
    k_gemm_bf16<<<dim3(12, 32), blk, 0, stream>>>(Qb + 384, 768, law1b + 384, 768, 1, nullptr, Qtb, 768, 384, 1, 32);

    // flash attention, key-split
    k_flash<<<dim3(64, nsplit), dim3(512), 0, stream>>>(img, Qtb, Qb, la_b1, pm, pl, pacc, nsplit);

    // fused tail (coop, grid 256 <= 256 so always co-residable; fallback: per-phase)
    {
        TailP P;
        P.pm = pm; P.pl = pl; P.pacc = pacc; P.lp = la_pool;
        P.la_w2 = la_w2; P.la_b2 = la_b2; P.la_w3 = la_w3; P.la_b3 = la_b3; P.scal = scal;
        P.plX = plX; P.pc = pc; P.hcat = hcat;
        P.f1w = f1w; P.f1b = f1b; P.f2w = f2w; P.f2b = f2b_; P.f3w = f3w; P.f3b = f3b;
        P.x1 = x1; P.x2 = x2; P.out = out;
        P.flags = bar + 320; P.p0 = 0; P.p1 = 5; P.nsplit = nsplit;
        void* args[1] = { &P };
        if (nsplit == 4) {
            hipError_t e = hipLaunchCooperativeKernel((void*)k_tail<4>, dim3(256), blk, args, 0, stream);
            if (e != hipSuccess)
                for (int p = 0; p <= 5; p++) { P.p0 = P.p1 = p; k_tail<4><<<256, blk, 0, stream>>>(P); }
        } else {
            hipError_t e = hipLaunchCooperativeKernel((void*)k_tail<2>, dim3(256), blk, args, 0, stream);
            if (e != hipSuccess)
                for (int p = 0; p <= 5; p++) { P.p0 = P.p1 = p; k_tail<2><<<256, blk, 0, stream>>>(P); }
        }
    }
}